// Round 9
// baseline (418.485 us; speedup 1.0000x reference)
//
#include <hip/hip_runtime.h>
#include <hip/hip_bf16.h>

#define T_STEPS 8192
#define LMAX 12
#define DV 128
#define DI 65
#define NG 256   // 4*H
#define HH 64

#define SMAX (T_STEPS * LMAX)        // 98304 worst-case lang rows
#define GD_ROWS (T_STEPS + 64)       // dense G3 rows (pad for prefetch)
#define GL_ROWS (SMAX + 64)          // lang G3 rows
#define KS_WORDS (SMAX + 64)
#define WARM 128                     // warmup rows (validated in r4-r6)
#define CH_VAD 85                    // chunks per vad/img chain
#define CH_LNG 384                   // chunks per lang chain
#define NBLK_SEQ (3*CH_VAD + 2*CH_LNG)   // 1023 <= 1024 SIMDs

// Abf segment row offsets (all 64-aligned)
#define SEG1 8192
#define SEG2 16384
#define SEG3 24576
#define SEG4 122880
#define TOTROWS 221184

typedef short s16x8 __attribute__((ext_vector_type(8)));
typedef float f32x4 __attribute__((ext_vector_type(4)));
typedef float v2f __attribute__((ext_vector_type(2)));

__device__ __forceinline__ void pk_fma(v2f& d, v2f a, v2f b){
    asm("v_pk_fma_f32 %0, %1, %2, %0" : "+v"(d) : "v"(a), "v"(b));
}

#if __has_builtin(__builtin_amdgcn_exp2f)
__device__ __forceinline__ float fast_exp2(float x){ return __builtin_amdgcn_exp2f(x); }
#else
__device__ __forceinline__ float fast_exp2(float x){ return exp2f(x); }
#endif
#if __has_builtin(__builtin_amdgcn_rcpf)
__device__ __forceinline__ float fast_rcp(float x){ return __builtin_amdgcn_rcpf(x); }
#else
__device__ __forceinline__ float fast_rcp(float x){ return 1.0f/x; }
#endif

__device__ __forceinline__ unsigned short f2bf(float f){
    unsigned u = __float_as_uint(f);
    unsigned r = (u + 0x7fffu + ((u>>16)&1u)) >> 16;   // RNE
    return (unsigned short)r;
}
__device__ __forceinline__ unsigned packbf2(float a, float b){
    return (unsigned)f2bf(a) | ((unsigned)f2bf(b) << 16);
}

// ---------------- prefix scan of lens -> exclusive offsets (+ total at [T]) --
__global__ void scan_kernel(const int* __restrict__ lenA, const int* __restrict__ lenB,
                            int* __restrict__ offsA, int* __restrict__ offsB)
{
    const int* len = blockIdx.x ? lenB : lenA;
    int* offs = blockIdx.x ? offsB : offsA;
    int lane = threadIdx.x;   // 64 threads
    int carry = 0;
    for (int base = 0; base < T_STEPS; base += 64) {
        int x = len[base + lane];
        int v = x;
        #pragma unroll
        for (int d = 1; d < 64; d <<= 1) {
            int u = __shfl_up(v, d);
            if (lane >= d) v += u;
        }
        offs[base + lane] = carry + v - x;     // exclusive
        carry += __shfl(v, 63);
    }
    if (lane == 0) offs[T_STEPS] = carry;
}

// ---- build compacted-row -> source-row map, and per-row boundary counts ----
__global__ void build_meta(const int* __restrict__ len, const int* __restrict__ offs,
                           int* __restrict__ idx, int* __restrict__ Ks)
{
    int t = blockIdx.x * blockDim.x + threadIdx.x;
    if (t >= T_STEPS) return;
    int n = len[t];
    int o = offs[t];
    for (int p = 0; p < n; p++) idx[o + p] = t * LMAX + p;
    int e = offs[t + 1];
    if (e > 0) atomicAdd(&Ks[e - 1], 1);   // boundary after row e-1
}

// ---------------- bf16 conversion passes -------------------------------------
__global__ __launch_bounds__(256) void conv_rows(const float* __restrict__ x, int D, int rows,
                                                 unsigned* __restrict__ dst)
{
    int wv = threadIdx.x >> 6, l = threadIdx.x & 63;
    for (int r = blockIdx.x*4 + wv; r < rows; r += gridDim.x*4) {
        const float* xr = x + (size_t)r * D;
        int c = 2*l;
        float a = (c < D)   ? xr[c]   : 0.f;
        float b = (c+1 < D) ? xr[c+1] : 0.f;
        dst[(size_t)r*64 + l] = packbf2(a, b);
    }
}

__global__ __launch_bounds__(256) void conv_lang(const float* __restrict__ P,
    const int* __restrict__ idx, const int* __restrict__ offs, unsigned* __restrict__ dst)
{
    int R = offs[T_STEPS];
    int Rpad = (R + 63) & ~63;
    int wv = threadIdx.x >> 6, l = threadIdx.x & 63;
    for (int r = blockIdx.x*4 + wv; r < Rpad; r += gridDim.x*4) {
        unsigned v = 0;
        if (r < R) {
            const float* xr = P + (size_t)idx[r] * DV;
            float2 p = *(const float2*)(xr + 2*l);
            v = packbf2(p.x, p.y);
        }
        dst[(size_t)r*64 + l] = v;
    }
}

__global__ __launch_bounds__(256) void conv_w(const float* __restrict__ Wv,
    const float* __restrict__ Wi, const float* __restrict__ Wl,
    unsigned* __restrict__ dv, unsigned* __restrict__ di, unsigned* __restrict__ dl)
{
    int mat = blockIdx.y;
    const float* W = mat==0 ? Wv : mat==1 ? Wi : Wl;
    unsigned* dst  = mat==0 ? dv : mat==1 ? di : dl;
    int D = (mat==1) ? DI : DV;
    int wv = threadIdx.x >> 6, l = threadIdx.x & 63;
    int j = blockIdx.x*4 + wv;
    const float* wr = W + (size_t)j * D;
    int c = 2*l;
    float a = (c < D)   ? wr[c]   : 0.f;
    float b = (c+1 < D) ? wr[c+1] : 0.f;
    dst[(size_t)j*64 + l] = packbf2(a, b);
}

// ---------------- all gate GEMMs on matrix cores -----------------------------
// Output layout: G3[row][cell*4 + q] bf16 (gate-interleaved per cell, row
// stride NG) so the seq kernel reads all 4 gate pre-acts of its cell as one
// coalesced 8B load per step.
struct GemmArgs {
    const unsigned* Abf;
    const unsigned* Wb[3];
    const float*    bias[3];
    unsigned short* G[5];
    const int*      offs[2];
};

__global__ __launch_bounds__(256) void gates_mfma(GemmArgs A)
{
    int rowbase0 = blockIdx.x * 64;
    int seg;
    if      (rowbase0 < SEG1) seg = 0;
    else if (rowbase0 < SEG2) seg = 1;
    else if (rowbase0 < SEG3) seg = 2;
    else if (rowbase0 < SEG4) seg = 3;
    else                      seg = 4;
    int segbase = (seg==0)?0:(seg==1)?SEG1:(seg==2)?SEG2:(seg==3)?SEG3:SEG4;
    int wi      = (seg<2)?0:((seg==2)?1:2);
    if (seg >= 3) {
        int R = A.offs[seg-3][T_STEPS];
        if (rowbase0 - segbase >= ((R + 63) & ~63)) return;
    }
    int tid = threadIdx.x, wv = tid >> 6, l = tid & 63;
    int m = l & 15, kg = l >> 4;
    int rowbase = rowbase0 + wv * 16;

    const unsigned* ar = A.Abf + (size_t)(rowbase + m) * 64 + kg * 4;
    uint4 af0 = *(const uint4*)(ar);
    uint4 af1 = *(const uint4*)(ar + 16);
    uint4 af2 = *(const uint4*)(ar + 32);
    uint4 af3 = *(const uint4*)(ar + 48);

    const unsigned* Wb = A.Wb[wi] + (size_t)m * 64 + kg * 4;
    const float* bias = A.bias[wi];

    f32x4 acc[16];
    #pragma unroll
    for (int n0 = 0; n0 < 16; n0++) acc[n0] = (f32x4){0.f,0.f,0.f,0.f};

    #pragma unroll
    for (int n0 = 0; n0 < 16; n0++) {
        const unsigned* wp = Wb + (size_t)n0 * 16 * 64;
        uint4 b0 = *(const uint4*)(wp);
        uint4 b1 = *(const uint4*)(wp + 16);
        uint4 b2 = *(const uint4*)(wp + 32);
        uint4 b3 = *(const uint4*)(wp + 48);
        acc[n0] = __builtin_amdgcn_mfma_f32_16x16x32_bf16(
            __builtin_bit_cast(s16x8, af0), __builtin_bit_cast(s16x8, b0), acc[n0], 0,0,0);
        acc[n0] = __builtin_amdgcn_mfma_f32_16x16x32_bf16(
            __builtin_bit_cast(s16x8, af1), __builtin_bit_cast(s16x8, b1), acc[n0], 0,0,0);
        acc[n0] = __builtin_amdgcn_mfma_f32_16x16x32_bf16(
            __builtin_bit_cast(s16x8, af2), __builtin_bit_cast(s16x8, b2), acc[n0], 0,0,0);
        acc[n0] = __builtin_amdgcn_mfma_f32_16x16x32_bf16(
            __builtin_bit_cast(s16x8, af3), __builtin_bit_cast(s16x8, b3), acc[n0], 0,0,0);
    }

    // gate j = n0*16+m = 64q + 16b + m  (q=n0>>2, b=n0&3) -> cell=16b+m
    unsigned short* Gp = A.G[seg];
    int localrow = rowbase - segbase + kg * 4;
    #pragma unroll
    for (int b = 0; b < 4; b++) {
        int cell = 16*b + m;
        float bj0 = bias[      16*b + m];
        float bj1 = bias[ 64 + 16*b + m];
        float bj2 = bias[128 + 16*b + m];
        float bj3 = bias[192 + 16*b + m];
        #pragma unroll
        for (int r = 0; r < 4; r++) {
            ushort4 o;
            o.x = f2bf(acc[b   ][r] + bj0);
            o.y = f2bf(acc[4+b ][r] + bj1);
            o.z = f2bf(acc[8+b ][r] + bj2);
            o.w = f2bf(acc[12+b][r] + bj3);
            *(ushort4*)(Gp + (size_t)(localrow + r)*NG + cell*4) = o;
        }
    }
}

// ---------------- chunked-parallel recurrence: ONE WAVE per chunk ------------
// lane = cell. Full fp32: weights as 128 v2f pairs (256 VGPRs, unified file
// at 1 wave/EU), h exchanged fp32 through 256B LDS, v_pk_fma_f32 matvec
// (pattern validated in r5). Single wave -> only lgkmcnt(0), no barrier.
struct SeqArgs {
    const unsigned short* gx[5];    // G3 [row][cell*4+q]
    const float*          whh[5];   // fp32 Whh [256][64]
    float*                hout[5];
    const int*            offs[5];  // lang: offsets array (for R + binsearch)
    const int*            ks[5];    // lang: per-row boundary counts
};

__global__ __launch_bounds__(64,1) void seq_kernel(SeqArgs A)
{
    int bid = blockIdx.x;
    int chain, chunk, nch;
    if (bid < 3*CH_VAD) { chain = bid / CH_VAD; chunk = bid % CH_VAD; nch = CH_VAD; }
    else { int b2 = bid - 3*CH_VAD; chain = 3 + b2 / CH_LNG; chunk = b2 % CH_LNG; nch = CH_LNG; }

    const unsigned short* __restrict__ G3 = A.gx[chain];
    const float* __restrict__ Whh = A.whh[chain];
    float* __restrict__ hout = A.hout[chain];
    const int* __restrict__ offs = A.offs[chain];
    const int* __restrict__ Ks = A.ks[chain];
    const bool isLang = (offs != nullptr);

    const int R = isLang ? offs[T_STEPS] : T_STEPS;
    const int len = ((R + nch - 1) / nch + 3) & ~3;
    const int S = chunk * len;
    if (chunk > 0 && S >= R) return;
    const int E = min(S + len, R);
    const int start = (S > WARM) ? (S - WARM) : 0;

    int cell = threadIdx.x;

    // tptr = #timesteps emitted before row S  (= #{t: offs[t+1] <= S})
    int tptr = 0;
    if (isLang) {
        int lo = 1, hi = T_STEPS + 1;
        while (lo < hi) {
            int mid = (lo + hi) >> 1;
            if (offs[mid] <= S) lo = mid + 1; else hi = mid;
        }
        tptr = lo - 1;
    }

    // resident fp32 weights: wreg[q][p] = Whh[q*64+cell][2p..2p+1]
    v2f wreg[4][32];
    #pragma unroll
    for (int q = 0; q < 4; q++) {
        const v2f* wrow = (const v2f*)(Whh + (size_t)(q*HH + cell)*HH);
        #pragma unroll
        for (int p = 0; p < 32; p++) wreg[q][p] = wrow[p];
    }

    __shared__ __align__(16) float hl[HH];
    hl[cell] = 0.f;
    asm volatile("s_waitcnt lgkmcnt(0)" ::: "memory");

    float c = 0.f;
    const float kSig = -1.44269504088896340736f;  // -log2(e)
    const float kTan =  2.88539008177792681472f;  //  2*log2(e)

    if (isLang && chunk == 0)
        for (int i = 0; i < tptr; i++) hout[(size_t)i*HH + cell] = 0.f;

    const unsigned short* grow = G3 + (size_t)start * NG + (size_t)cell * 4;
    auto ldg = [&](int r){ return *(const uint2*)(grow + (size_t)r * NG); };
    int rix = start;
    auto ldk = [&](int r){ return isLang ? Ks[rix + r] : 0; };

    uint2 g0 = ldg(0), g1 = ldg(1), g2 = ldg(2), g3 = ldg(3);
    int   k0 = ldk(0), k1 = ldk(1), k2 = ldk(2), k3 = ldk(3);

    const float4* h4 = (const float4*)hl;   // 16 x float4 = 64 h values

    auto step = [&](uint2 gx, int kc, int row) {
        v2f acc2[4];
        acc2[0] = (v2f){ __uint_as_float(gx.x << 16),          0.f };
        acc2[1] = (v2f){ __uint_as_float(gx.x & 0xffff0000u),  0.f };
        acc2[2] = (v2f){ __uint_as_float(gx.y << 16),          0.f };
        acc2[3] = (v2f){ __uint_as_float(gx.y & 0xffff0000u),  0.f };
        #pragma unroll
        for (int t = 0; t < 16; t++) {
            float4 hv = h4[t];
            v2f lo; lo.x = hv.x; lo.y = hv.y;
            v2f hi; hi.x = hv.z; hi.y = hv.w;
            pk_fma(acc2[0], wreg[0][2*t],   lo);
            pk_fma(acc2[1], wreg[1][2*t],   lo);
            pk_fma(acc2[2], wreg[2][2*t],   lo);
            pk_fma(acc2[3], wreg[3][2*t],   lo);
            pk_fma(acc2[0], wreg[0][2*t+1], hi);
            pk_fma(acc2[1], wreg[1][2*t+1], hi);
            pk_fma(acc2[2], wreg[2][2*t+1], hi);
            pk_fma(acc2[3], wreg[3][2*t+1], hi);
        }
        float a0 = acc2[0].x + acc2[0].y;
        float a1 = acc2[1].x + acc2[1].y;
        float a2 = acc2[2].x + acc2[2].y;
        float a3 = acc2[3].x + acc2[3].y;
        float i_ = fast_rcp(1.f + fast_exp2(a0 * kSig));
        float f_ = fast_rcp(1.f + fast_exp2(a1 * kSig));
        float g_ = fmaf(-2.f, fast_rcp(1.f + fast_exp2(a2 * kTan)), 1.f);
        float o_ = fast_rcp(1.f + fast_exp2(a3 * kSig));
        c = fmaf(f_, c, i_ * g_);
        float tc = fmaf(-2.f, fast_rcp(1.f + fast_exp2(c * kTan)), 1.f);
        float h = o_ * tc;
        hl[cell] = h;
        bool em = (row >= S) & (row < E);
        if (!isLang) {
            if (em) hout[(size_t)row*HH + cell] = h;
        } else if (em) {
            for (int i = 0; i < kc; i++)
                hout[(size_t)(tptr + i)*HH + cell] = h;
            tptr += kc;
        }
        asm volatile("s_waitcnt lgkmcnt(0)" ::: "memory");
    };

    int nblk = (E - start + 3) >> 2;
    for (int it = 0; it < nblk; ++it) {
        uint2 n0 = ldg(4), n1 = ldg(5), n2 = ldg(6), n3 = ldg(7);
        int   m0 = ldk(4), m1 = ldk(5), m2 = ldk(6), m3 = ldk(7);
        step(g0, k0, rix + 0);
        step(g1, k1, rix + 1);
        step(g2, k2, rix + 2);
        step(g3, k3, rix + 3);
        g0 = n0; g1 = n1; g2 = n2; g3 = n3;
        k0 = m0; k1 = m1; k2 = m2; k3 = m3;
        grow += 4 * NG;
        rix  += 4;
    }
}

// ---------------- final: alpha[t] = sigmoid(fc_w . concat + fc_b) ------------
__global__ __launch_bounds__(256) void final_fc(const float* __restrict__ hA,
    const float* __restrict__ hB, const float* __restrict__ hI,
    const float* __restrict__ hpa, const float* __restrict__ hpb,
    const float* __restrict__ fcw, const float* __restrict__ fcb,
    float* __restrict__ out)
{
    int t = blockIdx.x * blockDim.x + threadIdx.x;
    if (t >= T_STEPS) return;
    float acc = fcb[0];
    const float* hs0 = hA  + (size_t)t*HH;
    const float* hs1 = hB  + (size_t)t*HH;
    const float* hs2 = hI  + (size_t)t*HH;
    const float* hs3 = hpa + (size_t)t*HH;
    const float* hs4 = hpb + (size_t)t*HH;
    #pragma unroll
    for (int k = 0; k < HH; k++) acc = fmaf(hs0[k], fcw[0*HH+k], acc);
    #pragma unroll
    for (int k = 0; k < HH; k++) acc = fmaf(hs1[k], fcw[1*HH+k], acc);
    #pragma unroll
    for (int k = 0; k < HH; k++) acc = fmaf(hs2[k], fcw[2*HH+k], acc);
    #pragma unroll
    for (int k = 0; k < HH; k++) acc = fmaf(hs3[k], fcw[3*HH+k], acc);
    #pragma unroll
    for (int k = 0; k < HH; k++) acc = fmaf(hs4[k], fcw[4*HH+k], acc);
    out[t] = fast_rcp(1.f + fast_exp2(acc * -1.44269504088896340736f));
}

// ---------------- launch -----------------------------------------------------
extern "C" void kernel_launch(void* const* d_in, const int* in_sizes, int n_in,
                              void* d_out, int out_size, void* d_ws, size_t ws_size,
                              hipStream_t stream)
{
    const float* xA      = (const float*)d_in[0];
    const float* xB      = (const float*)d_in[1];
    const float* img     = (const float*)d_in[2];
    const float* PA      = (const float*)d_in[3];
    const float* PB      = (const float*)d_in[4];
    const int*   lenA    = (const int*)d_in[5];
    const int*   lenB    = (const int*)d_in[6];
    const float* Wih_vad = (const float*)d_in[7];
    const float* Whh_vad = (const float*)d_in[8];
    const float* b_vad   = (const float*)d_in[9];
    const float* Wih_img = (const float*)d_in[10];
    const float* Whh_img = (const float*)d_in[11];
    const float* b_img   = (const float*)d_in[12];
    const float* Wih_lng = (const float*)d_in[13];
    const float* Whh_lng = (const float*)d_in[14];
    const float* b_lng   = (const float*)d_in[15];
    const float* fc_w    = (const float*)d_in[16];
    const float* fc_b    = (const float*)d_in[17];
    float* out = (float*)d_out;

    char* ws = (char*)d_ws;
    size_t off = 0;
    auto alloc = [&](size_t bytes) -> void* {
        void* p = ws + off;
        off += (bytes + 255) & ~(size_t)255;
        return p;
    };
    int* offsA = (int*)alloc((T_STEPS+1)*sizeof(int));
    int* offsB = (int*)alloc((T_STEPS+1)*sizeof(int));
    int* idxA  = (int*)alloc((size_t)SMAX*sizeof(int));
    int* idxB  = (int*)alloc((size_t)SMAX*sizeof(int));
    int* KsA   = (int*)alloc((size_t)KS_WORDS*sizeof(int));   // contiguous with KsB
    int* KsB   = (int*)alloc((size_t)KS_WORDS*sizeof(int));
    unsigned short* GvA = (unsigned short*)alloc((size_t)GD_ROWS*NG*2);
    unsigned short* GvB = (unsigned short*)alloc((size_t)GD_ROWS*NG*2);
    unsigned short* Gim = (unsigned short*)alloc((size_t)GD_ROWS*NG*2);
    unsigned short* GlA = (unsigned short*)alloc((size_t)GL_ROWS*NG*2);
    unsigned short* GlB = (unsigned short*)alloc((size_t)GL_ROWS*NG*2);
    float* hA  = (float*)alloc((size_t)T_STEPS*HH*sizeof(float));
    float* hB  = (float*)alloc((size_t)T_STEPS*HH*sizeof(float));
    float* hI  = (float*)alloc((size_t)T_STEPS*HH*sizeof(float));
    float* hpa = (float*)alloc((size_t)T_STEPS*HH*sizeof(float));
    float* hpb = (float*)alloc((size_t)T_STEPS*HH*sizeof(float));
    unsigned* Abf  = (unsigned*)alloc((size_t)TOTROWS*64*sizeof(unsigned));
    unsigned* Wbf0 = (unsigned*)alloc((size_t)NG*64*sizeof(unsigned));
    unsigned* Wbf1 = (unsigned*)alloc((size_t)NG*64*sizeof(unsigned));
    unsigned* Wbf2 = (unsigned*)alloc((size_t)NG*64*sizeof(unsigned));
    (void)ws_size; (void)in_sizes; (void)n_in; (void)out_size;

    scan_kernel<<<2, 64, 0, stream>>>(lenA, lenB, offsA, offsB);
    hipMemsetAsync(KsA, 0, 2*(size_t)KS_WORDS*sizeof(int), stream);
    build_meta<<<(T_STEPS+255)/256, 256, 0, stream>>>(lenA, offsA, idxA, KsA);
    build_meta<<<(T_STEPS+255)/256, 256, 0, stream>>>(lenB, offsB, idxB, KsB);

    conv_w<<<dim3(64,3), 256, 0, stream>>>(Wih_vad, Wih_img, Wih_lng, Wbf0, Wbf1, Wbf2);
    conv_rows<<<512, 256, 0, stream>>>(xA,  DV, T_STEPS, Abf);
    conv_rows<<<512, 256, 0, stream>>>(xB,  DV, T_STEPS, Abf + (size_t)SEG1*64);
    conv_rows<<<512, 256, 0, stream>>>(img, DI, T_STEPS, Abf + (size_t)SEG2*64);
    conv_lang<<<1024, 256, 0, stream>>>(PA, idxA, offsA, Abf + (size_t)SEG3*64);
    conv_lang<<<1024, 256, 0, stream>>>(PB, idxB, offsB, Abf + (size_t)SEG4*64);

    GemmArgs GA;
    GA.Abf = Abf;
    GA.Wb[0]=Wbf0; GA.Wb[1]=Wbf1; GA.Wb[2]=Wbf2;
    GA.bias[0]=b_vad; GA.bias[1]=b_img; GA.bias[2]=b_lng;
    GA.G[0]=GvA; GA.G[1]=GvB; GA.G[2]=Gim; GA.G[3]=GlA; GA.G[4]=GlB;
    GA.offs[0]=offsA; GA.offs[1]=offsB;
    gates_mfma<<<TOTROWS/64, 256, 0, stream>>>(GA);

    SeqArgs A;
    A.gx[0]=GvA;  A.gx[1]=GvB;  A.gx[2]=Gim;  A.gx[3]=GlA;  A.gx[4]=GlB;
    A.whh[0]=Whh_vad; A.whh[1]=Whh_vad; A.whh[2]=Whh_img; A.whh[3]=Whh_lng; A.whh[4]=Whh_lng;
    A.hout[0]=hA; A.hout[1]=hB; A.hout[2]=hI; A.hout[3]=hpa; A.hout[4]=hpb;
    A.offs[0]=nullptr; A.offs[1]=nullptr; A.offs[2]=nullptr; A.offs[3]=offsA; A.offs[4]=offsB;
    A.ks[0]=nullptr; A.ks[1]=nullptr; A.ks[2]=nullptr; A.ks[3]=KsA; A.ks[4]=KsB;
    seq_kernel<<<NBLK_SEQ, 64, 0, stream>>>(A);

    final_fc<<<(T_STEPS+255)/256, 256, 0, stream>>>(hA, hB, hI, hpa, hpb, fc_w, fc_b, out);
}

// Round 10
// 411.967 us; speedup vs baseline: 1.0158x; 1.0158x over previous
//
#include <hip/hip_runtime.h>
#include <hip/hip_bf16.h>

#define T_STEPS 8192
#define LMAX 12
#define DV 128
#define DI 65
#define NG 256   // 4*H
#define HH 64

#define SMAX (T_STEPS * LMAX)        // 98304 worst-case lang rows
#define GD_ROWS (T_STEPS + 64)       // dense G3 rows (pad for prefetch)
#define GL_ROWS (SMAX + 64)          // lang G3 rows
#define KS_WORDS (SMAX + 64)
#define WARM 64                      // validated r6
#define CH_VAD 170
#define CH_LNG 768
#define NBLK_SEQ (3*CH_VAD + 2*CH_LNG)   // 2046

// Abf segment row offsets (all 64-aligned)
#define SEG1 8192
#define SEG2 16384
#define SEG3 24576
#define SEG4 122880
#define TOTROWS 221184

typedef short s16x8 __attribute__((ext_vector_type(8)));
typedef float f32x4 __attribute__((ext_vector_type(4)));
typedef float v2f __attribute__((ext_vector_type(2)));

__device__ __forceinline__ void pk_fma(v2f& d, v2f a, v2f b){
    asm("v_pk_fma_f32 %0, %1, %2, %0" : "+v"(d) : "v"(a), "v"(b));
}

#if __has_builtin(__builtin_amdgcn_exp2f)
__device__ __forceinline__ float fast_exp2(float x){ return __builtin_amdgcn_exp2f(x); }
#else
__device__ __forceinline__ float fast_exp2(float x){ return exp2f(x); }
#endif
#if __has_builtin(__builtin_amdgcn_rcpf)
__device__ __forceinline__ float fast_rcp(float x){ return __builtin_amdgcn_rcpf(x); }
#else
__device__ __forceinline__ float fast_rcp(float x){ return 1.0f/x; }
#endif

__device__ __forceinline__ unsigned short f2bf(float f){
    unsigned u = __float_as_uint(f);
    unsigned r = (u + 0x7fffu + ((u>>16)&1u)) >> 16;   // RNE
    return (unsigned short)r;
}
__device__ __forceinline__ unsigned packbf2(float a, float b){
    return (unsigned)f2bf(a) | ((unsigned)f2bf(b) << 16);
}

// ---------------- prefix scan of lens -> exclusive offsets (+ total at [T]) --
__global__ void scan_kernel(const int* __restrict__ lenA, const int* __restrict__ lenB,
                            int* __restrict__ offsA, int* __restrict__ offsB)
{
    const int* len = blockIdx.x ? lenB : lenA;
    int* offs = blockIdx.x ? offsB : offsA;
    int lane = threadIdx.x;   // 64 threads
    int carry = 0;
    for (int base = 0; base < T_STEPS; base += 64) {
        int x = len[base + lane];
        int v = x;
        #pragma unroll
        for (int d = 1; d < 64; d <<= 1) {
            int u = __shfl_up(v, d);
            if (lane >= d) v += u;
        }
        offs[base + lane] = carry + v - x;     // exclusive
        carry += __shfl(v, 63);
    }
    if (lane == 0) offs[T_STEPS] = carry;
}

// ---- build compacted-row -> source-row map, and per-row boundary counts ----
__global__ void build_meta(const int* __restrict__ len, const int* __restrict__ offs,
                           int* __restrict__ idx, int* __restrict__ Ks)
{
    int t = blockIdx.x * blockDim.x + threadIdx.x;
    if (t >= T_STEPS) return;
    int n = len[t];
    int o = offs[t];
    for (int p = 0; p < n; p++) idx[o + p] = t * LMAX + p;
    int e = offs[t + 1];
    if (e > 0) atomicAdd(&Ks[e - 1], 1);   // boundary after row e-1
}

// ---------------- bf16 conversion passes -------------------------------------
__global__ __launch_bounds__(256) void conv_rows(const float* __restrict__ x, int D, int rows,
                                                 unsigned* __restrict__ dst)
{
    int wv = threadIdx.x >> 6, l = threadIdx.x & 63;
    for (int r = blockIdx.x*4 + wv; r < rows; r += gridDim.x*4) {
        const float* xr = x + (size_t)r * D;
        int c = 2*l;
        float a = (c < D)   ? xr[c]   : 0.f;
        float b = (c+1 < D) ? xr[c+1] : 0.f;
        dst[(size_t)r*64 + l] = packbf2(a, b);
    }
}

__global__ __launch_bounds__(256) void conv_lang(const float* __restrict__ P,
    const int* __restrict__ idx, const int* __restrict__ offs, unsigned* __restrict__ dst)
{
    int R = offs[T_STEPS];
    int Rpad = (R + 63) & ~63;
    int wv = threadIdx.x >> 6, l = threadIdx.x & 63;
    for (int r = blockIdx.x*4 + wv; r < Rpad; r += gridDim.x*4) {
        unsigned v = 0;
        if (r < R) {
            const float* xr = P + (size_t)idx[r] * DV;
            float2 p = *(const float2*)(xr + 2*l);
            v = packbf2(p.x, p.y);
        }
        dst[(size_t)r*64 + l] = v;
    }
}

__global__ __launch_bounds__(256) void conv_w(const float* __restrict__ Wv,
    const float* __restrict__ Wi, const float* __restrict__ Wl,
    unsigned* __restrict__ dv, unsigned* __restrict__ di, unsigned* __restrict__ dl)
{
    int mat = blockIdx.y;
    const float* W = mat==0 ? Wv : mat==1 ? Wi : Wl;
    unsigned* dst  = mat==0 ? dv : mat==1 ? di : dl;
    int D = (mat==1) ? DI : DV;
    int wv = threadIdx.x >> 6, l = threadIdx.x & 63;
    int j = blockIdx.x*4 + wv;
    const float* wr = W + (size_t)j * D;
    int c = 2*l;
    float a = (c < D)   ? wr[c]   : 0.f;
    float b = (c+1 < D) ? wr[c+1] : 0.f;
    dst[(size_t)j*64 + l] = packbf2(a, b);
}

// ---------------- all gate GEMMs on matrix cores -----------------------------
struct GemmArgs {
    const unsigned* Abf;
    const unsigned* Wb[3];
    const float*    bias[3];
    unsigned short* G[5];
    const int*      offs[2];
};

__global__ __launch_bounds__(256) void gates_mfma(GemmArgs A)
{
    int rowbase0 = blockIdx.x * 64;
    int seg;
    if      (rowbase0 < SEG1) seg = 0;
    else if (rowbase0 < SEG2) seg = 1;
    else if (rowbase0 < SEG3) seg = 2;
    else if (rowbase0 < SEG4) seg = 3;
    else                      seg = 4;
    int segbase = (seg==0)?0:(seg==1)?SEG1:(seg==2)?SEG2:(seg==3)?SEG3:SEG4;
    int wi      = (seg<2)?0:((seg==2)?1:2);
    if (seg >= 3) {
        int R = A.offs[seg-3][T_STEPS];
        if (rowbase0 - segbase >= ((R + 63) & ~63)) return;
    }
    int tid = threadIdx.x, wv = tid >> 6, l = tid & 63;
    int m = l & 15, kg = l >> 4;
    int rowbase = rowbase0 + wv * 16;

    const unsigned* ar = A.Abf + (size_t)(rowbase + m) * 64 + kg * 4;
    uint4 af0 = *(const uint4*)(ar);
    uint4 af1 = *(const uint4*)(ar + 16);
    uint4 af2 = *(const uint4*)(ar + 32);
    uint4 af3 = *(const uint4*)(ar + 48);

    const unsigned* Wb = A.Wb[wi] + (size_t)m * 64 + kg * 4;
    const float* bias = A.bias[wi];

    f32x4 acc[16];
    #pragma unroll
    for (int n0 = 0; n0 < 16; n0++) acc[n0] = (f32x4){0.f,0.f,0.f,0.f};

    #pragma unroll
    for (int n0 = 0; n0 < 16; n0++) {
        const unsigned* wp = Wb + (size_t)n0 * 16 * 64;
        uint4 b0 = *(const uint4*)(wp);
        uint4 b1 = *(const uint4*)(wp + 16);
        uint4 b2 = *(const uint4*)(wp + 32);
        uint4 b3 = *(const uint4*)(wp + 48);
        acc[n0] = __builtin_amdgcn_mfma_f32_16x16x32_bf16(
            __builtin_bit_cast(s16x8, af0), __builtin_bit_cast(s16x8, b0), acc[n0], 0,0,0);
        acc[n0] = __builtin_amdgcn_mfma_f32_16x16x32_bf16(
            __builtin_bit_cast(s16x8, af1), __builtin_bit_cast(s16x8, b1), acc[n0], 0,0,0);
        acc[n0] = __builtin_amdgcn_mfma_f32_16x16x32_bf16(
            __builtin_bit_cast(s16x8, af2), __builtin_bit_cast(s16x8, b2), acc[n0], 0,0,0);
        acc[n0] = __builtin_amdgcn_mfma_f32_16x16x32_bf16(
            __builtin_bit_cast(s16x8, af3), __builtin_bit_cast(s16x8, b3), acc[n0], 0,0,0);
    }

    // gate j = n0*16+m = 64q + 16b + m  (q=n0>>2, b=n0&3) -> cell=16b+m
    unsigned short* Gp = A.G[seg];
    int localrow = rowbase - segbase + kg * 4;
    #pragma unroll
    for (int b = 0; b < 4; b++) {
        int cell = 16*b + m;
        float bj0 = bias[      16*b + m];
        float bj1 = bias[ 64 + 16*b + m];
        float bj2 = bias[128 + 16*b + m];
        float bj3 = bias[192 + 16*b + m];
        #pragma unroll
        for (int r = 0; r < 4; r++) {
            ushort4 o;
            o.x = f2bf(acc[b   ][r] + bj0);
            o.y = f2bf(acc[4+b ][r] + bj1);
            o.z = f2bf(acc[8+b ][r] + bj2);
            o.w = f2bf(acc[12+b][r] + bj3);
            *(ushort4*)(Gp + (size_t)(localrow + r)*NG + cell*4) = o;
        }
    }
}

// ---------------- chunked-parallel recurrence: ONE WAVE per chunk ------------
// lane = cell. Weights as 128 NAMED v2f variables (no array -> no spill
// excuse); fp32 pk_fma matvec; h through 256B LDS, same-wave DS ordering
// (no manual waits, no barrier).
struct SeqArgs {
    const unsigned short* gx[5];    // G3 [row][cell*4+q]
    const float*          whh[5];   // fp32 Whh [256][64]
    float*                hout[5];
    const int*            offs[5];
    const int*            ks[5];
};

#define XP32(M, q) M(q,0) M(q,1) M(q,2) M(q,3) M(q,4) M(q,5) M(q,6) M(q,7) \
  M(q,8) M(q,9) M(q,10) M(q,11) M(q,12) M(q,13) M(q,14) M(q,15) M(q,16) M(q,17) \
  M(q,18) M(q,19) M(q,20) M(q,21) M(q,22) M(q,23) M(q,24) M(q,25) M(q,26) M(q,27) \
  M(q,28) M(q,29) M(q,30) M(q,31)
#define DECLW(q,p) v2f W##q##_##p;
#define LOADW(q,p) W##q##_##p = wrow##q[p];

#define MACT(t,P0,P1) { float4 hv = h4[t]; \
  v2f lo; lo.x = hv.x; lo.y = hv.y; v2f hi; hi.x = hv.z; hi.y = hv.w; \
  pk_fma(acc2_0, W0_##P0, lo); pk_fma(acc2_1, W1_##P0, lo); \
  pk_fma(acc2_2, W2_##P0, lo); pk_fma(acc2_3, W3_##P0, lo); \
  pk_fma(acc2_0, W0_##P1, hi); pk_fma(acc2_1, W1_##P1, hi); \
  pk_fma(acc2_2, W2_##P1, hi); pk_fma(acc2_3, W3_##P1, hi); }

#define DO_STEP(gx, kc, row) do { \
  v2f acc2_0; acc2_0.x = __uint_as_float((gx).x << 16);         acc2_0.y = 0.f; \
  v2f acc2_1; acc2_1.x = __uint_as_float((gx).x & 0xffff0000u); acc2_1.y = 0.f; \
  v2f acc2_2; acc2_2.x = __uint_as_float((gx).y << 16);         acc2_2.y = 0.f; \
  v2f acc2_3; acc2_3.x = __uint_as_float((gx).y & 0xffff0000u); acc2_3.y = 0.f; \
  MACT(0,0,1) MACT(1,2,3) MACT(2,4,5) MACT(3,6,7) \
  MACT(4,8,9) MACT(5,10,11) MACT(6,12,13) MACT(7,14,15) \
  MACT(8,16,17) MACT(9,18,19) MACT(10,20,21) MACT(11,22,23) \
  MACT(12,24,25) MACT(13,26,27) MACT(14,28,29) MACT(15,30,31) \
  float a0 = acc2_0.x + acc2_0.y; \
  float a1 = acc2_1.x + acc2_1.y; \
  float a2 = acc2_2.x + acc2_2.y; \
  float a3 = acc2_3.x + acc2_3.y; \
  float i_ = fast_rcp(1.f + fast_exp2(a0 * kSig)); \
  float f_ = fast_rcp(1.f + fast_exp2(a1 * kSig)); \
  float g_ = fmaf(-2.f, fast_rcp(1.f + fast_exp2(a2 * kTan)), 1.f); \
  float o_ = fast_rcp(1.f + fast_exp2(a3 * kSig)); \
  c = fmaf(f_, c, i_ * g_); \
  float tc = fmaf(-2.f, fast_rcp(1.f + fast_exp2(c * kTan)), 1.f); \
  float h = o_ * tc; \
  hl[cell] = h; \
  bool em = ((row) >= S) & ((row) < E); \
  if (!isLang) { if (em) hout[(size_t)(row)*HH + cell] = h; } \
  else if (em) { \
    for (int i = 0; i < (kc); i++) hout[(size_t)(tptr + i)*HH + cell] = h; \
    tptr += (kc); \
  } \
} while(0)

__global__ __launch_bounds__(64,1) void seq_kernel(SeqArgs A)
{
    int bid = blockIdx.x;
    int chain, chunk, nch;
    if (bid < 3*CH_VAD) { chain = bid / CH_VAD; chunk = bid % CH_VAD; nch = CH_VAD; }
    else { int b2 = bid - 3*CH_VAD; chain = 3 + b2 / CH_LNG; chunk = b2 % CH_LNG; nch = CH_LNG; }

    const unsigned short* __restrict__ G3 = A.gx[chain];
    const float* __restrict__ Whh = A.whh[chain];
    float* __restrict__ hout = A.hout[chain];
    const int* __restrict__ offs = A.offs[chain];
    const int* __restrict__ Ks = A.ks[chain];
    const bool isLang = (offs != nullptr);

    const int R = isLang ? offs[T_STEPS] : T_STEPS;
    const int len = ((R + nch - 1) / nch + 3) & ~3;
    const int S = chunk * len;
    if (chunk > 0 && S >= R) return;
    const int E = min(S + len, R);
    const int start = (S > WARM) ? (S - WARM) : 0;

    int cell = threadIdx.x;

    int tptr = 0;
    if (isLang) {
        int lo = 1, hi = T_STEPS + 1;
        while (lo < hi) {
            int mid = (lo + hi) >> 1;
            if (offs[mid] <= S) lo = mid + 1; else hi = mid;
        }
        tptr = lo - 1;
    }

    const v2f* wrow0 = (const v2f*)(Whh + (size_t)(0*HH + cell)*HH);
    const v2f* wrow1 = (const v2f*)(Whh + (size_t)(1*HH + cell)*HH);
    const v2f* wrow2 = (const v2f*)(Whh + (size_t)(2*HH + cell)*HH);
    const v2f* wrow3 = (const v2f*)(Whh + (size_t)(3*HH + cell)*HH);
    XP32(DECLW,0) XP32(DECLW,1) XP32(DECLW,2) XP32(DECLW,3)
    XP32(LOADW,0) XP32(LOADW,1) XP32(LOADW,2) XP32(LOADW,3)

    __shared__ __align__(16) float hl[HH];
    hl[cell] = 0.f;

    float c = 0.f;
    const float kSig = -1.44269504088896340736f;  // -log2(e)
    const float kTan =  2.88539008177792681472f;  //  2*log2(e)

    if (isLang && chunk == 0)
        for (int i = 0; i < tptr; i++) hout[(size_t)i*HH + cell] = 0.f;

    const unsigned short* grow = G3 + (size_t)start * NG + (size_t)cell * 4;
    auto ldg = [&](int r){ return *(const uint2*)(grow + (size_t)r * NG); };
    int rix = start;
    auto ldk = [&](int r){ return isLang ? Ks[rix + r] : 0; };

    uint2 g0 = ldg(0), g1 = ldg(1), g2 = ldg(2), g3 = ldg(3);
    int   k0 = ldk(0), k1 = ldk(1), k2 = ldk(2), k3 = ldk(3);

    const float4* h4 = (const float4*)hl;

    int nblk = (E - start + 3) >> 2;
    for (int it = 0; it < nblk; ++it) {
        uint2 n0 = ldg(4), n1 = ldg(5), n2 = ldg(6), n3 = ldg(7);
        int   m0 = ldk(4), m1 = ldk(5), m2 = ldk(6), m3 = ldk(7);
        DO_STEP(g0, k0, rix + 0);
        DO_STEP(g1, k1, rix + 1);
        DO_STEP(g2, k2, rix + 2);
        DO_STEP(g3, k3, rix + 3);
        g0 = n0; g1 = n1; g2 = n2; g3 = n3;
        k0 = m0; k1 = m1; k2 = m2; k3 = m3;
        grow += 4 * NG;
        rix  += 4;
    }
}

// ---------------- final: alpha[t] = sigmoid(fc_w . concat + fc_b) ------------
__global__ __launch_bounds__(256) void final_fc(const float* __restrict__ hA,
    const float* __restrict__ hB, const float* __restrict__ hI,
    const float* __restrict__ hpa, const float* __restrict__ hpb,
    const float* __restrict__ fcw, const float* __restrict__ fcb,
    float* __restrict__ out)
{
    int t = blockIdx.x * blockDim.x + threadIdx.x;
    if (t >= T_STEPS) return;
    float acc = fcb[0];
    const float* hs0 = hA  + (size_t)t*HH;
    const float* hs1 = hB  + (size_t)t*HH;
    const float* hs2 = hI  + (size_t)t*HH;
    const float* hs3 = hpa + (size_t)t*HH;
    const float* hs4 = hpb + (size_t)t*HH;
    #pragma unroll
    for (int k = 0; k < HH; k++) acc = fmaf(hs0[k], fcw[0*HH+k], acc);
    #pragma unroll
    for (int k = 0; k < HH; k++) acc = fmaf(hs1[k], fcw[1*HH+k], acc);
    #pragma unroll
    for (int k = 0; k < HH; k++) acc = fmaf(hs2[k], fcw[2*HH+k], acc);
    #pragma unroll
    for (int k = 0; k < HH; k++) acc = fmaf(hs3[k], fcw[3*HH+k], acc);
    #pragma unroll
    for (int k = 0; k < HH; k++) acc = fmaf(hs4[k], fcw[4*HH+k], acc);
    out[t] = fast_rcp(1.f + fast_exp2(acc * -1.44269504088896340736f));
}

// ---------------- launch -----------------------------------------------------
extern "C" void kernel_launch(void* const* d_in, const int* in_sizes, int n_in,
                              void* d_out, int out_size, void* d_ws, size_t ws_size,
                              hipStream_t stream)
{
    const float* xA      = (const float*)d_in[0];
    const float* xB      = (const float*)d_in[1];
    const float* img     = (const float*)d_in[2];
    const float* PA      = (const float*)d_in[3];
    const float* PB      = (const float*)d_in[4];
    const int*   lenA    = (const int*)d_in[5];
    const int*   lenB    = (const int*)d_in[6];
    const float* Wih_vad = (const float*)d_in[7];
    const float* Whh_vad = (const float*)d_in[8];
    const float* b_vad   = (const float*)d_in[9];
    const float* Wih_img = (const float*)d_in[10];
    const float* Whh_img = (const float*)d_in[11];
    const float* b_img   = (const float*)d_in[12];
    const float* Wih_lng = (const float*)d_in[13];
    const float* Whh_lng = (const float*)d_in[14];
    const float* b_lng   = (const float*)d_in[15];
    const float* fc_w    = (const float*)d_in[16];
    const float* fc_b    = (const float*)d_in[17];
    float* out = (float*)d_out;

    char* ws = (char*)d_ws;
    size_t off = 0;
    auto alloc = [&](size_t bytes) -> void* {
        void* p = ws + off;
        off += (bytes + 255) & ~(size_t)255;
        return p;
    };
    int* offsA = (int*)alloc((T_STEPS+1)*sizeof(int));
    int* offsB = (int*)alloc((T_STEPS+1)*sizeof(int));
    int* idxA  = (int*)alloc((size_t)SMAX*sizeof(int));
    int* idxB  = (int*)alloc((size_t)SMAX*sizeof(int));
    int* KsA   = (int*)alloc((size_t)KS_WORDS*sizeof(int));   // contiguous with KsB
    int* KsB   = (int*)alloc((size_t)KS_WORDS*sizeof(int));
    unsigned short* GvA = (unsigned short*)alloc((size_t)GD_ROWS*NG*2);
    unsigned short* GvB = (unsigned short*)alloc((size_t)GD_ROWS*NG*2);
    unsigned short* Gim = (unsigned short*)alloc((size_t)GD_ROWS*NG*2);
    unsigned short* GlA = (unsigned short*)alloc((size_t)GL_ROWS*NG*2);
    unsigned short* GlB = (unsigned short*)alloc((size_t)GL_ROWS*NG*2);
    float* hA  = (float*)alloc((size_t)T_STEPS*HH*sizeof(float));
    float* hB  = (float*)alloc((size_t)T_STEPS*HH*sizeof(float));
    float* hI  = (float*)alloc((size_t)T_STEPS*HH*sizeof(float));
    float* hpa = (float*)alloc((size_t)T_STEPS*HH*sizeof(float));
    float* hpb = (float*)alloc((size_t)T_STEPS*HH*sizeof(float));
    unsigned* Abf  = (unsigned*)alloc((size_t)TOTROWS*64*sizeof(unsigned));
    unsigned* Wbf0 = (unsigned*)alloc((size_t)NG*64*sizeof(unsigned));
    unsigned* Wbf1 = (unsigned*)alloc((size_t)NG*64*sizeof(unsigned));
    unsigned* Wbf2 = (unsigned*)alloc((size_t)NG*64*sizeof(unsigned));
    (void)ws_size; (void)in_sizes; (void)n_in; (void)out_size;

    scan_kernel<<<2, 64, 0, stream>>>(lenA, lenB, offsA, offsB);
    hipMemsetAsync(KsA, 0, 2*(size_t)KS_WORDS*sizeof(int), stream);
    build_meta<<<(T_STEPS+255)/256, 256, 0, stream>>>(lenA, offsA, idxA, KsA);
    build_meta<<<(T_STEPS+255)/256, 256, 0, stream>>>(lenB, offsB, idxB, KsB);

    conv_w<<<dim3(64,3), 256, 0, stream>>>(Wih_vad, Wih_img, Wih_lng, Wbf0, Wbf1, Wbf2);
    conv_rows<<<512, 256, 0, stream>>>(xA,  DV, T_STEPS, Abf);
    conv_rows<<<512, 256, 0, stream>>>(xB,  DV, T_STEPS, Abf + (size_t)SEG1*64);
    conv_rows<<<512, 256, 0, stream>>>(img, DI, T_STEPS, Abf + (size_t)SEG2*64);
    conv_lang<<<1024, 256, 0, stream>>>(PA, idxA, offsA, Abf + (size_t)SEG3*64);
    conv_lang<<<1024, 256, 0, stream>>>(PB, idxB, offsB, Abf + (size_t)SEG4*64);

    GemmArgs GA;
    GA.Abf = Abf;
    GA.Wb[0]=Wbf0; GA.Wb[1]=Wbf1; GA.Wb[2]=Wbf2;
    GA.bias[0]=b_vad; GA.bias[1]=b_img; GA.bias[2]=b_lng;
    GA.G[0]=GvA; GA.G[1]=GvB; GA.G[2]=Gim; GA.G[3]=GlA; GA.G[4]=GlB;
    GA.offs[0]=offsA; GA.offs[1]=offsB;
    gates_mfma<<<TOTROWS/64, 256, 0, stream>>>(GA);

    SeqArgs A;
    A.gx[0]=GvA;  A.gx[1]=GvB;  A.gx[2]=Gim;  A.gx[3]=GlA;  A.gx[4]=GlB;
    A.whh[0]=Whh_vad; A.whh[1]=Whh_vad; A.whh[2]=Whh_img; A.whh[3]=Whh_lng; A.whh[4]=Whh_lng;
    A.hout[0]=hA; A.hout[1]=hB; A.hout[2]=hI; A.hout[3]=hpa; A.hout[4]=hpb;
    A.offs[0]=nullptr; A.offs[1]=nullptr; A.offs[2]=nullptr; A.offs[3]=offsA; A.offs[4]=offsB;
    A.ks[0]=nullptr; A.ks[1]=nullptr; A.ks[2]=nullptr; A.ks[3]=KsA; A.ks[4]=KsB;
    seq_kernel<<<NBLK_SEQ, 64, 0, stream>>>(A);

    final_fc<<<(T_STEPS+255)/256, 256, 0, stream>>>(hA, hB, hI, hpa, hpb, fc_w, fc_b, out);
}

// Round 11
// 308.294 us; speedup vs baseline: 1.3574x; 1.3363x over previous
//
#include <hip/hip_runtime.h>
#include <hip/hip_bf16.h>

#define T_STEPS 8192
#define LMAX 12
#define DV 128
#define DI 65
#define NG 256   // 4*H
#define HH 64

#define SMAX (T_STEPS * LMAX)        // 98304 worst-case lang rows
#define GD_ROWS (T_STEPS + 64)       // dense G3 rows (pad for prefetch)
#define GL_ROWS (SMAX + 64)          // lang G3 rows
#define KS_WORDS (SMAX + 64)
#define WARM 64                      // validated r6
#define CH_VAD 64
#define CH_LNG 256
#define NBLK_SEQ (3*CH_VAD + 2*CH_LNG)   // 704 blocks x 4 waves

// Abf segment row offsets (all 64-aligned)
#define SEG1 8192
#define SEG2 16384
#define SEG3 24576
#define SEG4 122880
#define TOTROWS 221184

typedef short s16x8 __attribute__((ext_vector_type(8)));
typedef float f32x4 __attribute__((ext_vector_type(4)));
typedef float v2f __attribute__((ext_vector_type(2)));

__device__ __forceinline__ void pk_fma(v2f& d, v2f a, v2f b){
    asm("v_pk_fma_f32 %0, %1, %2, %0" : "+v"(d) : "v"(a), "v"(b));
}

#if __has_builtin(__builtin_amdgcn_exp2f)
__device__ __forceinline__ float fast_exp2(float x){ return __builtin_amdgcn_exp2f(x); }
#else
__device__ __forceinline__ float fast_exp2(float x){ return exp2f(x); }
#endif
#if __has_builtin(__builtin_amdgcn_rcpf)
__device__ __forceinline__ float fast_rcp(float x){ return __builtin_amdgcn_rcpf(x); }
#else
__device__ __forceinline__ float fast_rcp(float x){ return 1.0f/x; }
#endif

__device__ __forceinline__ float bf2f(unsigned short u){
    return __uint_as_float(((unsigned)u)<<16);
}
__device__ __forceinline__ unsigned short f2bf(float f){
    unsigned u = __float_as_uint(f);
    unsigned r = (u + 0x7fffu + ((u>>16)&1u)) >> 16;   // RNE
    return (unsigned short)r;
}
__device__ __forceinline__ unsigned packbf2(float a, float b){
    return (unsigned)f2bf(a) | ((unsigned)f2bf(b) << 16);
}

// quad-local xor shuffles via DPP (validated r4-r6)
__device__ __forceinline__ float dpp_xor1(float x){
    return __uint_as_float((unsigned)__builtin_amdgcn_update_dpp(
        0, (int)__float_as_uint(x), 0xB1, 0xF, 0xF, true));
}
__device__ __forceinline__ float dpp_xor2(float x){
    return __uint_as_float((unsigned)__builtin_amdgcn_update_dpp(
        0, (int)__float_as_uint(x), 0x4E, 0xF, 0xF, true));
}

// barrier: drain LDS only, leave global prefetches in flight.
#define BAR() asm volatile("s_waitcnt lgkmcnt(0)\ns_barrier" ::: "memory")

// ---------------- prefix scan of lens -> exclusive offsets (+ total at [T]) --
__global__ void scan_kernel(const int* __restrict__ lenA, const int* __restrict__ lenB,
                            int* __restrict__ offsA, int* __restrict__ offsB)
{
    const int* len = blockIdx.x ? lenB : lenA;
    int* offs = blockIdx.x ? offsB : offsA;
    int lane = threadIdx.x;   // 64 threads
    int carry = 0;
    for (int base = 0; base < T_STEPS; base += 64) {
        int x = len[base + lane];
        int v = x;
        #pragma unroll
        for (int d = 1; d < 64; d <<= 1) {
            int u = __shfl_up(v, d);
            if (lane >= d) v += u;
        }
        offs[base + lane] = carry + v - x;     // exclusive
        carry += __shfl(v, 63);
    }
    if (lane == 0) offs[T_STEPS] = carry;
}

// ---- build compacted-row -> source-row map, and per-row boundary counts ----
__global__ void build_meta(const int* __restrict__ len, const int* __restrict__ offs,
                           int* __restrict__ idx, int* __restrict__ Ks)
{
    int t = blockIdx.x * blockDim.x + threadIdx.x;
    if (t >= T_STEPS) return;
    int n = len[t];
    int o = offs[t];
    for (int p = 0; p < n; p++) idx[o + p] = t * LMAX + p;
    int e = offs[t + 1];
    if (e > 0) atomicAdd(&Ks[e - 1], 1);   // boundary after row e-1
}

// ---------------- bf16 conversion passes -------------------------------------
__global__ __launch_bounds__(256) void conv_rows(const float* __restrict__ x, int D, int rows,
                                                 unsigned* __restrict__ dst)
{
    int wv = threadIdx.x >> 6, l = threadIdx.x & 63;
    for (int r = blockIdx.x*4 + wv; r < rows; r += gridDim.x*4) {
        const float* xr = x + (size_t)r * D;
        int c = 2*l;
        float a = (c < D)   ? xr[c]   : 0.f;
        float b = (c+1 < D) ? xr[c+1] : 0.f;
        dst[(size_t)r*64 + l] = packbf2(a, b);
    }
}

__global__ __launch_bounds__(256) void conv_lang(const float* __restrict__ P,
    const int* __restrict__ idx, const int* __restrict__ offs, unsigned* __restrict__ dst)
{
    int R = offs[T_STEPS];
    int Rpad = (R + 63) & ~63;
    int wv = threadIdx.x >> 6, l = threadIdx.x & 63;
    for (int r = blockIdx.x*4 + wv; r < Rpad; r += gridDim.x*4) {
        unsigned v = 0;
        if (r < R) {
            const float* xr = P + (size_t)idx[r] * DV;
            float2 p = *(const float2*)(xr + 2*l);
            v = packbf2(p.x, p.y);
        }
        dst[(size_t)r*64 + l] = v;
    }
}

__global__ __launch_bounds__(256) void conv_w(const float* __restrict__ Wv,
    const float* __restrict__ Wi, const float* __restrict__ Wl,
    unsigned* __restrict__ dv, unsigned* __restrict__ di, unsigned* __restrict__ dl)
{
    int mat = blockIdx.y;
    const float* W = mat==0 ? Wv : mat==1 ? Wi : Wl;
    unsigned* dst  = mat==0 ? dv : mat==1 ? di : dl;
    int D = (mat==1) ? DI : DV;
    int wv = threadIdx.x >> 6, l = threadIdx.x & 63;
    int j = blockIdx.x*4 + wv;
    const float* wr = W + (size_t)j * D;
    int c = 2*l;
    float a = (c < D)   ? wr[c]   : 0.f;
    float b = (c+1 < D) ? wr[c+1] : 0.f;
    dst[(size_t)j*64 + l] = packbf2(a, b);
}

// ---------------- all gate GEMMs on matrix cores -----------------------------
struct GemmArgs {
    const unsigned* Abf;
    const unsigned* Wb[3];
    const float*    bias[3];
    unsigned short* G[5];
    const int*      offs[2];
};

__global__ __launch_bounds__(256) void gates_mfma(GemmArgs A)
{
    int rowbase0 = blockIdx.x * 64;
    int seg;
    if      (rowbase0 < SEG1) seg = 0;
    else if (rowbase0 < SEG2) seg = 1;
    else if (rowbase0 < SEG3) seg = 2;
    else if (rowbase0 < SEG4) seg = 3;
    else                      seg = 4;
    int segbase = (seg==0)?0:(seg==1)?SEG1:(seg==2)?SEG2:(seg==3)?SEG3:SEG4;
    int wi      = (seg<2)?0:((seg==2)?1:2);
    if (seg >= 3) {
        int R = A.offs[seg-3][T_STEPS];
        if (rowbase0 - segbase >= ((R + 63) & ~63)) return;
    }
    int tid = threadIdx.x, wv = tid >> 6, l = tid & 63;
    int m = l & 15, kg = l >> 4;
    int rowbase = rowbase0 + wv * 16;

    const unsigned* ar = A.Abf + (size_t)(rowbase + m) * 64 + kg * 4;
    uint4 af0 = *(const uint4*)(ar);
    uint4 af1 = *(const uint4*)(ar + 16);
    uint4 af2 = *(const uint4*)(ar + 32);
    uint4 af3 = *(const uint4*)(ar + 48);

    const unsigned* Wb = A.Wb[wi] + (size_t)m * 64 + kg * 4;
    const float* bias = A.bias[wi];

    f32x4 acc[16];
    #pragma unroll
    for (int n0 = 0; n0 < 16; n0++) acc[n0] = (f32x4){0.f,0.f,0.f,0.f};

    #pragma unroll
    for (int n0 = 0; n0 < 16; n0++) {
        const unsigned* wp = Wb + (size_t)n0 * 16 * 64;
        uint4 b0 = *(const uint4*)(wp);
        uint4 b1 = *(const uint4*)(wp + 16);
        uint4 b2 = *(const uint4*)(wp + 32);
        uint4 b3 = *(const uint4*)(wp + 48);
        acc[n0] = __builtin_amdgcn_mfma_f32_16x16x32_bf16(
            __builtin_bit_cast(s16x8, af0), __builtin_bit_cast(s16x8, b0), acc[n0], 0,0,0);
        acc[n0] = __builtin_amdgcn_mfma_f32_16x16x32_bf16(
            __builtin_bit_cast(s16x8, af1), __builtin_bit_cast(s16x8, b1), acc[n0], 0,0,0);
        acc[n0] = __builtin_amdgcn_mfma_f32_16x16x32_bf16(
            __builtin_bit_cast(s16x8, af2), __builtin_bit_cast(s16x8, b2), acc[n0], 0,0,0);
        acc[n0] = __builtin_amdgcn_mfma_f32_16x16x32_bf16(
            __builtin_bit_cast(s16x8, af3), __builtin_bit_cast(s16x8, b3), acc[n0], 0,0,0);
    }

    // gate j = n0*16+m = 64q + 16b + m  (q=n0>>2, b=n0&3) -> cell=16b+m
    unsigned short* Gp = A.G[seg];
    int localrow = rowbase - segbase + kg * 4;
    #pragma unroll
    for (int b = 0; b < 4; b++) {
        int cell = 16*b + m;
        float bj0 = bias[      16*b + m];
        float bj1 = bias[ 64 + 16*b + m];
        float bj2 = bias[128 + 16*b + m];
        float bj3 = bias[192 + 16*b + m];
        #pragma unroll
        for (int r = 0; r < 4; r++) {
            ushort4 o;
            o.x = f2bf(acc[b   ][r] + bj0);
            o.y = f2bf(acc[4+b ][r] + bj1);
            o.z = f2bf(acc[8+b ][r] + bj2);
            o.w = f2bf(acc[12+b][r] + bj3);
            *(ushort4*)(Gp + (size_t)(localrow + r)*NG + cell*4) = o;
        }
    }
}

// ---------------- chunked-parallel recurrence: 4 waves per chunk -------------
// Lane (wave wv, lane l): k-slice s=l&3, cell=wv*16+(l>>2). Each lane computes
// partials of ALL 4 gates of its cell over h[16s..16s+15]; quad DPP all-reduce
// completes them. Weights: 32 v2f (64 VGPR) pinned via opaque asm so neither
// the barrier's memory clobber nor remat heuristics can reload them (the
// architectural 256-VGPR cap made the 1-wave fp32 layout unholdable — r9/r10).
// Gx: this lane's gate-s preact is G3[row][wv*64+l] -> coalesced 2B loads.
struct SeqArgs {
    const unsigned short* gx[5];    // G3 [row][cell*4+q]
    const float*          whh[5];   // fp32 Whh [256][64]
    float*                hout[5];
    const int*            offs[5];
    const int*            ks[5];
};

#define WDECL(q) v2f W##q##_0,W##q##_1,W##q##_2,W##q##_3,W##q##_4,W##q##_5,W##q##_6,W##q##_7;
#define WLOAD(q) { const v2f* p = (const v2f*)(Whh + (size_t)(q*HH + cell)*HH + s*16); \
  W##q##_0=p[0]; W##q##_1=p[1]; W##q##_2=p[2]; W##q##_3=p[3]; \
  W##q##_4=p[4]; W##q##_5=p[5]; W##q##_6=p[6]; W##q##_7=p[7]; }
#define WPIN(q) asm volatile("" : "+v"(W##q##_0),"+v"(W##q##_1),"+v"(W##q##_2),"+v"(W##q##_3), \
  "+v"(W##q##_4),"+v"(W##q##_5),"+v"(W##q##_6),"+v"(W##q##_7));

#define MACT(t,P0,P1) { float4 hv = h4[t]; \
  v2f lo; lo.x = hv.x; lo.y = hv.y; v2f hi; hi.x = hv.z; hi.y = hv.w; \
  pk_fma(a0, W0_##P0, lo); pk_fma(a1, W1_##P0, lo); \
  pk_fma(a2, W2_##P0, lo); pk_fma(a3, W3_##P0, lo); \
  pk_fma(a0, W0_##P1, hi); pk_fma(a1, W1_##P1, hi); \
  pk_fma(a2, W2_##P1, hi); pk_fma(a3, W3_##P1, hi); }

#define DO_STEP(gxraw, kc, row, pin, pout) do { \
  float gxv = bf2f(gxraw); \
  v2f a0; a0.x = gxv * msk0; a0.y = 0.f; \
  v2f a1; a1.x = gxv * msk1; a1.y = 0.f; \
  v2f a2; a2.x = gxv * msk2; a2.y = 0.f; \
  v2f a3; a3.x = gxv * msk3; a3.y = 0.f; \
  const float4* h4 = (const float4*)((pin) + (s << 4)); \
  MACT(0,0,1) MACT(1,2,3) MACT(2,4,5) MACT(3,6,7) \
  float s0 = a0.x + a0.y, s1 = a1.x + a1.y, s2 = a2.x + a2.y, s3 = a3.x + a3.y; \
  s0 += dpp_xor1(s0); s1 += dpp_xor1(s1); s2 += dpp_xor1(s2); s3 += dpp_xor1(s3); \
  s0 += dpp_xor2(s0); s1 += dpp_xor2(s1); s2 += dpp_xor2(s2); s3 += dpp_xor2(s3); \
  float i_ = fast_rcp(1.f + fast_exp2(s0 * kSig)); \
  float f_ = fast_rcp(1.f + fast_exp2(s1 * kSig)); \
  float g_ = fmaf(-2.f, fast_rcp(1.f + fast_exp2(s2 * kTan)), 1.f); \
  float o_ = fast_rcp(1.f + fast_exp2(s3 * kSig)); \
  c = fmaf(f_, c, i_ * g_); \
  float tc = fmaf(-2.f, fast_rcp(1.f + fast_exp2(c * kTan)), 1.f); \
  float h = o_ * tc; \
  bool em = ((row) >= S) & ((row) < E); \
  if (s == 0) { \
    (pout)[cell] = h; \
    if (em) { \
      if (!isLang) hout[(size_t)(row)*HH + cell] = h; \
      else for (int i = 0; i < (kc); i++) hout[(size_t)(tptr + i)*HH + cell] = h; \
    } \
  } \
  if (isLang && em) tptr += (kc); \
  BAR(); \
} while(0)

__global__ __launch_bounds__(256,1) void seq_kernel(SeqArgs A)
{
    int bid = blockIdx.x;
    int chain, chunk, nch;
    if (bid < 3*CH_VAD) { chain = bid / CH_VAD; chunk = bid % CH_VAD; nch = CH_VAD; }
    else { int b2 = bid - 3*CH_VAD; chain = 3 + b2 / CH_LNG; chunk = b2 % CH_LNG; nch = CH_LNG; }

    const unsigned short* __restrict__ G3 = A.gx[chain];
    const float* __restrict__ Whh = A.whh[chain];
    float* __restrict__ hout = A.hout[chain];
    const int* __restrict__ offs = A.offs[chain];
    const int* __restrict__ Ks = A.ks[chain];
    const bool isLang = (offs != nullptr);

    const int R = isLang ? offs[T_STEPS] : T_STEPS;
    const int len = ((R + nch - 1) / nch + 3) & ~3;
    const int S = chunk * len;
    if (chunk > 0 && S >= R) return;
    const int E = min(S + len, R);
    const int start = (S > WARM) ? (S - WARM) : 0;

    int tid = threadIdx.x, wv = tid >> 6, l = tid & 63;
    int s = l & 3;
    int cell = (wv << 4) | (l >> 2);

    int tptr = 0;
    if (isLang) {
        int lo = 1, hi = T_STEPS + 1;
        while (lo < hi) {
            int mid = (lo + hi) >> 1;
            if (offs[mid] <= S) lo = mid + 1; else hi = mid;
        }
        tptr = lo - 1;
    }

    WDECL(0) WDECL(1) WDECL(2) WDECL(3)
    WLOAD(0) WLOAD(1) WLOAD(2) WLOAD(3)
    WPIN(0) WPIN(1) WPIN(2) WPIN(3)

    float msk0 = (s == 0) ? 1.f : 0.f;
    float msk1 = (s == 1) ? 1.f : 0.f;
    float msk2 = (s == 2) ? 1.f : 0.f;
    float msk3 = (s == 3) ? 1.f : 0.f;

    __shared__ __align__(16) float hb[2][HH];
    if (tid < HH) { hb[0][tid] = 0.f; hb[1][tid] = 0.f; }

    float c = 0.f;
    const float kSig = -1.44269504088896340736f;  // -log2(e)
    const float kTan =  2.88539008177792681472f;  //  2*log2(e)

    if (isLang && chunk == 0 && s == 0)
        for (int i = 0; i < tptr; i++) hout[(size_t)i*HH + cell] = 0.f;

    // Gx stream: lane value for row r is G3[r*NG + wv*64 + l]  (coalesced)
    const unsigned short* gp = G3 + (size_t)start * NG + (wv << 6) + l;
    int rix = start;
    unsigned short ga0 = gp[0*NG], ga1 = gp[1*NG], ga2 = gp[2*NG], ga3 = gp[3*NG];
    int4 kcur = isLang ? *(const int4*)(Ks + start) : make_int4(0,0,0,0);
    gp += 4*NG;

    BAR();   // hb[0] visible to all waves

    int nblk = (E - start + 3) >> 2;
    for (int it = 0; it < nblk; ++it) {
        unsigned short nb0 = gp[0*NG], nb1 = gp[1*NG], nb2 = gp[2*NG], nb3 = gp[3*NG];
        int4 knext = isLang ? *(const int4*)(Ks + rix + 4) : make_int4(0,0,0,0);
        DO_STEP(ga0, kcur.x, rix + 0, hb[0], hb[1]);
        DO_STEP(ga1, kcur.y, rix + 1, hb[1], hb[0]);
        DO_STEP(ga2, kcur.z, rix + 2, hb[0], hb[1]);
        DO_STEP(ga3, kcur.w, rix + 3, hb[1], hb[0]);
        ga0 = nb0; ga1 = nb1; ga2 = nb2; ga3 = nb3;
        kcur = knext;
        gp += 4*NG;
        rix += 4;
    }
}

// ---------------- final: alpha[t] = sigmoid(fc_w . concat + fc_b) ------------
__global__ __launch_bounds__(256) void final_fc(const float* __restrict__ hA,
    const float* __restrict__ hB, const float* __restrict__ hI,
    const float* __restrict__ hpa, const float* __restrict__ hpb,
    const float* __restrict__ fcw, const float* __restrict__ fcb,
    float* __restrict__ out)
{
    int t = blockIdx.x * blockDim.x + threadIdx.x;
    if (t >= T_STEPS) return;
    float acc = fcb[0];
    const float* hs0 = hA  + (size_t)t*HH;
    const float* hs1 = hB  + (size_t)t*HH;
    const float* hs2 = hI  + (size_t)t*HH;
    const float* hs3 = hpa + (size_t)t*HH;
    const float* hs4 = hpb + (size_t)t*HH;
    #pragma unroll
    for (int k = 0; k < HH; k++) acc = fmaf(hs0[k], fcw[0*HH+k], acc);
    #pragma unroll
    for (int k = 0; k < HH; k++) acc = fmaf(hs1[k], fcw[1*HH+k], acc);
    #pragma unroll
    for (int k = 0; k < HH; k++) acc = fmaf(hs2[k], fcw[2*HH+k], acc);
    #pragma unroll
    for (int k = 0; k < HH; k++) acc = fmaf(hs3[k], fcw[3*HH+k], acc);
    #pragma unroll
    for (int k = 0; k < HH; k++) acc = fmaf(hs4[k], fcw[4*HH+k], acc);
    out[t] = fast_rcp(1.f + fast_exp2(acc * -1.44269504088896340736f));
}

// ---------------- launch -----------------------------------------------------
extern "C" void kernel_launch(void* const* d_in, const int* in_sizes, int n_in,
                              void* d_out, int out_size, void* d_ws, size_t ws_size,
                              hipStream_t stream)
{
    const float* xA      = (const float*)d_in[0];
    const float* xB      = (const float*)d_in[1];
    const float* img     = (const float*)d_in[2];
    const float* PA      = (const float*)d_in[3];
    const float* PB      = (const float*)d_in[4];
    const int*   lenA    = (const int*)d_in[5];
    const int*   lenB    = (const int*)d_in[6];
    const float* Wih_vad = (const float*)d_in[7];
    const float* Whh_vad = (const float*)d_in[8];
    const float* b_vad   = (const float*)d_in[9];
    const float* Wih_img = (const float*)d_in[10];
    const float* Whh_img = (const float*)d_in[11];
    const float* b_img   = (const float*)d_in[12];
    const float* Wih_lng = (const float*)d_in[13];
    const float* Whh_lng = (const float*)d_in[14];
    const float* b_lng   = (const float*)d_in[15];
    const float* fc_w    = (const float*)d_in[16];
    const float* fc_b    = (const float*)d_in[17];
    float* out = (float*)d_out;

    char* ws = (char*)d_ws;
    size_t off = 0;
    auto alloc = [&](size_t bytes) -> void* {
        void* p = ws + off;
        off += (bytes + 255) & ~(size_t)255;
        return p;
    };
    int* offsA = (int*)alloc((T_STEPS+1)*sizeof(int));
    int* offsB = (int*)alloc((T_STEPS+1)*sizeof(int));
    int* idxA  = (int*)alloc((size_t)SMAX*sizeof(int));
    int* idxB  = (int*)alloc((size_t)SMAX*sizeof(int));
    int* KsA   = (int*)alloc((size_t)KS_WORDS*sizeof(int));   // contiguous with KsB
    int* KsB   = (int*)alloc((size_t)KS_WORDS*sizeof(int));
    unsigned short* GvA = (unsigned short*)alloc((size_t)GD_ROWS*NG*2);
    unsigned short* GvB = (unsigned short*)alloc((size_t)GD_ROWS*NG*2);
    unsigned short* Gim = (unsigned short*)alloc((size_t)GD_ROWS*NG*2);
    unsigned short* GlA = (unsigned short*)alloc((size_t)GL_ROWS*NG*2);
    unsigned short* GlB = (unsigned short*)alloc((size_t)GL_ROWS*NG*2);
    float* hA  = (float*)alloc((size_t)T_STEPS*HH*sizeof(float));
    float* hB  = (float*)alloc((size_t)T_STEPS*HH*sizeof(float));
    float* hI  = (float*)alloc((size_t)T_STEPS*HH*sizeof(float));
    float* hpa = (float*)alloc((size_t)T_STEPS*HH*sizeof(float));
    float* hpb = (float*)alloc((size_t)T_STEPS*HH*sizeof(float));
    unsigned* Abf  = (unsigned*)alloc((size_t)TOTROWS*64*sizeof(unsigned));
    unsigned* Wbf0 = (unsigned*)alloc((size_t)NG*64*sizeof(unsigned));
    unsigned* Wbf1 = (unsigned*)alloc((size_t)NG*64*sizeof(unsigned));
    unsigned* Wbf2 = (unsigned*)alloc((size_t)NG*64*sizeof(unsigned));
    (void)ws_size; (void)in_sizes; (void)n_in; (void)out_size;

    scan_kernel<<<2, 64, 0, stream>>>(lenA, lenB, offsA, offsB);
    hipMemsetAsync(KsA, 0, 2*(size_t)KS_WORDS*sizeof(int), stream);
    build_meta<<<(T_STEPS+255)/256, 256, 0, stream>>>(lenA, offsA, idxA, KsA);
    build_meta<<<(T_STEPS+255)/256, 256, 0, stream>>>(lenB, offsB, idxB, KsB);

    conv_w<<<dim3(64,3), 256, 0, stream>>>(Wih_vad, Wih_img, Wih_lng, Wbf0, Wbf1, Wbf2);
    conv_rows<<<512, 256, 0, stream>>>(xA,  DV, T_STEPS, Abf);
    conv_rows<<<512, 256, 0, stream>>>(xB,  DV, T_STEPS, Abf + (size_t)SEG1*64);
    conv_rows<<<512, 256, 0, stream>>>(img, DI, T_STEPS, Abf + (size_t)SEG2*64);
    conv_lang<<<1024, 256, 0, stream>>>(PA, idxA, offsA, Abf + (size_t)SEG3*64);
    conv_lang<<<1024, 256, 0, stream>>>(PB, idxB, offsB, Abf + (size_t)SEG4*64);

    GemmArgs GA;
    GA.Abf = Abf;
    GA.Wb[0]=Wbf0; GA.Wb[1]=Wbf1; GA.Wb[2]=Wbf2;
    GA.bias[0]=b_vad; GA.bias[1]=b_img; GA.bias[2]=b_lng;
    GA.G[0]=GvA; GA.G[1]=GvB; GA.G[2]=Gim; GA.G[3]=GlA; GA.G[4]=GlB;
    GA.offs[0]=offsA; GA.offs[1]=offsB;
    gates_mfma<<<TOTROWS/64, 256, 0, stream>>>(GA);

    SeqArgs A;
    A.gx[0]=GvA;  A.gx[1]=GvB;  A.gx[2]=Gim;  A.gx[3]=GlA;  A.gx[4]=GlB;
    A.whh[0]=Whh_vad; A.whh[1]=Whh_vad; A.whh[2]=Whh_img; A.whh[3]=Whh_lng; A.whh[4]=Whh_lng;
    A.hout[0]=hA; A.hout[1]=hB; A.hout[2]=hI; A.hout[3]=hpa; A.hout[4]=hpb;
    A.offs[0]=nullptr; A.offs[1]=nullptr; A.offs[2]=nullptr; A.offs[3]=offsA; A.offs[4]=offsB;
    A.ks[0]=nullptr; A.ks[1]=nullptr; A.ks[2]=nullptr; A.ks[3]=KsA; A.ks[4]=KsB;
    seq_kernel<<<NBLK_SEQ, 256, 0, stream>>>(A);

    final_fc<<<(T_STEPS+255)/256, 256, 0, stream>>>(hA, hB, hI, hpa, hpb, fc_w, fc_b, out);
}

// Round 12
// 302.187 us; speedup vs baseline: 1.3849x; 1.0202x over previous
//
#include <hip/hip_runtime.h>
#include <hip/hip_bf16.h>

#define T_STEPS 8192
#define LMAX 12
#define DV 128
#define DI 65
#define NG 256   // 4*H
#define HH 64

#define SMAX (T_STEPS * LMAX)        // 98304 worst-case lang rows
#define GD_ROWS (T_STEPS + 64)       // dense G3 rows (pad for prefetch)
#define GL_ROWS (SMAX + 64)          // lang G3 rows
#define KS_WORDS (SMAX + 64)
#define WARM 64                      // validated r6
#define CH_VAD 128
#define CH_LNG 512
#define NBLK_SEQ (3*CH_VAD + 2*CH_LNG)   // 1408 blocks x 4 waves

// virtual row space for the fused gate GEMM (all 64-aligned)
#define SEG1 8192
#define SEG2 16384
#define SEG3 24576
#define SEG4 122880
#define TOTROWS 221184

typedef short s16x8 __attribute__((ext_vector_type(8)));
typedef float f32x4 __attribute__((ext_vector_type(4)));

#if __has_builtin(__builtin_amdgcn_exp2f)
__device__ __forceinline__ float fast_exp2(float x){ return __builtin_amdgcn_exp2f(x); }
#else
__device__ __forceinline__ float fast_exp2(float x){ return exp2f(x); }
#endif
#if __has_builtin(__builtin_amdgcn_rcpf)
__device__ __forceinline__ float fast_rcp(float x){ return __builtin_amdgcn_rcpf(x); }
#else
__device__ __forceinline__ float fast_rcp(float x){ return 1.0f/x; }
#endif

__device__ __forceinline__ float bf2f(unsigned short u){
    return __uint_as_float(((unsigned)u)<<16);
}
__device__ __forceinline__ unsigned short f2bf(float f){
    unsigned u = __float_as_uint(f);
    unsigned r = (u + 0x7fffu + ((u>>16)&1u)) >> 16;   // RNE
    return (unsigned short)r;
}
__device__ __forceinline__ unsigned packbf2(float a, float b){
    return (unsigned)f2bf(a) | ((unsigned)f2bf(b) << 16);
}

// quad-local xor shuffles via DPP (validated r4-r6)
__device__ __forceinline__ float dpp_xor1(float x){
    return __uint_as_float((unsigned)__builtin_amdgcn_update_dpp(
        0, (int)__float_as_uint(x), 0xB1, 0xF, 0xF, true));
}
__device__ __forceinline__ float dpp_xor2(float x){
    return __uint_as_float((unsigned)__builtin_amdgcn_update_dpp(
        0, (int)__float_as_uint(x), 0x4E, 0xF, 0xF, true));
}

// barrier: drain LDS only, leave global prefetches in flight.
#define BAR() asm volatile("s_waitcnt lgkmcnt(0)\ns_barrier" ::: "memory")

// ---------------- prefix scan of lens -> exclusive offsets (+ total at [T]) --
__global__ void scan_kernel(const int* __restrict__ lenA, const int* __restrict__ lenB,
                            int* __restrict__ offsA, int* __restrict__ offsB)
{
    const int* len = blockIdx.x ? lenB : lenA;
    int* offs = blockIdx.x ? offsB : offsA;
    int lane = threadIdx.x;   // 64 threads
    int carry = 0;
    for (int base = 0; base < T_STEPS; base += 64) {
        int x = len[base + lane];
        int v = x;
        #pragma unroll
        for (int d = 1; d < 64; d <<= 1) {
            int u = __shfl_up(v, d);
            if (lane >= d) v += u;
        }
        offs[base + lane] = carry + v - x;     // exclusive
        carry += __shfl(v, 63);
    }
    if (lane == 0) offs[T_STEPS] = carry;
}

// ---- build compacted-row -> source-row map, and per-row boundary counts ----
__global__ void build_meta(const int* __restrict__ len, const int* __restrict__ offs,
                           int* __restrict__ idx, int* __restrict__ Ks)
{
    int t = blockIdx.x * blockDim.x + threadIdx.x;
    if (t >= T_STEPS) return;
    int n = len[t];
    int o = offs[t];
    for (int p = 0; p < n; p++) idx[o + p] = t * LMAX + p;
    int e = offs[t + 1];
    if (e > 0) atomicAdd(&Ks[e - 1], 1);   // boundary after row e-1
}

// ---------------- bf16 weights for the GEMM B-operand ------------------------
__global__ __launch_bounds__(256) void conv_w(const float* __restrict__ Wv,
    const float* __restrict__ Wi, const float* __restrict__ Wl,
    unsigned* __restrict__ dv, unsigned* __restrict__ di, unsigned* __restrict__ dl)
{
    int mat = blockIdx.y;
    const float* W = mat==0 ? Wv : mat==1 ? Wi : Wl;
    unsigned* dst  = mat==0 ? dv : mat==1 ? di : dl;
    int D = (mat==1) ? DI : DV;
    int wv = threadIdx.x >> 6, l = threadIdx.x & 63;
    int j = blockIdx.x*4 + wv;
    const float* wr = W + (size_t)j * D;
    int c = 2*l;
    float a = (c < D)   ? wr[c]   : 0.f;
    float b = (c+1 < D) ? wr[c+1] : 0.f;
    dst[(size_t)j*64 + l] = packbf2(a, b);
}

// ---------------- fused gate GEMMs: fp32 in -> bf16 frag -> MFMA -> G3 -------
// A-frag converted in-register from fp32 sources (incl. lang idx-gather).
// Output G3[row][cell*4+q] bf16 so seq reads 4 gate pre-acts as one 8B load.
struct GemmArgs {
    const float*    xsrc[3];   // xA, xB, img
    const float*    psrc[2];   // PA, PB
    const int*      idx[2];
    const unsigned* Wb[3];
    const float*    bias[3];
    unsigned short* G[5];
    const int*      offs[2];
};

__global__ __launch_bounds__(256) void gates_mfma(GemmArgs A)
{
    int rowbase0 = blockIdx.x * 64;
    int seg;
    if      (rowbase0 < SEG1) seg = 0;
    else if (rowbase0 < SEG2) seg = 1;
    else if (rowbase0 < SEG3) seg = 2;
    else if (rowbase0 < SEG4) seg = 3;
    else                      seg = 4;
    int segbase = (seg==0)?0:(seg==1)?SEG1:(seg==2)?SEG2:(seg==3)?SEG3:SEG4;
    int wi      = (seg<2)?0:((seg==2)?1:2);
    int R = 0;
    if (seg >= 3) {
        R = A.offs[seg-3][T_STEPS];
        if (rowbase0 - segbase >= ((R + 63) & ~63)) return;
    }
    int tid = threadIdx.x, wv = tid >> 6, l = tid & 63;
    int m = l & 15, kg = l >> 4;
    int lrow = rowbase0 - segbase + wv * 16 + m;   // local row for this lane

    // ---- load + convert this lane's A fragments (4 x 8 fp32 -> 4 x uint4) --
    uint4 af0, af1, af2, af3;
    if (seg < 2 || seg >= 3) {
        const float* xr;
        bool ok = true;
        if (seg < 2) xr = A.xsrc[seg] + (size_t)lrow * DV;
        else { ok = lrow < R; xr = ok ? (A.psrc[seg-3] + (size_t)A.idx[seg-3][lrow] * DV) : nullptr; }
        auto lda = [&](int kb)->uint4 {
            uint4 u = make_uint4(0,0,0,0);
            if (ok) {
                float4 a = *(const float4*)(xr + kb);
                float4 b = *(const float4*)(xr + kb + 4);
                u.x = packbf2(a.x, a.y); u.y = packbf2(a.z, a.w);
                u.z = packbf2(b.x, b.y); u.w = packbf2(b.z, b.w);
            }
            return u;
        };
        af0 = lda(kg*8); af1 = lda(32+kg*8); af2 = lda(64+kg*8); af3 = lda(96+kg*8);
    } else {
        // img: D=65, per-element guard
        const float* xr = A.xsrc[2] + (size_t)lrow * DI;
        auto lda = [&](int kb)->uint4 {
            float v[8];
            #pragma unroll
            for (int j = 0; j < 8; j++) { int c = kb + j; v[j] = (c < DI) ? xr[c] : 0.f; }
            return make_uint4(packbf2(v[0],v[1]), packbf2(v[2],v[3]),
                              packbf2(v[4],v[5]), packbf2(v[6],v[7]));
        };
        af0 = lda(kg*8); af1 = lda(32+kg*8); af2 = lda(64+kg*8); af3 = lda(96+kg*8);
    }

    const unsigned* Wb = A.Wb[wi] + (size_t)m * 64 + kg * 4;
    const float* bias = A.bias[wi];

    f32x4 acc[16];
    #pragma unroll
    for (int n0 = 0; n0 < 16; n0++) acc[n0] = (f32x4){0.f,0.f,0.f,0.f};

    #pragma unroll
    for (int n0 = 0; n0 < 16; n0++) {
        const unsigned* wp = Wb + (size_t)n0 * 16 * 64;
        uint4 b0 = *(const uint4*)(wp);
        uint4 b1 = *(const uint4*)(wp + 16);
        uint4 b2 = *(const uint4*)(wp + 32);
        uint4 b3 = *(const uint4*)(wp + 48);
        acc[n0] = __builtin_amdgcn_mfma_f32_16x16x32_bf16(
            __builtin_bit_cast(s16x8, af0), __builtin_bit_cast(s16x8, b0), acc[n0], 0,0,0);
        acc[n0] = __builtin_amdgcn_mfma_f32_16x16x32_bf16(
            __builtin_bit_cast(s16x8, af1), __builtin_bit_cast(s16x8, b1), acc[n0], 0,0,0);
        acc[n0] = __builtin_amdgcn_mfma_f32_16x16x32_bf16(
            __builtin_bit_cast(s16x8, af2), __builtin_bit_cast(s16x8, b2), acc[n0], 0,0,0);
        acc[n0] = __builtin_amdgcn_mfma_f32_16x16x32_bf16(
            __builtin_bit_cast(s16x8, af3), __builtin_bit_cast(s16x8, b3), acc[n0], 0,0,0);
    }

    // gate j = n0*16+m = 64q + 16b + m  (q=n0>>2, b=n0&3) -> cell=16b+m
    unsigned short* Gp = A.G[seg];
    int localrow = rowbase0 - segbase + wv * 16 + kg * 4;
    #pragma unroll
    for (int b = 0; b < 4; b++) {
        int cell = 16*b + m;
        float bj0 = bias[      16*b + m];
        float bj1 = bias[ 64 + 16*b + m];
        float bj2 = bias[128 + 16*b + m];
        float bj3 = bias[192 + 16*b + m];
        #pragma unroll
        for (int r = 0; r < 4; r++) {
            ushort4 o;
            o.x = f2bf(acc[b   ][r] + bj0);
            o.y = f2bf(acc[4+b ][r] + bj1);
            o.z = f2bf(acc[8+b ][r] + bj2);
            o.w = f2bf(acc[12+b][r] + bj3);
            *(ushort4*)(Gp + (size_t)(localrow + r)*NG + cell*4) = o;
        }
    }
}

// ---------------- chunked-parallel recurrence: 4 waves per chunk -------------
// Lane (wave wv, lane l): k-slice s=l&3, cell=wv*16+(l>>2). Plain fmaf matvec
// (r4-proven — inline-asm pk_fma was SLOWER due to operand marshalling);
// quad DPP all-reduce; coalesced 2B Gx loads 4 rows ahead; lgkm-only barrier.
struct SeqArgs {
    const unsigned short* gx[5];    // G3 [row][cell*4+q]
    const float*          whh[5];   // fp32 Whh [256][64]
    float*                hout[5];
    const int*            offs[5];
    const int*            ks[5];
};

__global__ __launch_bounds__(256,1) void seq_kernel(SeqArgs A)
{
    int bid = blockIdx.x;
    int chain, chunk, nch;
    if (bid < 3*CH_VAD) { chain = bid / CH_VAD; chunk = bid % CH_VAD; nch = CH_VAD; }
    else { int b2 = bid - 3*CH_VAD; chain = 3 + b2 / CH_LNG; chunk = b2 % CH_LNG; nch = CH_LNG; }

    const unsigned short* __restrict__ G3 = A.gx[chain];
    const float* __restrict__ Whh = A.whh[chain];
    float* __restrict__ hout = A.hout[chain];
    const int* __restrict__ offs = A.offs[chain];
    const int* __restrict__ Ks = A.ks[chain];
    const bool isLang = (offs != nullptr);

    const int R = isLang ? offs[T_STEPS] : T_STEPS;
    const int len = ((R + nch - 1) / nch + 3) & ~3;
    const int S = chunk * len;
    if (chunk > 0 && S >= R) return;
    const int E = min(S + len, R);
    const int start = (S > WARM) ? (S - WARM) : 0;

    int tid = threadIdx.x, wv = tid >> 6, l = tid & 63;
    int s = l & 3;
    int cell = (wv << 4) | (l >> 2);

    int tptr = 0;
    if (isLang) {
        int lo = 1, hi = T_STEPS + 1;
        while (lo < hi) {
            int mid = (lo + hi) >> 1;
            if (offs[mid] <= S) lo = mid + 1; else hi = mid;
        }
        tptr = lo - 1;
    }

    // wreg[q][k] = Whh[q*64+cell][16s+k]
    float wreg[4][16];
    #pragma unroll
    for (int q = 0; q < 4; q++) {
        const float* wrow = Whh + (size_t)(q*HH + cell)*HH + s*16;
        #pragma unroll
        for (int k = 0; k < 16; k++) wreg[q][k] = wrow[k];
    }

    float msk0 = (s == 0) ? 1.f : 0.f;
    float msk1 = (s == 1) ? 1.f : 0.f;
    float msk2 = (s == 2) ? 1.f : 0.f;
    float msk3 = (s == 3) ? 1.f : 0.f;

    __shared__ __align__(16) float hb[2][HH];
    if (tid < HH) { hb[0][tid] = 0.f; hb[1][tid] = 0.f; }

    float c = 0.f;
    const float kSig = -1.44269504088896340736f;  // -log2(e)
    const float kTan =  2.88539008177792681472f;  //  2*log2(e)

    if (isLang && chunk == 0 && s == 0)
        for (int i = 0; i < tptr; i++) hout[(size_t)i*HH + cell] = 0.f;

    // Gx stream: lane value for row r is G3[r*NG + wv*64 + l]  (coalesced 2B)
    const unsigned short* gp = G3 + (size_t)start * NG + (wv << 6) + l;
    int rix = start;
    unsigned short ga0 = gp[0*NG], ga1 = gp[1*NG], ga2 = gp[2*NG], ga3 = gp[3*NG];
    int4 kcur = isLang ? *(const int4*)(Ks + start) : make_int4(0,0,0,0);
    gp += 4*NG;

    BAR();   // hb[0] visible to all waves

    auto step = [&](unsigned short gxraw, int kc, int row, const float* pin, float* pout) {
        float gxv = bf2f(gxraw);
        const float4* h4 = (const float4*)(pin + (s << 4));
        float4 h0 = h4[0], h1 = h4[1], h2 = h4[2], h3 = h4[3];
        float hv[16] = { h0.x,h0.y,h0.z,h0.w, h1.x,h1.y,h1.z,h1.w,
                         h2.x,h2.y,h2.z,h2.w, h3.x,h3.y,h3.z,h3.w };
        float a0 = gxv * msk0, a1 = gxv * msk1, a2 = gxv * msk2, a3 = gxv * msk3;
        #pragma unroll
        for (int k = 0; k < 16; k++) {
            a0 = fmaf(wreg[0][k], hv[k], a0);
            a1 = fmaf(wreg[1][k], hv[k], a1);
            a2 = fmaf(wreg[2][k], hv[k], a2);
            a3 = fmaf(wreg[3][k], hv[k], a3);
        }
        a0 += dpp_xor1(a0); a1 += dpp_xor1(a1); a2 += dpp_xor1(a2); a3 += dpp_xor1(a3);
        a0 += dpp_xor2(a0); a1 += dpp_xor2(a1); a2 += dpp_xor2(a2); a3 += dpp_xor2(a3);
        float i_ = fast_rcp(1.f + fast_exp2(a0 * kSig));
        float f_ = fast_rcp(1.f + fast_exp2(a1 * kSig));
        float g_ = fmaf(-2.f, fast_rcp(1.f + fast_exp2(a2 * kTan)), 1.f);
        float o_ = fast_rcp(1.f + fast_exp2(a3 * kSig));
        c = fmaf(f_, c, i_ * g_);
        float tc = fmaf(-2.f, fast_rcp(1.f + fast_exp2(c * kTan)), 1.f);
        float h = o_ * tc;
        bool em = (row >= S) & (row < E);
        if (s == 0) {
            pout[cell] = h;
            if (em) {
                if (!isLang) hout[(size_t)row*HH + cell] = h;
                else for (int i = 0; i < kc; i++) hout[(size_t)(tptr + i)*HH + cell] = h;
            }
        }
        if (isLang && em) tptr += kc;
        BAR();
    };

    int nblk = (E - start + 3) >> 2;
    for (int it = 0; it < nblk; ++it) {
        unsigned short nb0 = gp[0*NG], nb1 = gp[1*NG], nb2 = gp[2*NG], nb3 = gp[3*NG];
        int4 knext = isLang ? *(const int4*)(Ks + rix + 4) : make_int4(0,0,0,0);
        step(ga0, kcur.x, rix + 0, hb[0], hb[1]);
        step(ga1, kcur.y, rix + 1, hb[1], hb[0]);
        step(ga2, kcur.z, rix + 2, hb[0], hb[1]);
        step(ga3, kcur.w, rix + 3, hb[1], hb[0]);
        ga0 = nb0; ga1 = nb1; ga2 = nb2; ga3 = nb3;
        kcur = knext;
        gp += 4*NG;
        rix += 4;
    }
}

// ---------------- final: alpha[t] = sigmoid(fc_w . concat + fc_b) ------------
__global__ __launch_bounds__(256) void final_fc(const float* __restrict__ hA,
    const float* __restrict__ hB, const float* __restrict__ hI,
    const float* __restrict__ hpa, const float* __restrict__ hpb,
    const float* __restrict__ fcw, const float* __restrict__ fcb,
    float* __restrict__ out)
{
    int t = blockIdx.x * blockDim.x + threadIdx.x;
    if (t >= T_STEPS) return;
    float acc = fcb[0];
    const float* hs0 = hA  + (size_t)t*HH;
    const float* hs1 = hB  + (size_t)t*HH;
    const float* hs2 = hI  + (size_t)t*HH;
    const float* hs3 = hpa + (size_t)t*HH;
    const float* hs4 = hpb + (size_t)t*HH;
    #pragma unroll
    for (int k = 0; k < HH; k++) acc = fmaf(hs0[k], fcw[0*HH+k], acc);
    #pragma unroll
    for (int k = 0; k < HH; k++) acc = fmaf(hs1[k], fcw[1*HH+k], acc);
    #pragma unroll
    for (int k = 0; k < HH; k++) acc = fmaf(hs2[k], fcw[2*HH+k], acc);
    #pragma unroll
    for (int k = 0; k < HH; k++) acc = fmaf(hs3[k], fcw[3*HH+k], acc);
    #pragma unroll
    for (int k = 0; k < HH; k++) acc = fmaf(hs4[k], fcw[4*HH+k], acc);
    out[t] = fast_rcp(1.f + fast_exp2(acc * -1.44269504088896340736f));
}

// ---------------- launch -----------------------------------------------------
extern "C" void kernel_launch(void* const* d_in, const int* in_sizes, int n_in,
                              void* d_out, int out_size, void* d_ws, size_t ws_size,
                              hipStream_t stream)
{
    const float* xA      = (const float*)d_in[0];
    const float* xB      = (const float*)d_in[1];
    const float* img     = (const float*)d_in[2];
    const float* PA      = (const float*)d_in[3];
    const float* PB      = (const float*)d_in[4];
    const int*   lenA    = (const int*)d_in[5];
    const int*   lenB    = (const int*)d_in[6];
    const float* Wih_vad = (const float*)d_in[7];
    const float* Whh_vad = (const float*)d_in[8];
    const float* b_vad   = (const float*)d_in[9];
    const float* Wih_img = (const float*)d_in[10];
    const float* Whh_img = (const float*)d_in[11];
    const float* b_img   = (const float*)d_in[12];
    const float* Wih_lng = (const float*)d_in[13];
    const float* Whh_lng = (const float*)d_in[14];
    const float* b_lng   = (const float*)d_in[15];
    const float* fc_w    = (const float*)d_in[16];
    const float* fc_b    = (const float*)d_in[17];
    float* out = (float*)d_out;

    char* ws = (char*)d_ws;
    size_t off = 0;
    auto alloc = [&](size_t bytes) -> void* {
        void* p = ws + off;
        off += (bytes + 255) & ~(size_t)255;
        return p;
    };
    int* offsA = (int*)alloc((T_STEPS+1)*sizeof(int));
    int* offsB = (int*)alloc((T_STEPS+1)*sizeof(int));
    int* idxA  = (int*)alloc((size_t)SMAX*sizeof(int));
    int* idxB  = (int*)alloc((size_t)SMAX*sizeof(int));
    int* KsA   = (int*)alloc((size_t)KS_WORDS*sizeof(int));   // contiguous with KsB
    int* KsB   = (int*)alloc((size_t)KS_WORDS*sizeof(int));
    unsigned short* GvA = (unsigned short*)alloc((size_t)GD_ROWS*NG*2);
    unsigned short* GvB = (unsigned short*)alloc((size_t)GD_ROWS*NG*2);
    unsigned short* Gim = (unsigned short*)alloc((size_t)GD_ROWS*NG*2);
    unsigned short* GlA = (unsigned short*)alloc((size_t)GL_ROWS*NG*2);
    unsigned short* GlB = (unsigned short*)alloc((size_t)GL_ROWS*NG*2);
    float* hA  = (float*)alloc((size_t)T_STEPS*HH*sizeof(float));
    float* hB  = (float*)alloc((size_t)T_STEPS*HH*sizeof(float));
    float* hI  = (float*)alloc((size_t)T_STEPS*HH*sizeof(float));
    float* hpa = (float*)alloc((size_t)T_STEPS*HH*sizeof(float));
    float* hpb = (float*)alloc((size_t)T_STEPS*HH*sizeof(float));
    unsigned* Wbf0 = (unsigned*)alloc((size_t)NG*64*sizeof(unsigned));
    unsigned* Wbf1 = (unsigned*)alloc((size_t)NG*64*sizeof(unsigned));
    unsigned* Wbf2 = (unsigned*)alloc((size_t)NG*64*sizeof(unsigned));
    (void)ws_size; (void)in_sizes; (void)n_in; (void)out_size;

    scan_kernel<<<2, 64, 0, stream>>>(lenA, lenB, offsA, offsB);
    hipMemsetAsync(KsA, 0, 2*(size_t)KS_WORDS*sizeof(int), stream);
    build_meta<<<(T_STEPS+255)/256, 256, 0, stream>>>(lenA, offsA, idxA, KsA);
    build_meta<<<(T_STEPS+255)/256, 256, 0, stream>>>(lenB, offsB, idxB, KsB);
    conv_w<<<dim3(64,3), 256, 0, stream>>>(Wih_vad, Wih_img, Wih_lng, Wbf0, Wbf1, Wbf2);

    GemmArgs GA;
    GA.xsrc[0]=xA; GA.xsrc[1]=xB; GA.xsrc[2]=img;
    GA.psrc[0]=PA; GA.psrc[1]=PB;
    GA.idx[0]=idxA; GA.idx[1]=idxB;
    GA.Wb[0]=Wbf0; GA.Wb[1]=Wbf1; GA.Wb[2]=Wbf2;
    GA.bias[0]=b_vad; GA.bias[1]=b_img; GA.bias[2]=b_lng;
    GA.G[0]=GvA; GA.G[1]=GvB; GA.G[2]=Gim; GA.G[3]=GlA; GA.G[4]=GlB;
    GA.offs[0]=offsA; GA.offs[1]=offsB;
    gates_mfma<<<TOTROWS/64, 256, 0, stream>>>(GA);

    SeqArgs A;
    A.gx[0]=GvA;  A.gx[1]=GvB;  A.gx[2]=Gim;  A.gx[3]=GlA;  A.gx[4]=GlB;
    A.whh[0]=Whh_vad; A.whh[1]=Whh_vad; A.whh[2]=Whh_img; A.whh[3]=Whh_lng; A.whh[4]=Whh_lng;
    A.hout[0]=hA; A.hout[1]=hB; A.hout[2]=hI; A.hout[3]=hpa; A.hout[4]=hpb;
    A.offs[0]=nullptr; A.offs[1]=nullptr; A.offs[2]=nullptr; A.offs[3]=offsA; A.offs[4]=offsB;
    A.ks[0]=nullptr; A.ks[1]=nullptr; A.ks[2]=nullptr; A.ks[3]=KsA; A.ks[4]=KsB;
    seq_kernel<<<NBLK_SEQ, 256, 0, stream>>>(A);

    final_fc<<<(T_STEPS+255)/256, 256, 0, stream>>>(hA, hB, hI, hpa, hpb, fc_w, fc_b, out);
}

// Round 13
// 292.621 us; speedup vs baseline: 1.4301x; 1.0327x over previous
//
#include <hip/hip_runtime.h>
#include <hip/hip_bf16.h>

#define T_STEPS 8192
#define LMAX 12
#define DV 128
#define DI 65
#define NG 256   // 4*H
#define HH 64

#define SMAX (T_STEPS * LMAX)        // 98304 worst-case lang rows
#define GD_ROWS (T_STEPS + 64)       // dense G3 rows (pad for prefetch)
#define GL_ROWS (SMAX + 64)          // lang G3 rows
#define KS_WORDS (SMAX + 64)
#define WARM 64                      // validated r6
#define CH_VAD 128
#define CH_LNG 512
#define NBLK_SEQ (3*CH_VAD + 2*CH_LNG)   // 1408 blocks x 4 waves

// virtual row space for the fused gate GEMM (all 64-aligned)
#define SEG1 8192
#define SEG2 16384
#define SEG3 24576
#define SEG4 122880
#define TOTROWS 221184

typedef short s16x8 __attribute__((ext_vector_type(8)));
typedef float f32x4 __attribute__((ext_vector_type(4)));
typedef float v2f __attribute__((ext_vector_type(2)));

// packed fp32 FMA via compiler (emits v_pk_fma_f32; no asm marshalling)
__device__ __forceinline__ v2f pk2(v2f a, v2f b, v2f c){
#if __has_builtin(__builtin_elementwise_fma)
    return __builtin_elementwise_fma(a, b, c);
#else
    v2f r; r.x = fmaf(a.x, b.x, c.x); r.y = fmaf(a.y, b.y, c.y); return r;
#endif
}

#if __has_builtin(__builtin_amdgcn_exp2f)
__device__ __forceinline__ float fast_exp2(float x){ return __builtin_amdgcn_exp2f(x); }
#else
__device__ __forceinline__ float fast_exp2(float x){ return exp2f(x); }
#endif
#if __has_builtin(__builtin_amdgcn_rcpf)
__device__ __forceinline__ float fast_rcp(float x){ return __builtin_amdgcn_rcpf(x); }
#else
__device__ __forceinline__ float fast_rcp(float x){ return 1.0f/x; }
#endif

__device__ __forceinline__ float bf2f(unsigned short u){
    return __uint_as_float(((unsigned)u)<<16);
}
__device__ __forceinline__ unsigned short f2bf(float f){
    unsigned u = __float_as_uint(f);
    unsigned r = (u + 0x7fffu + ((u>>16)&1u)) >> 16;   // RNE
    return (unsigned short)r;
}
__device__ __forceinline__ unsigned packbf2(float a, float b){
    return (unsigned)f2bf(a) | ((unsigned)f2bf(b) << 16);
}

// quad-local xor shuffles via DPP (validated r4-r6)
__device__ __forceinline__ float dpp_xor1(float x){
    return __uint_as_float((unsigned)__builtin_amdgcn_update_dpp(
        0, (int)__float_as_uint(x), 0xB1, 0xF, 0xF, true));
}
__device__ __forceinline__ float dpp_xor2(float x){
    return __uint_as_float((unsigned)__builtin_amdgcn_update_dpp(
        0, (int)__float_as_uint(x), 0x4E, 0xF, 0xF, true));
}

// barrier: drain LDS only, leave global prefetches in flight.
#define BAR() asm volatile("s_waitcnt lgkmcnt(0)\ns_barrier" ::: "memory")

// ---------------- prefix scan of lens -> exclusive offsets (+ total at [T]) --
__global__ void scan_kernel(const int* __restrict__ lenA, const int* __restrict__ lenB,
                            int* __restrict__ offsA, int* __restrict__ offsB)
{
    const int* len = blockIdx.x ? lenB : lenA;
    int* offs = blockIdx.x ? offsB : offsA;
    int lane = threadIdx.x;   // 64 threads
    int carry = 0;
    for (int base = 0; base < T_STEPS; base += 64) {
        int x = len[base + lane];
        int v = x;
        #pragma unroll
        for (int d = 1; d < 64; d <<= 1) {
            int u = __shfl_up(v, d);
            if (lane >= d) v += u;
        }
        offs[base + lane] = carry + v - x;     // exclusive
        carry += __shfl(v, 63);
    }
    if (lane == 0) offs[T_STEPS] = carry;
}

// ---- build compacted-row -> source-row map, and per-row boundary counts ----
__global__ void build_meta(const int* __restrict__ len, const int* __restrict__ offs,
                           int* __restrict__ idx, int* __restrict__ Ks)
{
    int t = blockIdx.x * blockDim.x + threadIdx.x;
    if (t >= T_STEPS) return;
    int n = len[t];
    int o = offs[t];
    for (int p = 0; p < n; p++) idx[o + p] = t * LMAX + p;
    int e = offs[t + 1];
    if (e > 0) atomicAdd(&Ks[e - 1], 1);   // boundary after row e-1
}

// ---------------- bf16 weights for the GEMM B-operand ------------------------
__global__ __launch_bounds__(256) void conv_w(const float* __restrict__ Wv,
    const float* __restrict__ Wi, const float* __restrict__ Wl,
    unsigned* __restrict__ dv, unsigned* __restrict__ di, unsigned* __restrict__ dl)
{
    int mat = blockIdx.y;
    const float* W = mat==0 ? Wv : mat==1 ? Wi : Wl;
    unsigned* dst  = mat==0 ? dv : mat==1 ? di : dl;
    int D = (mat==1) ? DI : DV;
    int wv = threadIdx.x >> 6, l = threadIdx.x & 63;
    int j = blockIdx.x*4 + wv;
    const float* wr = W + (size_t)j * D;
    int c = 2*l;
    float a = (c < D)   ? wr[c]   : 0.f;
    float b = (c+1 < D) ? wr[c+1] : 0.f;
    dst[(size_t)j*64 + l] = packbf2(a, b);
}

// ---------------- fused gate GEMMs: fp32 in -> bf16 frag -> MFMA -> G3 -------
struct GemmArgs {
    const float*    xsrc[3];   // xA, xB, img
    const float*    psrc[2];   // PA, PB
    const int*      idx[2];
    const unsigned* Wb[3];
    const float*    bias[3];
    unsigned short* G[5];
    const int*      offs[2];
};

__global__ __launch_bounds__(256) void gates_mfma(GemmArgs A)
{
    int rowbase0 = blockIdx.x * 64;
    int seg;
    if      (rowbase0 < SEG1) seg = 0;
    else if (rowbase0 < SEG2) seg = 1;
    else if (rowbase0 < SEG3) seg = 2;
    else if (rowbase0 < SEG4) seg = 3;
    else                      seg = 4;
    int segbase = (seg==0)?0:(seg==1)?SEG1:(seg==2)?SEG2:(seg==3)?SEG3:SEG4;
    int wi      = (seg<2)?0:((seg==2)?1:2);
    int R = 0;
    if (seg >= 3) {
        R = A.offs[seg-3][T_STEPS];
        if (rowbase0 - segbase >= ((R + 63) & ~63)) return;
    }
    int tid = threadIdx.x, wv = tid >> 6, l = tid & 63;
    int m = l & 15, kg = l >> 4;
    int lrow = rowbase0 - segbase + wv * 16 + m;   // local row for this lane

    uint4 af0, af1, af2, af3;
    if (seg < 2 || seg >= 3) {
        const float* xr;
        bool ok = true;
        if (seg < 2) xr = A.xsrc[seg] + (size_t)lrow * DV;
        else { ok = lrow < R; xr = ok ? (A.psrc[seg-3] + (size_t)A.idx[seg-3][lrow] * DV) : nullptr; }
        auto lda = [&](int kb)->uint4 {
            uint4 u = make_uint4(0,0,0,0);
            if (ok) {
                float4 a = *(const float4*)(xr + kb);
                float4 b = *(const float4*)(xr + kb + 4);
                u.x = packbf2(a.x, a.y); u.y = packbf2(a.z, a.w);
                u.z = packbf2(b.x, b.y); u.w = packbf2(b.z, b.w);
            }
            return u;
        };
        af0 = lda(kg*8); af1 = lda(32+kg*8); af2 = lda(64+kg*8); af3 = lda(96+kg*8);
    } else {
        const float* xr = A.xsrc[2] + (size_t)lrow * DI;
        auto lda = [&](int kb)->uint4 {
            float v[8];
            #pragma unroll
            for (int j = 0; j < 8; j++) { int c = kb + j; v[j] = (c < DI) ? xr[c] : 0.f; }
            return make_uint4(packbf2(v[0],v[1]), packbf2(v[2],v[3]),
                              packbf2(v[4],v[5]), packbf2(v[6],v[7]));
        };
        af0 = lda(kg*8); af1 = lda(32+kg*8); af2 = lda(64+kg*8); af3 = lda(96+kg*8);
    }

    const unsigned* Wb = A.Wb[wi] + (size_t)m * 64 + kg * 4;
    const float* bias = A.bias[wi];

    f32x4 acc[16];
    #pragma unroll
    for (int n0 = 0; n0 < 16; n0++) acc[n0] = (f32x4){0.f,0.f,0.f,0.f};

    #pragma unroll
    for (int n0 = 0; n0 < 16; n0++) {
        const unsigned* wp = Wb + (size_t)n0 * 16 * 64;
        uint4 b0 = *(const uint4*)(wp);
        uint4 b1 = *(const uint4*)(wp + 16);
        uint4 b2 = *(const uint4*)(wp + 32);
        uint4 b3 = *(const uint4*)(wp + 48);
        acc[n0] = __builtin_amdgcn_mfma_f32_16x16x32_bf16(
            __builtin_bit_cast(s16x8, af0), __builtin_bit_cast(s16x8, b0), acc[n0], 0,0,0);
        acc[n0] = __builtin_amdgcn_mfma_f32_16x16x32_bf16(
            __builtin_bit_cast(s16x8, af1), __builtin_bit_cast(s16x8, b1), acc[n0], 0,0,0);
        acc[n0] = __builtin_amdgcn_mfma_f32_16x16x32_bf16(
            __builtin_bit_cast(s16x8, af2), __builtin_bit_cast(s16x8, b2), acc[n0], 0,0,0);
        acc[n0] = __builtin_amdgcn_mfma_f32_16x16x32_bf16(
            __builtin_bit_cast(s16x8, af3), __builtin_bit_cast(s16x8, b3), acc[n0], 0,0,0);
    }

    // gate j = n0*16+m = 64q + 16b + m  (q=n0>>2, b=n0&3) -> cell=16b+m
    unsigned short* Gp = A.G[seg];
    int localrow = rowbase0 - segbase + wv * 16 + kg * 4;
    #pragma unroll
    for (int b = 0; b < 4; b++) {
        int cell = 16*b + m;
        float bj0 = bias[      16*b + m];
        float bj1 = bias[ 64 + 16*b + m];
        float bj2 = bias[128 + 16*b + m];
        float bj3 = bias[192 + 16*b + m];
        #pragma unroll
        for (int r = 0; r < 4; r++) {
            ushort4 o;
            o.x = f2bf(acc[b   ][r] + bj0);
            o.y = f2bf(acc[4+b ][r] + bj1);
            o.z = f2bf(acc[8+b ][r] + bj2);
            o.w = f2bf(acc[12+b][r] + bj3);
            *(ushort4*)(Gp + (size_t)(localrow + r)*NG + cell*4) = o;
        }
    }
}

// ---------------- chunked-parallel recurrence: 4 waves per chunk -------------
// Lane (wave wv, lane l): k-slice s=l&3, cell=wv*16+(l>>2). float2 pk-FMA
// matvec via __builtin_elementwise_fma (compiler-native v_pk_fma_f32 —
// inline-asm pk marshalling was slower, r11); quad DPP all-reduce; warm/body
// loop split removes emission logic from warm steps; lgkm-only barrier.
struct SeqArgs {
    const unsigned short* gx[5];    // G3 [row][cell*4+q]
    const float*          whh[5];   // fp32 Whh [256][64]
    float*                hout[5];
    const int*            offs[5];
    const int*            ks[5];
};

// EMIT is a literal (0/1) so dead code folds per expansion.
#define DO_STEP(gxraw, kc, row, pin, pout, EMIT) do { \
  float gxv = bf2f(gxraw); \
  v2f A0; A0.x = gxv * msk0; A0.y = 0.f; \
  v2f A1; A1.x = gxv * msk1; A1.y = 0.f; \
  v2f A2; A2.x = gxv * msk2; A2.y = 0.f; \
  v2f A3; A3.x = gxv * msk3; A3.y = 0.f; \
  const float4* h4_ = (const float4*)((pin) + (s << 4)); \
  float4 H0 = h4_[0], H1 = h4_[1], H2 = h4_[2], H3 = h4_[3]; \
  v2f hv2[8]; \
  hv2[0].x=H0.x; hv2[0].y=H0.y; hv2[1].x=H0.z; hv2[1].y=H0.w; \
  hv2[2].x=H1.x; hv2[2].y=H1.y; hv2[3].x=H1.z; hv2[3].y=H1.w; \
  hv2[4].x=H2.x; hv2[4].y=H2.y; hv2[5].x=H2.z; hv2[5].y=H2.w; \
  hv2[6].x=H3.x; hv2[6].y=H3.y; hv2[7].x=H3.z; hv2[7].y=H3.w; \
  _Pragma("unroll") \
  for (int p = 0; p < 8; p++) { \
    A0 = pk2(wreg[0][p], hv2[p], A0); \
    A1 = pk2(wreg[1][p], hv2[p], A1); \
    A2 = pk2(wreg[2][p], hv2[p], A2); \
    A3 = pk2(wreg[3][p], hv2[p], A3); \
  } \
  float a0 = A0.x + A0.y, a1 = A1.x + A1.y, a2 = A2.x + A2.y, a3 = A3.x + A3.y; \
  a0 += dpp_xor1(a0); a1 += dpp_xor1(a1); a2 += dpp_xor1(a2); a3 += dpp_xor1(a3); \
  a0 += dpp_xor2(a0); a1 += dpp_xor2(a1); a2 += dpp_xor2(a2); a3 += dpp_xor2(a3); \
  float i_ = fast_rcp(1.f + fast_exp2(a0 * kSig)); \
  float f_ = fast_rcp(1.f + fast_exp2(a1 * kSig)); \
  float g_ = fmaf(-2.f, fast_rcp(1.f + fast_exp2(a2 * kTan)), 1.f); \
  float o_ = fast_rcp(1.f + fast_exp2(a3 * kSig)); \
  c = fmaf(f_, c, i_ * g_); \
  float tc = fmaf(-2.f, fast_rcp(1.f + fast_exp2(c * kTan)), 1.f); \
  float h = o_ * tc; \
  if (s == 0) { \
    (pout)[cell] = h; \
    if (EMIT) { \
      bool em_ = (row) < E; \
      if (!isLang) { if (em_) hout[(size_t)(row)*HH + cell] = h; } \
      else if (em_) for (int i = 0; i < (kc); i++) hout[(size_t)(tptr + i)*HH + cell] = h; \
    } \
  } \
  if (EMIT && isLang && ((row) < E)) tptr += (kc); \
  BAR(); \
} while(0)

__global__ __launch_bounds__(256,1) void seq_kernel(SeqArgs A)
{
    int bid = blockIdx.x;
    int chain, chunk, nch;
    if (bid < 3*CH_VAD) { chain = bid / CH_VAD; chunk = bid % CH_VAD; nch = CH_VAD; }
    else { int b2 = bid - 3*CH_VAD; chain = 3 + b2 / CH_LNG; chunk = b2 % CH_LNG; nch = CH_LNG; }

    const unsigned short* __restrict__ G3 = A.gx[chain];
    const float* __restrict__ Whh = A.whh[chain];
    float* __restrict__ hout = A.hout[chain];
    const int* __restrict__ offs = A.offs[chain];
    const int* __restrict__ Ks = A.ks[chain];
    const bool isLang = (offs != nullptr);

    const int R = isLang ? offs[T_STEPS] : T_STEPS;
    const int len = ((R + nch - 1) / nch + 3) & ~3;
    const int S = chunk * len;
    if (chunk > 0 && S >= R) return;
    const int E = min(S + len, R);
    const int start = (S > WARM) ? (S - WARM) : 0;

    int tid = threadIdx.x, wv = tid >> 6, l = tid & 63;
    int s = l & 3;
    int cell = (wv << 4) | (l >> 2);

    int tptr = 0;
    if (isLang) {
        int lo = 1, hi = T_STEPS + 1;
        while (lo < hi) {
            int mid = (lo + hi) >> 1;
            if (offs[mid] <= S) lo = mid + 1; else hi = mid;
        }
        tptr = lo - 1;
    }

    // wreg[q][p] = Whh[q*64+cell][16s + 2p .. 2p+1]
    v2f wreg[4][8];
    #pragma unroll
    for (int q = 0; q < 4; q++) {
        const v2f* wrow = (const v2f*)(Whh + (size_t)(q*HH + cell)*HH + s*16);
        #pragma unroll
        for (int p = 0; p < 8; p++) wreg[q][p] = wrow[p];
    }

    float msk0 = (s == 0) ? 1.f : 0.f;
    float msk1 = (s == 1) ? 1.f : 0.f;
    float msk2 = (s == 2) ? 1.f : 0.f;
    float msk3 = (s == 3) ? 1.f : 0.f;

    __shared__ __align__(16) float hb[2][HH];
    if (tid < HH) { hb[0][tid] = 0.f; hb[1][tid] = 0.f; }

    float c = 0.f;
    const float kSig = -1.44269504088896340736f;  // -log2(e)
    const float kTan =  2.88539008177792681472f;  //  2*log2(e)

    if (isLang && chunk == 0 && s == 0)
        for (int i = 0; i < tptr; i++) hout[(size_t)i*HH + cell] = 0.f;

    // Gx stream: lane value for row r is G3[r*NG + wv*64 + l]  (coalesced 2B)
    const unsigned short* gp = G3 + (size_t)start * NG + (wv << 6) + l;
    int rix = start;
    unsigned short ga0 = gp[0*NG], ga1 = gp[1*NG], ga2 = gp[2*NG], ga3 = gp[3*NG];
    gp += 4*NG;

    BAR();   // hb[0] visible to all waves

    // ---- warm phase: no emission logic, no Ks traffic ----
    int witer = (S - start) >> 2;
    for (int it = 0; it < witer; ++it) {
        unsigned short nb0 = gp[0*NG], nb1 = gp[1*NG], nb2 = gp[2*NG], nb3 = gp[3*NG];
        DO_STEP(ga0, 0, rix + 0, hb[0], hb[1], 0);
        DO_STEP(ga1, 0, rix + 1, hb[1], hb[0], 0);
        DO_STEP(ga2, 0, rix + 2, hb[0], hb[1], 0);
        DO_STEP(ga3, 0, rix + 3, hb[1], hb[0], 0);
        ga0 = nb0; ga1 = nb1; ga2 = nb2; ga3 = nb3;
        gp += 4*NG;
        rix += 4;
    }

    // ---- body phase: rows [S, E), em = row < E ----
    int4 kcur = isLang ? *(const int4*)(Ks + rix) : make_int4(0,0,0,0);
    int biter = (E - S + 3) >> 2;
    for (int it = 0; it < biter; ++it) {
        unsigned short nb0 = gp[0*NG], nb1 = gp[1*NG], nb2 = gp[2*NG], nb3 = gp[3*NG];
        int4 knext = isLang ? *(const int4*)(Ks + rix + 4) : make_int4(0,0,0,0);
        DO_STEP(ga0, kcur.x, rix + 0, hb[0], hb[1], 1);
        DO_STEP(ga1, kcur.y, rix + 1, hb[1], hb[0], 1);
        DO_STEP(ga2, kcur.z, rix + 2, hb[0], hb[1], 1);
        DO_STEP(ga3, kcur.w, rix + 3, hb[1], hb[0], 1);
        ga0 = nb0; ga1 = nb1; ga2 = nb2; ga3 = nb3;
        kcur = knext;
        gp += 4*NG;
        rix += 4;
    }
}

// ---------------- final: alpha[t] = sigmoid(fc_w . concat + fc_b) ------------
__global__ __launch_bounds__(256) void final_fc(const float* __restrict__ hA,
    const float* __restrict__ hB, const float* __restrict__ hI,
    const float* __restrict__ hpa, const float* __restrict__ hpb,
    const float* __restrict__ fcw, const float* __restrict__ fcb,
    float* __restrict__ out)
{
    int t = blockIdx.x * blockDim.x + threadIdx.x;
    if (t >= T_STEPS) return;
    float acc = fcb[0];
    const float* hs0 = hA  + (size_t)t*HH;
    const float* hs1 = hB  + (size_t)t*HH;
    const float* hs2 = hI  + (size_t)t*HH;
    const float* hs3 = hpa + (size_t)t*HH;
    const float* hs4 = hpb + (size_t)t*HH;
    #pragma unroll
    for (int k = 0; k < HH; k++) acc = fmaf(hs0[k], fcw[0*HH+k], acc);
    #pragma unroll
    for (int k = 0; k < HH; k++) acc = fmaf(hs1[k], fcw[1*HH+k], acc);
    #pragma unroll
    for (int k = 0; k < HH; k++) acc = fmaf(hs2[k], fcw[2*HH+k], acc);
    #pragma unroll
    for (int k = 0; k < HH; k++) acc = fmaf(hs3[k], fcw[3*HH+k], acc);
    #pragma unroll
    for (int k = 0; k < HH; k++) acc = fmaf(hs4[k], fcw[4*HH+k], acc);
    out[t] = fast_rcp(1.f + fast_exp2(acc * -1.44269504088896340736f));
}

// ---------------- launch -----------------------------------------------------
extern "C" void kernel_launch(void* const* d_in, const int* in_sizes, int n_in,
                              void* d_out, int out_size, void* d_ws, size_t ws_size,
                              hipStream_t stream)
{
    const float* xA      = (const float*)d_in[0];
    const float* xB      = (const float*)d_in[1];
    const float* img     = (const float*)d_in[2];
    const float* PA      = (const float*)d_in[3];
    const float* PB      = (const float*)d_in[4];
    const int*   lenA    = (const int*)d_in[5];
    const int*   lenB    = (const int*)d_in[6];
    const float* Wih_vad = (const float*)d_in[7];
    const float* Whh_vad = (const float*)d_in[8];
    const float* b_vad   = (const float*)d_in[9];
    const float* Wih_img = (const float*)d_in[10];
    const float* Whh_img = (const float*)d_in[11];
    const float* b_img   = (const float*)d_in[12];
    const float* Wih_lng = (const float*)d_in[13];
    const float* Whh_lng = (const float*)d_in[14];
    const float* b_lng   = (const float*)d_in[15];
    const float* fc_w    = (const float*)d_in[16];
    const float* fc_b    = (const float*)d_in[17];
    float* out = (float*)d_out;

    char* ws = (char*)d_ws;
    size_t off = 0;
    auto alloc = [&](size_t bytes) -> void* {
        void* p = ws + off;
        off += (bytes + 255) & ~(size_t)255;
        return p;
    };
    int* offsA = (int*)alloc((T_STEPS+1)*sizeof(int));
    int* offsB = (int*)alloc((T_STEPS+1)*sizeof(int));
    int* idxA  = (int*)alloc((size_t)SMAX*sizeof(int));
    int* idxB  = (int*)alloc((size_t)SMAX*sizeof(int));
    int* KsA   = (int*)alloc((size_t)KS_WORDS*sizeof(int));   // contiguous with KsB
    int* KsB   = (int*)alloc((size_t)KS_WORDS*sizeof(int));
    unsigned short* GvA = (unsigned short*)alloc((size_t)GD_ROWS*NG*2);
    unsigned short* GvB = (unsigned short*)alloc((size_t)GD_ROWS*NG*2);
    unsigned short* Gim = (unsigned short*)alloc((size_t)GD_ROWS*NG*2);
    unsigned short* GlA = (unsigned short*)alloc((size_t)GL_ROWS*NG*2);
    unsigned short* GlB = (unsigned short*)alloc((size_t)GL_ROWS*NG*2);
    float* hA  = (float*)alloc((size_t)T_STEPS*HH*sizeof(float));
    float* hB  = (float*)alloc((size_t)T_STEPS*HH*sizeof(float));
    float* hI  = (float*)alloc((size_t)T_STEPS*HH*sizeof(float));
    float* hpa = (float*)alloc((size_t)T_STEPS*HH*sizeof(float));
    float* hpb = (float*)alloc((size_t)T_STEPS*HH*sizeof(float));
    unsigned* Wbf0 = (unsigned*)alloc((size_t)NG*64*sizeof(unsigned));
    unsigned* Wbf1 = (unsigned*)alloc((size_t)NG*64*sizeof(unsigned));
    unsigned* Wbf2 = (unsigned*)alloc((size_t)NG*64*sizeof(unsigned));
    (void)ws_size; (void)in_sizes; (void)n_in; (void)out_size;

    scan_kernel<<<2, 64, 0, stream>>>(lenA, lenB, offsA, offsB);
    hipMemsetAsync(KsA, 0, 2*(size_t)KS_WORDS*sizeof(int), stream);
    build_meta<<<(T_STEPS+255)/256, 256, 0, stream>>>(lenA, offsA, idxA, KsA);
    build_meta<<<(T_STEPS+255)/256, 256, 0, stream>>>(lenB, offsB, idxB, KsB);
    conv_w<<<dim3(64,3), 256, 0, stream>>>(Wih_vad, Wih_img, Wih_lng, Wbf0, Wbf1, Wbf2);

    GemmArgs GA;
    GA.xsrc[0]=xA; GA.xsrc[1]=xB; GA.xsrc[2]=img;
    GA.psrc[0]=PA; GA.psrc[1]=PB;
    GA.idx[0]=idxA; GA.idx[1]=idxB;
    GA.Wb[0]=Wbf0; GA.Wb[1]=Wbf1; GA.Wb[2]=Wbf2;
    GA.bias[0]=b_vad; GA.bias[1]=b_img; GA.bias[2]=b_lng;
    GA.G[0]=GvA; GA.G[1]=GvB; GA.G[2]=Gim; GA.G[3]=GlA; GA.G[4]=GlB;
    GA.offs[0]=offsA; GA.offs[1]=offsB;
    gates_mfma<<<TOTROWS/64, 256, 0, stream>>>(GA);

    SeqArgs A;
    A.gx[0]=GvA;  A.gx[1]=GvB;  A.gx[2]=Gim;  A.gx[3]=GlA;  A.gx[4]=GlB;
    A.whh[0]=Whh_vad; A.whh[1]=Whh_vad; A.whh[2]=Whh_img; A.whh[3]=Whh_lng; A.whh[4]=Whh_lng;
    A.hout[0]=hA; A.hout[1]=hB; A.hout[2]=hI; A.hout[3]=hpa; A.hout[4]=hpb;
    A.offs[0]=nullptr; A.offs[1]=nullptr; A.offs[2]=nullptr; A.offs[3]=offsA; A.offs[4]=offsB;
    A.ks[0]=nullptr; A.ks[1]=nullptr; A.ks[2]=nullptr; A.ks[3]=KsA; A.ks[4]=KsB;
    seq_kernel<<<NBLK_SEQ, 256, 0, stream>>>(A);

    final_fc<<<(T_STEPS+255)/256, 256, 0, stream>>>(hA, hB, hI, hpa, hpb, fc_w, fc_b, out);
}

// Round 14
// 261.245 us; speedup vs baseline: 1.6019x; 1.1201x over previous
//
#include <hip/hip_runtime.h>
#include <hip/hip_bf16.h>

#define T_STEPS 8192
#define LMAX 12
#define DV 128
#define DI 65
#define NG 256   // 4*H
#define HH 64

#define SMAX (T_STEPS * LMAX)        // 98304 worst-case lang rows
#define GD_ROWS (T_STEPS + 64)       // dense G3 rows (pad for prefetch)
#define GL_ROWS (SMAX + 64)          // lang G3 rows
#define KS_WORDS (SMAX + 64)
#define WARM 64                      // validated r6
#define BLK_VAD 16                   // blocks per vad chain (16 chunks each -> CH=256)
#define BLK_LNG 64                   // blocks per lang chain (CH=1024)
#define NBLK_SEQ (3*BLK_VAD + 2*BLK_LNG)   // 176 blocks x 4 waves

// virtual row space for the fused gate GEMM (all 64-aligned)
#define SEG1 8192
#define SEG2 16384
#define SEG3 24576
#define SEG4 122880
#define TOTROWS 221184

typedef short s16x8 __attribute__((ext_vector_type(8)));
typedef float f32x4 __attribute__((ext_vector_type(4)));

#if __has_builtin(__builtin_amdgcn_exp2f)
__device__ __forceinline__ float fast_exp2(float x){ return __builtin_amdgcn_exp2f(x); }
#else
__device__ __forceinline__ float fast_exp2(float x){ return exp2f(x); }
#endif
#if __has_builtin(__builtin_amdgcn_rcpf)
__device__ __forceinline__ float fast_rcp(float x){ return __builtin_amdgcn_rcpf(x); }
#else
__device__ __forceinline__ float fast_rcp(float x){ return 1.0f/x; }
#endif

__device__ __forceinline__ float bf2f(unsigned short u){
    return __uint_as_float(((unsigned)u)<<16);
}
__device__ __forceinline__ unsigned short f2bf(float f){
    unsigned u = __float_as_uint(f);
    unsigned r = (u + 0x7fffu + ((u>>16)&1u)) >> 16;   // RNE
    return (unsigned short)r;
}
__device__ __forceinline__ unsigned packbf2(float a, float b){
    return (unsigned)f2bf(a) | ((unsigned)f2bf(b) << 16);
}

// quad-local xor shuffles via DPP (validated r4-r13)
__device__ __forceinline__ float dpp_xor1(float x){
    return __uint_as_float((unsigned)__builtin_amdgcn_update_dpp(
        0, (int)__float_as_uint(x), 0xB1, 0xF, 0xF, true));
}
__device__ __forceinline__ float dpp_xor2(float x){
    return __uint_as_float((unsigned)__builtin_amdgcn_update_dpp(
        0, (int)__float_as_uint(x), 0x4E, 0xF, 0xF, true));
}

__device__ __forceinline__ f32x4 MF(uint4 a, uint4 b, f32x4 c){
    return __builtin_amdgcn_mfma_f32_16x16x32_bf16(
        __builtin_bit_cast(s16x8, a), __builtin_bit_cast(s16x8, b), c, 0, 0, 0);
}

// barrier: drain LDS only, leave global prefetches in flight.
#define BAR() asm volatile("s_waitcnt lgkmcnt(0)\ns_barrier" ::: "memory")

// ---------------- prefix scan of lens -> exclusive offsets (+ total at [T]) --
__global__ void scan_kernel(const int* __restrict__ lenA, const int* __restrict__ lenB,
                            int* __restrict__ offsA, int* __restrict__ offsB)
{
    const int* len = blockIdx.x ? lenB : lenA;
    int* offs = blockIdx.x ? offsB : offsA;
    int lane = threadIdx.x;   // 64 threads
    int carry = 0;
    for (int base = 0; base < T_STEPS; base += 64) {
        int x = len[base + lane];
        int v = x;
        #pragma unroll
        for (int d = 1; d < 64; d <<= 1) {
            int u = __shfl_up(v, d);
            if (lane >= d) v += u;
        }
        offs[base + lane] = carry + v - x;     // exclusive
        carry += __shfl(v, 63);
    }
    if (lane == 0) offs[T_STEPS] = carry;
}

// ---- build compacted-row -> source-row map, and per-row boundary counts ----
__global__ void build_meta(const int* __restrict__ len, const int* __restrict__ offs,
                           int* __restrict__ idx, int* __restrict__ Ks)
{
    int t = blockIdx.x * blockDim.x + threadIdx.x;
    if (t >= T_STEPS) return;
    int n = len[t];
    int o = offs[t];
    for (int p = 0; p < n; p++) idx[o + p] = t * LMAX + p;
    int e = offs[t + 1];
    if (e > 0) atomicAdd(&Ks[e - 1], 1);   // boundary after row e-1
}

// ---------------- bf16 weights for the gate GEMM B-operand -------------------
__global__ __launch_bounds__(256) void conv_w(const float* __restrict__ Wv,
    const float* __restrict__ Wi, const float* __restrict__ Wl,
    unsigned* __restrict__ dv, unsigned* __restrict__ di, unsigned* __restrict__ dl)
{
    int mat = blockIdx.y;
    const float* W = mat==0 ? Wv : mat==1 ? Wi : Wl;
    unsigned* dst  = mat==0 ? dv : mat==1 ? di : dl;
    int D = (mat==1) ? DI : DV;
    int wv = threadIdx.x >> 6, l = threadIdx.x & 63;
    int j = blockIdx.x*4 + wv;
    const float* wr = W + (size_t)j * D;
    int c = 2*l;
    float a = (c < D)   ? wr[c]   : 0.f;
    float b = (c+1 < D) ? wr[c+1] : 0.f;
    dst[(size_t)j*64 + l] = packbf2(a, b);
}

// ---- Whh reordered+bf16 for the seq MFMA: Wseq[n][k], n = cell*4+q ----------
__global__ __launch_bounds__(256) void conv_wseq(const float* __restrict__ Wv,
    const float* __restrict__ Wi, const float* __restrict__ Wl,
    unsigned* __restrict__ d0, unsigned* __restrict__ d1, unsigned* __restrict__ d2)
{
    int mat = blockIdx.x;
    const float* W = mat==0 ? Wv : mat==1 ? Wi : Wl;
    unsigned* dst  = mat==0 ? d0 : mat==1 ? d1 : d2;
    int n = threadIdx.x;                 // 0..255
    int cell = n >> 2, q = n & 3;
    const float* src = W + (size_t)(q*HH + cell) * HH;
    unsigned* drow = dst + (size_t)n * 32;
    #pragma unroll
    for (int p = 0; p < 32; p++)
        drow[p] = packbf2(src[2*p], src[2*p+1]);
}

// ---------------- fused gate GEMMs: fp32 in -> bf16 frag -> MFMA -> G3 -------
struct GemmArgs {
    const float*    xsrc[3];   // xA, xB, img
    const float*    psrc[2];   // PA, PB
    const int*      idx[2];
    const unsigned* Wb[3];
    const float*    bias[3];
    unsigned short* G[5];
    const int*      offs[2];
};

__global__ __launch_bounds__(256) void gates_mfma(GemmArgs A)
{
    int rowbase0 = blockIdx.x * 64;
    int seg;
    if      (rowbase0 < SEG1) seg = 0;
    else if (rowbase0 < SEG2) seg = 1;
    else if (rowbase0 < SEG3) seg = 2;
    else if (rowbase0 < SEG4) seg = 3;
    else                      seg = 4;
    int segbase = (seg==0)?0:(seg==1)?SEG1:(seg==2)?SEG2:(seg==3)?SEG3:SEG4;
    int wi      = (seg<2)?0:((seg==2)?1:2);
    int R = 0;
    if (seg >= 3) {
        R = A.offs[seg-3][T_STEPS];
        if (rowbase0 - segbase >= ((R + 63) & ~63)) return;
    }
    int tid = threadIdx.x, wv = tid >> 6, l = tid & 63;
    int m = l & 15, kg = l >> 4;
    int lrow = rowbase0 - segbase + wv * 16 + m;   // local row for this lane

    uint4 af0, af1, af2, af3;
    if (seg < 2 || seg >= 3) {
        const float* xr;
        bool ok = true;
        if (seg < 2) xr = A.xsrc[seg] + (size_t)lrow * DV;
        else { ok = lrow < R; xr = ok ? (A.psrc[seg-3] + (size_t)A.idx[seg-3][lrow] * DV) : nullptr; }
        auto lda = [&](int kb)->uint4 {
            uint4 u = make_uint4(0,0,0,0);
            if (ok) {
                float4 a = *(const float4*)(xr + kb);
                float4 b = *(const float4*)(xr + kb + 4);
                u.x = packbf2(a.x, a.y); u.y = packbf2(a.z, a.w);
                u.z = packbf2(b.x, b.y); u.w = packbf2(b.z, b.w);
            }
            return u;
        };
        af0 = lda(kg*8); af1 = lda(32+kg*8); af2 = lda(64+kg*8); af3 = lda(96+kg*8);
    } else {
        const float* xr = A.xsrc[2] + (size_t)lrow * DI;
        auto lda = [&](int kb)->uint4 {
            float v[8];
            #pragma unroll
            for (int j = 0; j < 8; j++) { int c = kb + j; v[j] = (c < DI) ? xr[c] : 0.f; }
            return make_uint4(packbf2(v[0],v[1]), packbf2(v[2],v[3]),
                              packbf2(v[4],v[5]), packbf2(v[6],v[7]));
        };
        af0 = lda(kg*8); af1 = lda(32+kg*8); af2 = lda(64+kg*8); af3 = lda(96+kg*8);
    }

    const unsigned* Wb = A.Wb[wi] + (size_t)m * 64 + kg * 4;
    const float* bias = A.bias[wi];

    f32x4 acc[16];
    #pragma unroll
    for (int n0 = 0; n0 < 16; n0++) acc[n0] = (f32x4){0.f,0.f,0.f,0.f};

    #pragma unroll
    for (int n0 = 0; n0 < 16; n0++) {
        const unsigned* wp = Wb + (size_t)n0 * 16 * 64;
        uint4 b0 = *(const uint4*)(wp);
        uint4 b1 = *(const uint4*)(wp + 16);
        uint4 b2 = *(const uint4*)(wp + 32);
        uint4 b3 = *(const uint4*)(wp + 48);
        acc[n0] = MF(af0, b0, acc[n0]);
        acc[n0] = MF(af1, b1, acc[n0]);
        acc[n0] = MF(af2, b2, acc[n0]);
        acc[n0] = MF(af3, b3, acc[n0]);
    }

    // gate j = n0*16+m = 64q + 16b + m  (q=n0>>2, b=n0&3) -> cell=16b+m
    unsigned short* Gp = A.G[seg];
    int localrow = rowbase0 - segbase + wv * 16 + kg * 4;
    #pragma unroll
    for (int b = 0; b < 4; b++) {
        int cell = 16*b + m;
        float bj0 = bias[      16*b + m];
        float bj1 = bias[ 64 + 16*b + m];
        float bj2 = bias[128 + 16*b + m];
        float bj3 = bias[192 + 16*b + m];
        #pragma unroll
        for (int r = 0; r < 4; r++) {
            ushort4 o;
            o.x = f2bf(acc[b   ][r] + bj0);
            o.y = f2bf(acc[4+b ][r] + bj1);
            o.z = f2bf(acc[8+b ][r] + bj2);
            o.w = f2bf(acc[12+b][r] + bj3);
            *(ushort4*)(Gp + (size_t)(localrow + r)*NG + cell*4) = o;
        }
    }
}

// ---------------- MFMA-based recurrence: 16 chunks per block -----------------
// Per step: D[16 rows=chunks][256 cols=cell*4+q] = A[16][64]·Wseq^T + Gx,
// A = h as 2 bf16 planes (h = b1 + b2, ~2^-18 effective error).
// D layout (verified): col = l&15 (+16*n0+64*wv), row = (l>>4)*4 + reg.
// Gate types of one cell sit in quad lanes -> in-register 4x4 quad transpose
// (2 DPP butterfly stages; after it reg q = gate q of row l&3).
// h planes go to XOR-swizzled LDS for the next step's A-frags.
struct SeqArgs {
    const unsigned short* gx[5];    // G3 [row][cell*4+q]
    const unsigned*       wseq[5];  // Wseq [256][32] uints (bf16 pairs)
    float*                hout[5];
    const int*            offs[5];
    const int*            ks[5];
};

__global__ __launch_bounds__(256,1) void seq_kernel(SeqArgs A)
{
    int bid = blockIdx.x;
    int chain, blk;
    if (bid < 3*BLK_VAD) { chain = bid / BLK_VAD; blk = bid % BLK_VAD; }
    else { int b2 = bid - 3*BLK_VAD; chain = 3 + b2 / BLK_LNG; blk = b2 % BLK_LNG; }

    const unsigned short* __restrict__ G3 = A.gx[chain];
    const unsigned* __restrict__ Wq = A.wseq[chain];
    float* __restrict__ hout = A.hout[chain];
    const int* __restrict__ offs = A.offs[chain];
    const int* __restrict__ Ks = A.ks[chain];
    const bool isLang = (offs != nullptr);

    const int R = isLang ? offs[T_STEPS] : T_STEPS;
    const int CH = isLang ? (BLK_LNG*16) : (BLK_VAD*16);
    const int len = (R + CH - 1) / CH;
    const int nsteps = len + WARM;

    int tid = threadIdx.x, wv = tid >> 6, l = tid & 63;
    int cl = l & 15, kg = l >> 4;            // A/B-frag roles (kg == rg)
    int rg = l >> 4, a = (l >> 2) & 3, rr = l & 3;  // D roles

    // B-frags (static): Bf[n0][kk] = Wseq[wv*64+n0*16+cl][k=32kk+8kg..+8]
    uint4 Bf[4][2];
    #pragma unroll
    for (int n0 = 0; n0 < 4; n0++)
        #pragma unroll
        for (int kk = 0; kk < 2; kk++)
            Bf[n0][kk] = *(const uint4*)(Wq + (size_t)(wv*64 + n0*16 + cl)*32 + kk*16 + kg*4);

    // Gx row pointers for chunk slots m = 4*rg + r  (D rows)
    const unsigned short* gptr0; const unsigned short* gptr1;
    const unsigned short* gptr2; const unsigned short* gptr3;
    {
        auto mk = [&](int r)->const unsigned short* {
            int gc = blk*16 + 4*rg + r;
            int S = gc * len;
            int st = (S < R) ? max(0, S - WARM) : 0;
            return G3 + (size_t)st * NG + wv*64 + cl;
        };
        gptr0 = mk(0); gptr1 = mk(1); gptr2 = mk(2); gptr3 = mk(3);
    }

    // emission chunk m_e = 4*rg + rr  (post-transpose row)
    int gcE = blk*16 + 4*rg + rr;
    int S_e = gcE * len;
    bool aliveE = S_e < R;
    int E_e = min(S_e + len, R);
    int start_e = aliveE ? max(0, S_e - WARM) : 0;
    int rix = start_e;

    int tptr = 0;
    if (isLang && aliveE) {
        int lo = 1, hi = T_STEPS + 1;
        while (lo < hi) { int mid=(lo+hi)>>1; if (offs[mid] <= S_e) lo = mid+1; else hi = mid; }
        tptr = lo - 1;
    }
    // leading empty timesteps -> zero hp rows (chunk 0 only)
    if (isLang && blk == 0 && rg == 0 && rr == 0) {
        for (int i = 0; i < tptr; i++)
            #pragma unroll
            for (int n0 = 0; n0 < 4; n0++)
                hout[(size_t)i*HH + wv*16 + n0*4 + a] = 0.f;
    }

    // LDS: h planes [buf][plane][row 16][cell 64] bf16, XOR-swizzled bytes
    __shared__ unsigned short hb[2][2][16][64];
    {
        uint4* p = (uint4*)hb;   // 512 x uint4 = 8KB
        p[tid] = make_uint4(0,0,0,0);
        p[tid+256] = make_uint4(0,0,0,0);
    }
    __syncthreads();

    float c0=0.f, c1=0.f, c2=0.f, c3=0.f;   // c per n0 for (cell(n0), row_e)

    // preload gx for step 0
    unsigned short gxc[4][4];   // [reg r][n0]
    #pragma unroll
    for (int r = 0; r < 4; r++) {
        const unsigned short* gp = (r==0)?gptr0:(r==1)?gptr1:(r==2)?gptr2:gptr3;
        #pragma unroll
        for (int n0 = 0; n0 < 4; n0++) gxc[r][n0] = gp[n0*16];
    }

    const float kSig = -1.44269504088896340736f;
    const float kTan =  2.88539008177779268f + 0.0f;  // see below
    // (use precise constant)
    const float kTan2 = 2.88539008177792681472f;

    bool q0 = (rr & 1) != 0, q1 = (rr & 2) != 0;
    int buf = 0;
    int rowe = 4*rg + rr;
    int swe = (rowe & 7) << 4;
    int cbw = wv*32 + a*2;              // + n0*8, XOR swe
    int swr = (cl & 7) << 4;            // A-frag read swizzle (row = cl)

    for (int it = 0; it < nsteps; ++it) {
        // prefetch next-step gx
        unsigned short gxn[4][4];
        #pragma unroll
        for (int r = 0; r < 4; r++) {
            const unsigned short* gp = (r==0)?gptr0:(r==1)?gptr1:(r==2)?gptr2:gptr3;
            #pragma unroll
            for (int n0 = 0; n0 < 4; n0++) gxn[r][n0] = gp[NG + n0*16];
        }
        int kcnt = isLang ? Ks[rix] : 0;

        // A-frags from hb[buf] (planes 0,1 x k-halves 0,1)
        uint4 A0k0, A0k1, A1k0, A1k1;
        {
            char* base = (char*)hb;
            int b0 = ((buf*2+0)*16 + cl)*128;
            int b1 = ((buf*2+1)*16 + cl)*128;
            A0k0 = *(const uint4*)(base + b0 + ((kg*16)      ^ swr));
            A0k1 = *(const uint4*)(base + b0 + ((64 + kg*16) ^ swr));
            A1k0 = *(const uint4*)(base + b1 + ((kg*16)      ^ swr));
            A1k1 = *(const uint4*)(base + b1 + ((64 + kg*16) ^ swr));
        }

        // MFMA per n0 (C init = Gx)
        f32x4 d0v, d1v, d2v, d3v;
        #define DO_N0(dd, n0) { \
            f32x4 acc; \
            acc[0]=bf2f(gxc[0][n0]); acc[1]=bf2f(gxc[1][n0]); \
            acc[2]=bf2f(gxc[2][n0]); acc[3]=bf2f(gxc[3][n0]); \
            acc = MF(A0k0, Bf[n0][0], acc); \
            acc = MF(A0k1, Bf[n0][1], acc); \
            acc = MF(A1k0, Bf[n0][0], acc); \
            acc = MF(A1k1, Bf[n0][1], acc); \
            dd = acc; }
        DO_N0(d0v, 0) DO_N0(d1v, 1) DO_N0(d2v, 2) DO_N0(d3v, 3)
        #undef DO_N0

        // transpose + acts per n0
        float h0, h1, h2, h3;
        #define PROC(dd, cc, hh) { \
            float v0 = dd[0], v1 = dd[1], v2 = dd[2], v3 = dd[3]; \
            float s0 = q0 ? v0 : v1;  float s1 = q0 ? v2 : v3; \
            float x0 = dpp_xor1(s0), x1 = dpp_xor1(s1); \
            v0 = q0 ? x0 : v0;  v1 = q0 ? v1 : x0; \
            v2 = q0 ? x1 : v2;  v3 = q0 ? v3 : x1; \
            s0 = q1 ? v0 : v2;  s1 = q1 ? v1 : v3; \
            x0 = dpp_xor2(s0);  x1 = dpp_xor2(s1); \
            v0 = q1 ? x0 : v0;  v2 = q1 ? v2 : x0; \
            v1 = q1 ? x1 : v1;  v3 = q1 ? v3 : x1; \
            float i_ = fast_rcp(1.f + fast_exp2(v0 * kSig)); \
            float f_ = fast_rcp(1.f + fast_exp2(v1 * kSig)); \
            float g_ = fmaf(-2.f, fast_rcp(1.f + fast_exp2(v2 * kTan2)), 1.f); \
            float o_ = fast_rcp(1.f + fast_exp2(v3 * kSig)); \
            cc = fmaf(f_, cc, i_ * g_); \
            float tc = fmaf(-2.f, fast_rcp(1.f + fast_exp2(cc * kTan2)), 1.f); \
            hh = o_ * tc; }
        PROC(d0v, c0, h0) PROC(d1v, c1, h1) PROC(d2v, c2, h2) PROC(d3v, c3, h3)
        #undef PROC

        // decompose h -> 2 bf16 planes, write to hb[buf^1] (swizzled)
        {
            char* wb0 = (char*)hb + (((buf^1)*2+0)*16 + rowe)*128;
            char* wb1 = (char*)hb + (((buf^1)*2+1)*16 + rowe)*128;
            #define WRH(n0, hh) { \
                unsigned hu = __float_as_uint(hh); \
                unsigned bu = hu & 0xffff0000u; \
                float dd2 = hh - __uint_as_float(bu); \
                *(unsigned short*)(wb0 + ((cbw + n0*8) ^ swe)) = (unsigned short)(bu >> 16); \
                *(unsigned short*)(wb1 + ((cbw + n0*8) ^ swe)) = f2bf(dd2); }
            WRH(0, h0) WRH(1, h1) WRH(2, h2) WRH(3, h3)
            #undef WRH
        }

        // emission for (cells, row rix) of chunk m_e
        bool em = aliveE & (rix >= S_e) & (rix < E_e);
        if (!isLang) {
            if (em) {
                hout[(size_t)rix*HH + wv*16 + 0*4 + a] = h0;
                hout[(size_t)rix*HH + wv*16 + 1*4 + a] = h1;
                hout[(size_t)rix*HH + wv*16 + 2*4 + a] = h2;
                hout[(size_t)rix*HH + wv*16 + 3*4 + a] = h3;
            }
        } else if (em) {
            for (int i = 0; i < kcnt; i++) {
                float* hp = hout + (size_t)(tptr+i)*HH + wv*16 + a;
                hp[0] = h0; hp[4] = h1; hp[8] = h2; hp[12] = h3;
            }
            tptr += kcnt;
        }
        rix++;
        gptr0 += NG; gptr1 += NG; gptr2 += NG; gptr3 += NG;
        #pragma unroll
        for (int r = 0; r < 4; r++)
            #pragma unroll
            for (int n0 = 0; n0 < 4; n0++) gxc[r][n0] = gxn[r][n0];
        BAR();
        buf ^= 1;
    }
    (void)kTan;
}

// ---------------- final: alpha[t] = sigmoid(fc_w . concat + fc_b) ------------
__global__ __launch_bounds__(256) void final_fc(const float* __restrict__ hA,
    const float* __restrict__ hB, const float* __restrict__ hI,
    const float* __restrict__ hpa, const float* __restrict__ hpb,
    const float* __restrict__ fcw, const float* __restrict__ fcb,
    float* __restrict__ out)
{
    int t = blockIdx.x * blockDim.x + threadIdx.x;
    if (t >= T_STEPS) return;
    float acc = fcb[0];
    const float* hs0 = hA  + (size_t)t*HH;
    const float* hs1 = hB  + (size_t)t*HH;
    const float* hs2 = hI  + (size_t)t*HH;
    const float* hs3 = hpa + (size_t)t*HH;
    const float* hs4 = hpb + (size_t)t*HH;
    #pragma unroll
    for (int k = 0; k < HH; k++) acc = fmaf(hs0[k], fcw[0*HH+k], acc);
    #pragma unroll
    for (int k = 0; k < HH; k++) acc = fmaf(hs1[k], fcw[1*HH+k], acc);
    #pragma unroll
    for (int k = 0; k < HH; k++) acc = fmaf(hs2[k], fcw[2*HH+k], acc);
    #pragma unroll
    for (int k = 0; k < HH; k++) acc = fmaf(hs3[k], fcw[3*HH+k], acc);
    #pragma unroll
    for (int k = 0; k < HH; k++) acc = fmaf(hs4[k], fcw[4*HH+k], acc);
    out[t] = fast_rcp(1.f + fast_exp2(acc * -1.44269504088896340736f));
}

// ---------------- launch -----------------------------------------------------
extern "C" void kernel_launch(void* const* d_in, const int* in_sizes, int n_in,
                              void* d_out, int out_size, void* d_ws, size_t ws_size,
                              hipStream_t stream)
{
    const float* xA      = (const float*)d_in[0];
    const float* xB      = (const float*)d_in[1];
    const float* img     = (const float*)d_in[2];
    const float* PA      = (const float*)d_in[3];
    const float* PB      = (const float*)d_in[4];
    const int*   lenA    = (const int*)d_in[5];
    const int*   lenB    = (const int*)d_in[6];
    const float* Wih_vad = (const float*)d_in[7];
    const float* Whh_vad = (const float*)d_in[8];
    const float* b_vad   = (const float*)d_in[9];
    const float* Wih_img = (const float*)d_in[10];
    const float* Whh_img = (const float*)d_in[11];
    const float* b_img   = (const float*)d_in[12];
    const float* Wih_lng = (const float*)d_in[13];
    const float* Whh_lng = (const float*)d_in[14];
    const float* b_lng   = (const float*)d_in[15];
    const float* fc_w    = (const float*)d_in[16];
    const float* fc_b    = (const float*)d_in[17];
    float* out = (float*)d_out;

    char* ws = (char*)d_ws;
    size_t off = 0;
    auto alloc = [&](size_t bytes) -> void* {
        void* p = ws + off;
        off += (bytes + 255) & ~(size_t)255;
        return p;
    };
    int* offsA = (int*)alloc((T_STEPS+1)*sizeof(int));
    int* offsB = (int*)alloc((T_STEPS+1)*sizeof(int));
    int* idxA  = (int*)alloc((size_t)SMAX*sizeof(int));
    int* idxB  = (int*)alloc((size_t)SMAX*sizeof(int));
    int* KsA   = (int*)alloc((size_t)KS_WORDS*sizeof(int));   // contiguous with KsB
    int* KsB   = (int*)alloc((size_t)KS_WORDS*sizeof(int));
    unsigned short* GvA = (unsigned short*)alloc((size_t)GD_ROWS*NG*2);
    unsigned short* GvB = (unsigned short*)alloc((size_t)GD_ROWS*NG*2);
    unsigned short* Gim = (unsigned short*)alloc((size_t)GD_ROWS*NG*2);
    unsigned short* GlA = (unsigned short*)alloc((size_t)GL_ROWS*NG*2);
    unsigned short* GlB = (unsigned short*)alloc((size_t)GL_ROWS*NG*2);
    float* hA  = (float*)alloc((size_t)T_STEPS*HH*sizeof(float));
    float* hB  = (float*)alloc((size_t)T_STEPS*HH*sizeof(float));
    float* hI  = (float*)alloc((size_t)T_STEPS*HH*sizeof(float));
    float* hpa = (float*)alloc((size_t)T_STEPS*HH*sizeof(float));
    float* hpb = (float*)alloc((size_t)T_STEPS*HH*sizeof(float));
    unsigned* Wbf0 = (unsigned*)alloc((size_t)NG*64*sizeof(unsigned));
    unsigned* Wbf1 = (unsigned*)alloc((size_t)NG*64*sizeof(unsigned));
    unsigned* Wbf2 = (unsigned*)alloc((size_t)NG*64*sizeof(unsigned));
    unsigned* Wsq0 = (unsigned*)alloc((size_t)NG*32*sizeof(unsigned));
    unsigned* Wsq1 = (unsigned*)alloc((size_t)NG*32*sizeof(unsigned));
    unsigned* Wsq2 = (unsigned*)alloc((size_t)NG*32*sizeof(unsigned));
    (void)ws_size; (void)in_sizes; (void)n_in; (void)out_size;

    scan_kernel<<<2, 64, 0, stream>>>(lenA, lenB, offsA, offsB);
    hipMemsetAsync(KsA, 0, 2*(size_t)KS_WORDS*sizeof(int), stream);
    build_meta<<<(T_STEPS+255)/256, 256, 0, stream>>>(lenA, offsA, idxA, KsA);
    build_meta<<<(T_STEPS+255)/256, 256, 0, stream>>>(lenB, offsB, idxB, KsB);
    conv_w<<<dim3(64,3), 256, 0, stream>>>(Wih_vad, Wih_img, Wih_lng, Wbf0, Wbf1, Wbf2);
    conv_wseq<<<3, 256, 0, stream>>>(Whh_vad, Whh_img, Whh_lng, Wsq0, Wsq1, Wsq2);

    GemmArgs GA;
    GA.xsrc[0]=xA; GA.xsrc[1]=xB; GA.xsrc[2]=img;
    GA.psrc[0]=PA; GA.psrc[1]=PB;
    GA.idx[0]=idxA; GA.idx[1]=idxB;
    GA.Wb[0]=Wbf0; GA.Wb[1]=Wbf1; GA.Wb[2]=Wbf2;
    GA.bias[0]=b_vad; GA.bias[1]=b_img; GA.bias[2]=b_lng;
    GA.G[0]=GvA; GA.G[1]=GvB; GA.G[2]=Gim; GA.G[3]=GlA; GA.G[4]=GlB;
    GA.offs[0]=offsA; GA.offs[1]=offsB;
    gates_mfma<<<TOTROWS/64, 256, 0, stream>>>(GA);

    SeqArgs A;
    A.gx[0]=GvA;  A.gx[1]=GvB;  A.gx[2]=Gim;  A.gx[3]=GlA;  A.gx[4]=GlB;
    A.wseq[0]=Wsq0; A.wseq[1]=Wsq0; A.wseq[2]=Wsq1; A.wseq[3]=Wsq2; A.wseq[4]=Wsq2;
    A.hout[0]=hA; A.hout[1]=hB; A.hout[2]=hI; A.hout[3]=hpa; A.hout[4]=hpb;
    A.offs[0]=nullptr; A.offs[1]=nullptr; A.offs[2]=nullptr; A.offs[3]=offsA; A.offs[4]=offsB;
    A.ks[0]=nullptr; A.ks[1]=nullptr; A.ks[2]=nullptr; A.ks[3]=KsA; A.ks[4]=KsB;
    seq_kernel<<<NBLK_SEQ, 256, 0, stream>>>(A);

    final_fc<<<(T_STEPS+255)/256, 256, 0, stream>>>(hA, hB, hI, hpa, hpb, fc_w, fc_b, out);
}

// Round 15
// 254.002 us; speedup vs baseline: 1.6476x; 1.0285x over previous
//
#include <hip/hip_runtime.h>
#include <hip/hip_bf16.h>

#define T_STEPS 8192
#define LMAX 12
#define DV 128
#define DI 65
#define NG 256   // 4*H
#define HH 64

#define SMAX (T_STEPS * LMAX)        // 98304 worst-case lang rows
#define GD_ROWS (T_STEPS + 128)      // dense G3 rows (pad for prefetch)
#define GL_ROWS (SMAX + 128)         // lang G3 rows
#define KS_WORDS (SMAX + 128)
#define WARM 64                      // validated r6/r14
#define BLK_VAD 32                   // blocks per vad chain (CH=512)
#define BLK_LNG 128                  // blocks per lang chain (CH=2048)
#define NBLK_SEQ (3*BLK_VAD + 2*BLK_LNG)   // 352 blocks x 4 waves

// virtual row space for the fused gate GEMM (all 64-aligned)
#define SEG1 8192
#define SEG2 16384
#define SEG3 24576
#define SEG4 122880
#define TOTROWS 221184

typedef short s16x8 __attribute__((ext_vector_type(8)));
typedef float f32x4 __attribute__((ext_vector_type(4)));

#if __has_builtin(__builtin_amdgcn_exp2f)
__device__ __forceinline__ float fast_exp2(float x){ return __builtin_amdgcn_exp2f(x); }
#else
__device__ __forceinline__ float fast_exp2(float x){ return exp2f(x); }
#endif
#if __has_builtin(__builtin_amdgcn_rcpf)
__device__ __forceinline__ float fast_rcp(float x){ return __builtin_amdgcn_rcpf(x); }
#else
__device__ __forceinline__ float fast_rcp(float x){ return 1.0f/x; }
#endif

__device__ __forceinline__ float bf2f(unsigned short u){
    return __uint_as_float(((unsigned)u)<<16);
}
__device__ __forceinline__ unsigned short f2bf(float f){
    unsigned u = __float_as_uint(f);
    unsigned r = (u + 0x7fffu + ((u>>16)&1u)) >> 16;   // RNE
    return (unsigned short)r;
}
__device__ __forceinline__ unsigned packbf2(float a, float b){
    return (unsigned)f2bf(a) | ((unsigned)f2bf(b) << 16);
}

// quad-local xor shuffles via DPP (validated r4-r14)
__device__ __forceinline__ float dpp_xor1(float x){
    return __uint_as_float((unsigned)__builtin_amdgcn_update_dpp(
        0, (int)__float_as_uint(x), 0xB1, 0xF, 0xF, true));
}
__device__ __forceinline__ float dpp_xor2(float x){
    return __uint_as_float((unsigned)__builtin_amdgcn_update_dpp(
        0, (int)__float_as_uint(x), 0x4E, 0xF, 0xF, true));
}

__device__ __forceinline__ f32x4 MF(uint4 a, uint4 b, f32x4 c){
    return __builtin_amdgcn_mfma_f32_16x16x32_bf16(
        __builtin_bit_cast(s16x8, a), __builtin_bit_cast(s16x8, b), c, 0, 0, 0);
}

// barrier: drain LDS only, leave global prefetches in flight.
#define BAR() asm volatile("s_waitcnt lgkmcnt(0)\ns_barrier" ::: "memory")

// ---------------- prefix scan of lens -> exclusive offsets (+ total at [T]) --
__global__ void scan_kernel(const int* __restrict__ lenA, const int* __restrict__ lenB,
                            int* __restrict__ offsA, int* __restrict__ offsB)
{
    const int* len = blockIdx.x ? lenB : lenA;
    int* offs = blockIdx.x ? offsB : offsA;
    int lane = threadIdx.x;   // 64 threads
    int carry = 0;
    for (int base = 0; base < T_STEPS; base += 64) {
        int x = len[base + lane];
        int v = x;
        #pragma unroll
        for (int d = 1; d < 64; d <<= 1) {
            int u = __shfl_up(v, d);
            if (lane >= d) v += u;
        }
        offs[base + lane] = carry + v - x;     // exclusive
        carry += __shfl(v, 63);
    }
    if (lane == 0) offs[T_STEPS] = carry;
}

// ---- build compacted-row -> source-row map, and per-row boundary counts ----
__global__ void build_meta(const int* __restrict__ len, const int* __restrict__ offs,
                           int* __restrict__ idx, int* __restrict__ Ks)
{
    int t = blockIdx.x * blockDim.x + threadIdx.x;
    if (t >= T_STEPS) return;
    int n = len[t];
    int o = offs[t];
    for (int p = 0; p < n; p++) idx[o + p] = t * LMAX + p;
    int e = offs[t + 1];
    if (e > 0) atomicAdd(&Ks[e - 1], 1);   // boundary after row e-1
}

// ---------------- bf16 weights for the gate GEMM B-operand -------------------
__global__ __launch_bounds__(256) void conv_w(const float* __restrict__ Wv,
    const float* __restrict__ Wi, const float* __restrict__ Wl,
    unsigned* __restrict__ dv, unsigned* __restrict__ di, unsigned* __restrict__ dl)
{
    int mat = blockIdx.y;
    const float* W = mat==0 ? Wv : mat==1 ? Wi : Wl;
    unsigned* dst  = mat==0 ? dv : mat==1 ? di : dl;
    int D = (mat==1) ? DI : DV;
    int wv = threadIdx.x >> 6, l = threadIdx.x & 63;
    int j = blockIdx.x*4 + wv;
    const float* wr = W + (size_t)j * D;
    int c = 2*l;
    float a = (c < D)   ? wr[c]   : 0.f;
    float b = (c+1 < D) ? wr[c+1] : 0.f;
    dst[(size_t)j*64 + l] = packbf2(a, b);
}

// ---- Whh reordered+bf16 for the seq MFMA: Wseq[n][k], n = cell*4+q ----------
__global__ __launch_bounds__(256) void conv_wseq(const float* __restrict__ Wv,
    const float* __restrict__ Wi, const float* __restrict__ Wl,
    unsigned* __restrict__ d0, unsigned* __restrict__ d1, unsigned* __restrict__ d2)
{
    int mat = blockIdx.x;
    const float* W = mat==0 ? Wv : mat==1 ? Wi : Wl;
    unsigned* dst  = mat==0 ? d0 : mat==1 ? d1 : d2;
    int n = threadIdx.x;                 // 0..255
    int cell = n >> 2, q = n & 3;
    const float* src = W + (size_t)(q*HH + cell) * HH;
    unsigned* drow = dst + (size_t)n * 32;
    #pragma unroll
    for (int p = 0; p < 32; p++)
        drow[p] = packbf2(src[2*p], src[2*p+1]);
}

// ---------------- fused gate GEMMs: fp32 in -> bf16 frag -> MFMA -> G3 -------
struct GemmArgs {
    const float*    xsrc[3];   // xA, xB, img
    const float*    psrc[2];   // PA, PB
    const int*      idx[2];
    const unsigned* Wb[3];
    const float*    bias[3];
    unsigned short* G[5];
    const int*      offs[2];
};

__global__ __launch_bounds__(256) void gates_mfma(GemmArgs A)
{
    int rowbase0 = blockIdx.x * 64;
    int seg;
    if      (rowbase0 < SEG1) seg = 0;
    else if (rowbase0 < SEG2) seg = 1;
    else if (rowbase0 < SEG3) seg = 2;
    else if (rowbase0 < SEG4) seg = 3;
    else                      seg = 4;
    int segbase = (seg==0)?0:(seg==1)?SEG1:(seg==2)?SEG2:(seg==3)?SEG3:SEG4;
    int wi      = (seg<2)?0:((seg==2)?1:2);
    int R = 0;
    if (seg >= 3) {
        R = A.offs[seg-3][T_STEPS];
        if (rowbase0 - segbase >= ((R + 63) & ~63)) return;
    }
    int tid = threadIdx.x, wv = tid >> 6, l = tid & 63;
    int m = l & 15, kg = l >> 4;
    int lrow = rowbase0 - segbase + wv * 16 + m;   // local row for this lane

    uint4 af0, af1, af2, af3;
    if (seg < 2 || seg >= 3) {
        const float* xr;
        bool ok = true;
        if (seg < 2) xr = A.xsrc[seg] + (size_t)lrow * DV;
        else { ok = lrow < R; xr = ok ? (A.psrc[seg-3] + (size_t)A.idx[seg-3][lrow] * DV) : nullptr; }
        auto lda = [&](int kb)->uint4 {
            uint4 u = make_uint4(0,0,0,0);
            if (ok) {
                float4 a = *(const float4*)(xr + kb);
                float4 b = *(const float4*)(xr + kb + 4);
                u.x = packbf2(a.x, a.y); u.y = packbf2(a.z, a.w);
                u.z = packbf2(b.x, b.y); u.w = packbf2(b.z, b.w);
            }
            return u;
        };
        af0 = lda(kg*8); af1 = lda(32+kg*8); af2 = lda(64+kg*8); af3 = lda(96+kg*8);
    } else {
        const float* xr = A.xsrc[2] + (size_t)lrow * DI;
        auto lda = [&](int kb)->uint4 {
            float v[8];
            #pragma unroll
            for (int j = 0; j < 8; j++) { int c = kb + j; v[j] = (c < DI) ? xr[c] : 0.f; }
            return make_uint4(packbf2(v[0],v[1]), packbf2(v[2],v[3]),
                              packbf2(v[4],v[5]), packbf2(v[6],v[7]));
        };
        af0 = lda(kg*8); af1 = lda(32+kg*8); af2 = lda(64+kg*8); af3 = lda(96+kg*8);
    }

    const unsigned* Wb = A.Wb[wi] + (size_t)m * 64 + kg * 4;
    const float* bias = A.bias[wi];

    f32x4 acc[16];
    #pragma unroll
    for (int n0 = 0; n0 < 16; n0++) acc[n0] = (f32x4){0.f,0.f,0.f,0.f};

    #pragma unroll
    for (int n0 = 0; n0 < 16; n0++) {
        const unsigned* wp = Wb + (size_t)n0 * 16 * 64;
        uint4 b0 = *(const uint4*)(wp);
        uint4 b1 = *(const uint4*)(wp + 16);
        uint4 b2 = *(const uint4*)(wp + 32);
        uint4 b3 = *(const uint4*)(wp + 48);
        acc[n0] = MF(af0, b0, acc[n0]);
        acc[n0] = MF(af1, b1, acc[n0]);
        acc[n0] = MF(af2, b2, acc[n0]);
        acc[n0] = MF(af3, b3, acc[n0]);
    }

    // gate j = n0*16+m = 64q + 16b + m  (q=n0>>2, b=n0&3) -> cell=16b+m
    unsigned short* Gp = A.G[seg];
    int localrow = rowbase0 - segbase + wv * 16 + kg * 4;
    #pragma unroll
    for (int b = 0; b < 4; b++) {
        int cell = 16*b + m;
        float bj0 = bias[      16*b + m];
        float bj1 = bias[ 64 + 16*b + m];
        float bj2 = bias[128 + 16*b + m];
        float bj3 = bias[192 + 16*b + m];
        #pragma unroll
        for (int r = 0; r < 4; r++) {
            ushort4 o;
            o.x = f2bf(acc[b   ][r] + bj0);
            o.y = f2bf(acc[4+b ][r] + bj1);
            o.z = f2bf(acc[8+b ][r] + bj2);
            o.w = f2bf(acc[12+b][r] + bj3);
            *(ushort4*)(Gp + (size_t)(localrow + r)*NG + cell*4) = o;
        }
    }
}

// ---------------- MFMA-based recurrence: 16 chunks per block -----------------
// Per step: D[16 rows=chunks][256 cols=cell*4+q] = A[16][64]·Wseq^T + Gx,
// A = h as 2 bf16 planes (h = b1 + b2, ~2^-18 effective error).
// D layout (verified): col = l&15 (+16*n0+64*wv), row = (l>>4)*4 + reg.
// Gate types of one cell sit in quad lanes -> in-register 4x4 quad transpose.
// h planes go to XOR-swizzled LDS for the next step's A-frags.
// r15: Ks prefetched 1 step ahead (was a same-step L2 gather stall);
//      2x blocks for TLP (r14 was 0.7 blocks/CU, zero latency hiding).
struct SeqArgs {
    const unsigned short* gx[5];    // G3 [row][cell*4+q]
    const unsigned*       wseq[5];  // Wseq [256][32] uints (bf16 pairs)
    float*                hout[5];
    const int*            offs[5];
    const int*            ks[5];
};

__global__ __launch_bounds__(256,1) void seq_kernel(SeqArgs A)
{
    int bid = blockIdx.x;
    int chain, blk;
    if (bid < 3*BLK_VAD) { chain = bid / BLK_VAD; blk = bid % BLK_VAD; }
    else { int b2 = bid - 3*BLK_VAD; chain = 3 + b2 / BLK_LNG; blk = b2 % BLK_LNG; }

    const unsigned short* __restrict__ G3 = A.gx[chain];
    const unsigned* __restrict__ Wq = A.wseq[chain];
    float* __restrict__ hout = A.hout[chain];
    const int* __restrict__ offs = A.offs[chain];
    const int* __restrict__ Ks = A.ks[chain];
    const bool isLang = (offs != nullptr);

    const int R = isLang ? offs[T_STEPS] : T_STEPS;
    const int CH = isLang ? (BLK_LNG*16) : (BLK_VAD*16);
    const int len = (R + CH - 1) / CH;
    const int nsteps = len + WARM;

    int tid = threadIdx.x, wv = tid >> 6, l = tid & 63;
    int cl = l & 15, kg = l >> 4;            // A/B-frag roles (kg == rg)
    int rg = l >> 4, a = (l >> 2) & 3, rr = l & 3;  // D roles

    // B-frags (static): Bf[n0][kk] = Wseq[wv*64+n0*16+cl][k=32kk+8kg..+8]
    uint4 Bf[4][2];
    #pragma unroll
    for (int n0 = 0; n0 < 4; n0++)
        #pragma unroll
        for (int kk = 0; kk < 2; kk++)
            Bf[n0][kk] = *(const uint4*)(Wq + (size_t)(wv*64 + n0*16 + cl)*32 + kk*16 + kg*4);

    // Gx row pointers for chunk slots m = 4*rg + r  (D rows)
    const unsigned short* gptr0; const unsigned short* gptr1;
    const unsigned short* gptr2; const unsigned short* gptr3;
    {
        auto mk = [&](int r)->const unsigned short* {
            int gc = blk*16 + 4*rg + r;
            int S = gc * len;
            int st = (S < R) ? max(0, S - WARM) : 0;
            return G3 + (size_t)st * NG + wv*64 + cl;
        };
        gptr0 = mk(0); gptr1 = mk(1); gptr2 = mk(2); gptr3 = mk(3);
    }

    // emission chunk m_e = 4*rg + rr  (post-transpose row)
    int gcE = blk*16 + 4*rg + rr;
    int S_e = gcE * len;
    bool aliveE = S_e < R;
    int E_e = min(S_e + len, R);
    int start_e = aliveE ? max(0, S_e - WARM) : 0;
    int rix = start_e;

    int tptr = 0;
    if (isLang && aliveE) {
        int lo = 1, hi = T_STEPS + 1;
        while (lo < hi) { int mid=(lo+hi)>>1; if (offs[mid] <= S_e) lo = mid+1; else hi = mid; }
        tptr = lo - 1;
    }
    // leading empty timesteps -> zero hp rows (chunk 0 only)
    if (isLang && blk == 0 && rg == 0 && rr == 0) {
        for (int i = 0; i < tptr; i++)
            #pragma unroll
            for (int n0 = 0; n0 < 4; n0++)
                hout[(size_t)i*HH + wv*16 + n0*4 + a] = 0.f;
    }

    // LDS: h planes [buf][plane][row 16][cell 64] bf16, XOR-swizzled bytes
    __shared__ unsigned short hb[2][2][16][64];
    {
        uint4* p = (uint4*)hb;   // 512 x uint4 = 8KB
        p[tid] = make_uint4(0,0,0,0);
        p[tid+256] = make_uint4(0,0,0,0);
    }
    __syncthreads();

    float c0=0.f, c1=0.f, c2=0.f, c3=0.f;   // c per n0 for (cell(n0), row_e)

    // preload gx for step 0 and Ks for rix
    unsigned short gxc[4][4];   // [reg r][n0]
    #pragma unroll
    for (int r = 0; r < 4; r++) {
        const unsigned short* gp = (r==0)?gptr0:(r==1)?gptr1:(r==2)?gptr2:gptr3;
        #pragma unroll
        for (int n0 = 0; n0 < 4; n0++) gxc[r][n0] = gp[n0*16];
    }
    int kcur = isLang ? Ks[rix] : 0;

    const float kSig  = -1.44269504088896340736f;
    const float kTan2 =  2.88539008177792681472f;

    bool q0 = (rr & 1) != 0, q1 = (rr & 2) != 0;
    int buf = 0;
    int rowe = 4*rg + rr;
    int swe = (rowe & 7) << 4;
    int cbw = wv*32 + a*2;              // + n0*8, XOR swe
    int swr = (cl & 7) << 4;            // A-frag read swizzle (row = cl)

    for (int it = 0; it < nsteps; ++it) {
        // prefetch next-step gx and Ks
        unsigned short gxn[4][4];
        #pragma unroll
        for (int r = 0; r < 4; r++) {
            const unsigned short* gp = (r==0)?gptr0:(r==1)?gptr1:(r==2)?gptr2:gptr3;
            #pragma unroll
            for (int n0 = 0; n0 < 4; n0++) gxn[r][n0] = gp[NG + n0*16];
        }
        int knext = isLang ? Ks[rix + 1] : 0;

        // A-frags from hb[buf] (planes 0,1 x k-halves 0,1)
        uint4 A0k0, A0k1, A1k0, A1k1;
        {
            char* base = (char*)hb;
            int b0 = ((buf*2+0)*16 + cl)*128;
            int b1 = ((buf*2+1)*16 + cl)*128;
            A0k0 = *(const uint4*)(base + b0 + ((kg*16)      ^ swr));
            A0k1 = *(const uint4*)(base + b0 + ((64 + kg*16) ^ swr));
            A1k0 = *(const uint4*)(base + b1 + ((kg*16)      ^ swr));
            A1k1 = *(const uint4*)(base + b1 + ((64 + kg*16) ^ swr));
        }

        // MFMA per n0 (C init = Gx)
        f32x4 d0v, d1v, d2v, d3v;
        #define DO_N0(dd, n0) { \
            f32x4 acc; \
            acc[0]=bf2f(gxc[0][n0]); acc[1]=bf2f(gxc[1][n0]); \
            acc[2]=bf2f(gxc[2][n0]); acc[3]=bf2f(gxc[3][n0]); \
            acc = MF(A0k0, Bf[n0][0], acc); \
            acc = MF(A0k1, Bf[n0][1], acc); \
            acc = MF(A1k0, Bf[n0][0], acc); \
            acc = MF(A1k1, Bf[n0][1], acc); \
            dd = acc; }
        DO_N0(d0v, 0) DO_N0(d1v, 1) DO_N0(d2v, 2) DO_N0(d3v, 3)
        #undef DO_N0

        // transpose + acts per n0
        float h0, h1, h2, h3;
        #define PROC(dd, cc, hh) { \
            float v0 = dd[0], v1 = dd[1], v2 = dd[2], v3 = dd[3]; \
            float s0 = q0 ? v0 : v1;  float s1 = q0 ? v2 : v3; \
            float x0 = dpp_xor1(s0), x1 = dpp_xor1(s1); \
            v0 = q0 ? x0 : v0;  v1 = q0 ? v1 : x0; \
            v2 = q0 ? x1 : v2;  v3 = q0 ? v3 : x1; \
            s0 = q1 ? v0 : v2;  s1 = q1 ? v1 : v3; \
            x0 = dpp_xor2(s0);  x1 = dpp_xor2(s1); \
            v0 = q1 ? x0 : v0;  v2 = q1 ? v2 : x0; \
            v1 = q1 ? x1 : v1;  v3 = q1 ? v3 : x1; \
            float i_ = fast_rcp(1.f + fast_exp2(v0 * kSig)); \
            float f_ = fast_rcp(1.f + fast_exp2(v1 * kSig)); \
            float g_ = fmaf(-2.f, fast_rcp(1.f + fast_exp2(v2 * kTan2)), 1.f); \
            float o_ = fast_rcp(1.f + fast_exp2(v3 * kSig)); \
            cc = fmaf(f_, cc, i_ * g_); \
            float tc = fmaf(-2.f, fast_rcp(1.f + fast_exp2(cc * kTan2)), 1.f); \
            hh = o_ * tc; }
        PROC(d0v, c0, h0) PROC(d1v, c1, h1) PROC(d2v, c2, h2) PROC(d3v, c3, h3)
        #undef PROC

        // decompose h -> 2 bf16 planes, write to hb[buf^1] (swizzled)
        {
            char* wb0 = (char*)hb + (((buf^1)*2+0)*16 + rowe)*128;
            char* wb1 = (char*)hb + (((buf^1)*2+1)*16 + rowe)*128;
            #define WRH(n0, hh) { \
                unsigned hu = __float_as_uint(hh); \
                unsigned bu = hu & 0xffff0000u; \
                float dd2 = hh - __uint_as_float(bu); \
                *(unsigned short*)(wb0 + ((cbw + n0*8) ^ swe)) = (unsigned short)(bu >> 16); \
                *(unsigned short*)(wb1 + ((cbw + n0*8) ^ swe)) = f2bf(dd2); }
            WRH(0, h0) WRH(1, h1) WRH(2, h2) WRH(3, h3)
            #undef WRH
        }

        // emission for (cells, row rix) of chunk m_e
        bool em = aliveE & (rix >= S_e) & (rix < E_e);
        if (!isLang) {
            if (em) {
                hout[(size_t)rix*HH + wv*16 + 0*4 + a] = h0;
                hout[(size_t)rix*HH + wv*16 + 1*4 + a] = h1;
                hout[(size_t)rix*HH + wv*16 + 2*4 + a] = h2;
                hout[(size_t)rix*HH + wv*16 + 3*4 + a] = h3;
            }
        } else if (em) {
            for (int i = 0; i < kcur; i++) {
                float* hp = hout + (size_t)(tptr+i)*HH + wv*16 + a;
                hp[0] = h0; hp[4] = h1; hp[8] = h2; hp[12] = h3;
            }
            tptr += kcur;
        }
        rix++;
        gptr0 += NG; gptr1 += NG; gptr2 += NG; gptr3 += NG;
        #pragma unroll
        for (int r = 0; r < 4; r++)
            #pragma unroll
            for (int n0 = 0; n0 < 4; n0++) gxc[r][n0] = gxn[r][n0];
        kcur = knext;
        BAR();
        buf ^= 1;
    }
}

// ---------------- final: alpha[t] = sigmoid(fc_w . concat + fc_b) ------------
__global__ __launch_bounds__(256) void final_fc(const float* __restrict__ hA,
    const float* __restrict__ hB, const float* __restrict__ hI,
    const float* __restrict__ hpa, const float* __restrict__ hpb,
    const float* __restrict__ fcw, const float* __restrict__ fcb,
    float* __restrict__ out)
{
    int t = blockIdx.x * blockDim.x + threadIdx.x;
    if (t >= T_STEPS) return;
    float acc = fcb[0];
    const float* hs0 = hA  + (size_t)t*HH;
    const float* hs1 = hB  + (size_t)t*HH;
    const float* hs2 = hI  + (size_t)t*HH;
    const float* hs3 = hpa + (size_t)t*HH;
    const float* hs4 = hpb + (size_t)t*HH;
    #pragma unroll
    for (int k = 0; k < HH; k++) acc = fmaf(hs0[k], fcw[0*HH+k], acc);
    #pragma unroll
    for (int k = 0; k < HH; k++) acc = fmaf(hs1[k], fcw[1*HH+k], acc);
    #pragma unroll
    for (int k = 0; k < HH; k++) acc = fmaf(hs2[k], fcw[2*HH+k], acc);
    #pragma unroll
    for (int k = 0; k < HH; k++) acc = fmaf(hs3[k], fcw[3*HH+k], acc);
    #pragma unroll
    for (int k = 0; k < HH; k++) acc = fmaf(hs4[k], fcw[4*HH+k], acc);
    out[t] = fast_rcp(1.f + fast_exp2(acc * -1.44269504088896340736f));
}

// ---------------- launch -----------------------------------------------------
extern "C" void kernel_launch(void* const* d_in, const int* in_sizes, int n_in,
                              void* d_out, int out_size, void* d_ws, size_t ws_size,
                              hipStream_t stream)
{
    const float* xA      = (const float*)d_in[0];
    const float* xB      = (const float*)d_in[1];
    const float* img     = (const float*)d_in[2];
    const float* PA      = (const float*)d_in[3];
    const float* PB      = (const float*)d_in[4];
    const int*   lenA    = (const int*)d_in[5];
    const int*   lenB    = (const int*)d_in[6];
    const float* Wih_vad = (const float*)d_in[7];
    const float* Whh_vad = (const float*)d_in[8];
    const float* b_vad   = (const float*)d_in[9];
    const float* Wih_img = (const float*)d_in[10];
    const float* Whh_img = (const float*)d_in[11];
    const float* b_img   = (const float*)d_in[12];
    const float* Wih_lng = (const float*)d_in[13];
    const float* Whh_lng = (const float*)d_in[14];
    const float* b_lng   = (const float*)d_in[15];
    const float* fc_w    = (const float*)d_in[16];
    const float* fc_b    = (const float*)d_in[17];
    float* out = (float*)d_out;

    char* ws = (char*)d_ws;
    size_t off = 0;
    auto alloc = [&](size_t bytes) -> void* {
        void* p = ws + off;
        off += (bytes + 255) & ~(size_t)255;
        return p;
    };
    int* offsA = (int*)alloc((T_STEPS+1)*sizeof(int));
    int* offsB = (int*)alloc((T_STEPS+1)*sizeof(int));
    int* idxA  = (int*)alloc((size_t)SMAX*sizeof(int));
    int* idxB  = (int*)alloc((size_t)SMAX*sizeof(int));
    int* KsA   = (int*)alloc((size_t)KS_WORDS*sizeof(int));   // contiguous with KsB
    int* KsB   = (int*)alloc((size_t)KS_WORDS*sizeof(int));
    unsigned short* GvA = (unsigned short*)alloc((size_t)GD_ROWS*NG*2);
    unsigned short* GvB = (unsigned short*)alloc((size_t)GD_ROWS*NG*2);
    unsigned short* Gim = (unsigned short*)alloc((size_t)GD_ROWS*NG*2);
    unsigned short* GlA = (unsigned short*)alloc((size_t)GL_ROWS*NG*2);
    unsigned short* GlB = (unsigned short*)alloc((size_t)GL_ROWS*NG*2);
    float* hA  = (float*)alloc((size_t)T_STEPS*HH*sizeof(float));
    float* hB  = (float*)alloc((size_t)T_STEPS*HH*sizeof(float));
    float* hI  = (float*)alloc((size_t)T_STEPS*HH*sizeof(float));
    float* hpa = (float*)alloc((size_t)T_STEPS*HH*sizeof(float));
    float* hpb = (float*)alloc((size_t)T_STEPS*HH*sizeof(float));
    unsigned* Wbf0 = (unsigned*)alloc((size_t)NG*64*sizeof(unsigned));
    unsigned* Wbf1 = (unsigned*)alloc((size_t)NG*64*sizeof(unsigned));
    unsigned* Wbf2 = (unsigned*)alloc((size_t)NG*64*sizeof(unsigned));
    unsigned* Wsq0 = (unsigned*)alloc((size_t)NG*32*sizeof(unsigned));
    unsigned* Wsq1 = (unsigned*)alloc((size_t)NG*32*sizeof(unsigned));
    unsigned* Wsq2 = (unsigned*)alloc((size_t)NG*32*sizeof(unsigned));
    (void)ws_size; (void)in_sizes; (void)n_in; (void)out_size;

    scan_kernel<<<2, 64, 0, stream>>>(lenA, lenB, offsA, offsB);
    hipMemsetAsync(KsA, 0, 2*(size_t)KS_WORDS*sizeof(int), stream);
    build_meta<<<(T_STEPS+255)/256, 256, 0, stream>>>(lenA, offsA, idxA, KsA);
    build_meta<<<(T_STEPS+255)/256, 256, 0, stream>>>(lenB, offsB, idxB, KsB);
    conv_w<<<dim3(64,3), 256, 0, stream>>>(Wih_vad, Wih_img, Wih_lng, Wbf0, Wbf1, Wbf2);
    conv_wseq<<<3, 256, 0, stream>>>(Whh_vad, Whh_img, Whh_lng, Wsq0, Wsq1, Wsq2);

    GemmArgs GA;
    GA.xsrc[0]=xA; GA.xsrc[1]=xB; GA.xsrc[2]=img;
    GA.psrc[0]=PA; GA.psrc[1]=PB;
    GA.idx[0]=idxA; GA.idx[1]=idxB;
    GA.Wb[0]=Wbf0; GA.Wb[1]=Wbf1; GA.Wb[2]=Wbf2;
    GA.bias[0]=b_vad; GA.bias[1]=b_img; GA.bias[2]=b_lng;
    GA.G[0]=GvA; GA.G[1]=GvB; GA.G[2]=Gim; GA.G[3]=GlA; GA.G[4]=GlB;
    GA.offs[0]=offsA; GA.offs[1]=offsB;
    gates_mfma<<<TOTROWS/64, 256, 0, stream>>>(GA);

    SeqArgs A;
    A.gx[0]=GvA;  A.gx[1]=GvB;  A.gx[2]=Gim;  A.gx[3]=GlA;  A.gx[4]=GlB;
    A.wseq[0]=Wsq0; A.wseq[1]=Wsq0; A.wseq[2]=Wsq1; A.wseq[3]=Wsq2; A.wseq[4]=Wsq2;
    A.hout[0]=hA; A.hout[1]=hB; A.hout[2]=hI; A.hout[3]=hpa; A.hout[4]=hpb;
    A.offs[0]=nullptr; A.offs[1]=nullptr; A.offs[2]=nullptr; A.offs[3]=offsA; A.offs[4]=offsB;
    A.ks[0]=nullptr; A.ks[1]=nullptr; A.ks[2]=nullptr; A.ks[3]=KsA; A.ks[4]=KsB;
    seq_kernel<<<NBLK_SEQ, 256, 0, stream>>>(A);

    final_fc<<<(T_STEPS+255)/256, 256, 0, stream>>>(hA, hB, hI, hpa, hpb, fc_w, fc_b, out);
}

// Round 16
// 250.453 us; speedup vs baseline: 1.6709x; 1.0142x over previous
//
#include <hip/hip_runtime.h>
#include <hip/hip_bf16.h>

#define T_STEPS 8192
#define LMAX 12
#define DV 128
#define DI 65
#define NG 256   // 4*H
#define HH 64

#define SMAX (T_STEPS * LMAX)        // 98304 worst-case lang rows
#define GD_ROWS (T_STEPS + 128)      // dense G3 rows (pad for prefetch)
#define GL_ROWS (SMAX + 128)         // lang G3 rows
#define KS_WORDS (SMAX + 128)
#define WARM 64                      // validated r6/r14
#define BLK_VAD 32                   // blocks per vad chain (CH=512)
#define BLK_LNG 128                  // blocks per lang chain (CH=2048)
#define NBLK_SEQ (3*BLK_VAD + 2*BLK_LNG)   // 352 blocks x 4 waves

// virtual row space for the fused gate GEMM (all 64-aligned)
#define SEG1 8192
#define SEG2 16384
#define SEG3 24576
#define SEG4 122880
#define TOTROWS 221184

typedef short s16x8 __attribute__((ext_vector_type(8)));
typedef float f32x4 __attribute__((ext_vector_type(4)));

#if __has_builtin(__builtin_amdgcn_exp2f)
__device__ __forceinline__ float fast_exp2(float x){ return __builtin_amdgcn_exp2f(x); }
#else
__device__ __forceinline__ float fast_exp2(float x){ return exp2f(x); }
#endif
#if __has_builtin(__builtin_amdgcn_rcpf)
__device__ __forceinline__ float fast_rcp(float x){ return __builtin_amdgcn_rcpf(x); }
#else
__device__ __forceinline__ float fast_rcp(float x){ return 1.0f/x; }
#endif

__device__ __forceinline__ float bf2f(unsigned short u){
    return __uint_as_float(((unsigned)u)<<16);
}
__device__ __forceinline__ unsigned short f2bf(float f){
    unsigned u = __float_as_uint(f);
    unsigned r = (u + 0x7fffu + ((u>>16)&1u)) >> 16;   // RNE
    return (unsigned short)r;
}
__device__ __forceinline__ unsigned packbf2(float a, float b){
    return (unsigned)f2bf(a) | ((unsigned)f2bf(b) << 16);
}

// quad-local xor shuffles via DPP (validated r4-r15)
__device__ __forceinline__ float dpp_xor1(float x){
    return __uint_as_float((unsigned)__builtin_amdgcn_update_dpp(
        0, (int)__float_as_uint(x), 0xB1, 0xF, 0xF, true));
}
__device__ __forceinline__ float dpp_xor2(float x){
    return __uint_as_float((unsigned)__builtin_amdgcn_update_dpp(
        0, (int)__float_as_uint(x), 0x4E, 0xF, 0xF, true));
}

__device__ __forceinline__ f32x4 MF(uint4 a, uint4 b, f32x4 c){
    return __builtin_amdgcn_mfma_f32_16x16x32_bf16(
        __builtin_bit_cast(s16x8, a), __builtin_bit_cast(s16x8, b), c, 0, 0, 0);
}

// barrier: drain LDS only, leave global prefetches in flight.
#define BAR() asm volatile("s_waitcnt lgkmcnt(0)\ns_barrier" ::: "memory")

// ---------------- prefix scan of lens -> exclusive offsets (+ total at [T]) --
__global__ void scan_kernel(const int* __restrict__ lenA, const int* __restrict__ lenB,
                            int* __restrict__ offsA, int* __restrict__ offsB)
{
    const int* len = blockIdx.x ? lenB : lenA;
    int* offs = blockIdx.x ? offsB : offsA;
    int lane = threadIdx.x;   // 64 threads
    int carry = 0;
    for (int base = 0; base < T_STEPS; base += 64) {
        int x = len[base + lane];
        int v = x;
        #pragma unroll
        for (int d = 1; d < 64; d <<= 1) {
            int u = __shfl_up(v, d);
            if (lane >= d) v += u;
        }
        offs[base + lane] = carry + v - x;     // exclusive
        carry += __shfl(v, 63);
    }
    if (lane == 0) offs[T_STEPS] = carry;
}

// ---- build compacted-row -> source-row map, and per-row boundary counts ----
__global__ void build_meta(const int* __restrict__ len, const int* __restrict__ offs,
                           int* __restrict__ idx, int* __restrict__ Ks)
{
    int t = blockIdx.x * blockDim.x + threadIdx.x;
    if (t >= T_STEPS) return;
    int n = len[t];
    int o = offs[t];
    for (int p = 0; p < n; p++) idx[o + p] = t * LMAX + p;
    int e = offs[t + 1];
    if (e > 0) atomicAdd(&Ks[e - 1], 1);   // boundary after row e-1
}

// ---------------- bf16 weights for the gate GEMM B-operand -------------------
__global__ __launch_bounds__(256) void conv_w(const float* __restrict__ Wv,
    const float* __restrict__ Wi, const float* __restrict__ Wl,
    unsigned* __restrict__ dv, unsigned* __restrict__ di, unsigned* __restrict__ dl)
{
    int mat = blockIdx.y;
    const float* W = mat==0 ? Wv : mat==1 ? Wi : Wl;
    unsigned* dst  = mat==0 ? dv : mat==1 ? di : dl;
    int D = (mat==1) ? DI : DV;
    int wv = threadIdx.x >> 6, l = threadIdx.x & 63;
    int j = blockIdx.x*4 + wv;
    const float* wr = W + (size_t)j * D;
    int c = 2*l;
    float a = (c < D)   ? wr[c]   : 0.f;
    float b = (c+1 < D) ? wr[c+1] : 0.f;
    dst[(size_t)j*64 + l] = packbf2(a, b);
}

// ---- Whh reordered+bf16 for the seq MFMA: Wseq[n][k], n = cell*4+q ----------
__global__ __launch_bounds__(256) void conv_wseq(const float* __restrict__ Wv,
    const float* __restrict__ Wi, const float* __restrict__ Wl,
    unsigned* __restrict__ d0, unsigned* __restrict__ d1, unsigned* __restrict__ d2)
{
    int mat = blockIdx.x;
    const float* W = mat==0 ? Wv : mat==1 ? Wi : Wl;
    unsigned* dst  = mat==0 ? d0 : mat==1 ? d1 : d2;
    int n = threadIdx.x;                 // 0..255
    int cell = n >> 2, q = n & 3;
    const float* src = W + (size_t)(q*HH + cell) * HH;
    unsigned* drow = dst + (size_t)n * 32;
    #pragma unroll
    for (int p = 0; p < 32; p++)
        drow[p] = packbf2(src[2*p], src[2*p+1]);
}

// ---------------- fused gate GEMMs: fp32 in -> bf16 frag -> MFMA -> G3 -------
struct GemmArgs {
    const float*    xsrc[3];   // xA, xB, img
    const float*    psrc[2];   // PA, PB
    const int*      idx[2];
    const unsigned* Wb[3];
    const float*    bias[3];
    unsigned short* G[5];
    const int*      offs[2];
};

__global__ __launch_bounds__(256) void gates_mfma(GemmArgs A)
{
    int rowbase0 = blockIdx.x * 64;
    int seg;
    if      (rowbase0 < SEG1) seg = 0;
    else if (rowbase0 < SEG2) seg = 1;
    else if (rowbase0 < SEG3) seg = 2;
    else if (rowbase0 < SEG4) seg = 3;
    else                      seg = 4;
    int segbase = (seg==0)?0:(seg==1)?SEG1:(seg==2)?SEG2:(seg==3)?SEG3:SEG4;
    int wi      = (seg<2)?0:((seg==2)?1:2);
    int R = 0;
    if (seg >= 3) {
        R = A.offs[seg-3][T_STEPS];
        if (rowbase0 - segbase >= ((R + 63) & ~63)) return;
    }
    int tid = threadIdx.x, wv = tid >> 6, l = tid & 63;
    int m = l & 15, kg = l >> 4;
    int lrow = rowbase0 - segbase + wv * 16 + m;   // local row for this lane

    uint4 af0, af1, af2, af3;
    if (seg < 2 || seg >= 3) {
        const float* xr;
        bool ok = true;
        if (seg < 2) xr = A.xsrc[seg] + (size_t)lrow * DV;
        else { ok = lrow < R; xr = ok ? (A.psrc[seg-3] + (size_t)A.idx[seg-3][lrow] * DV) : nullptr; }
        auto lda = [&](int kb)->uint4 {
            uint4 u = make_uint4(0,0,0,0);
            if (ok) {
                float4 a = *(const float4*)(xr + kb);
                float4 b = *(const float4*)(xr + kb + 4);
                u.x = packbf2(a.x, a.y); u.y = packbf2(a.z, a.w);
                u.z = packbf2(b.x, b.y); u.w = packbf2(b.z, b.w);
            }
            return u;
        };
        af0 = lda(kg*8); af1 = lda(32+kg*8); af2 = lda(64+kg*8); af3 = lda(96+kg*8);
    } else {
        const float* xr = A.xsrc[2] + (size_t)lrow * DI;
        auto lda = [&](int kb)->uint4 {
            float v[8];
            #pragma unroll
            for (int j = 0; j < 8; j++) { int c = kb + j; v[j] = (c < DI) ? xr[c] : 0.f; }
            return make_uint4(packbf2(v[0],v[1]), packbf2(v[2],v[3]),
                              packbf2(v[4],v[5]), packbf2(v[6],v[7]));
        };
        af0 = lda(kg*8); af1 = lda(32+kg*8); af2 = lda(64+kg*8); af3 = lda(96+kg*8);
    }

    const unsigned* Wb = A.Wb[wi] + (size_t)m * 64 + kg * 4;
    const float* bias = A.bias[wi];

    f32x4 acc[16];
    #pragma unroll
    for (int n0 = 0; n0 < 16; n0++) acc[n0] = (f32x4){0.f,0.f,0.f,0.f};

    #pragma unroll
    for (int n0 = 0; n0 < 16; n0++) {
        const unsigned* wp = Wb + (size_t)n0 * 16 * 64;
        uint4 b0 = *(const uint4*)(wp);
        uint4 b1 = *(const uint4*)(wp + 16);
        uint4 b2 = *(const uint4*)(wp + 32);
        uint4 b3 = *(const uint4*)(wp + 48);
        acc[n0] = MF(af0, b0, acc[n0]);
        acc[n0] = MF(af1, b1, acc[n0]);
        acc[n0] = MF(af2, b2, acc[n0]);
        acc[n0] = MF(af3, b3, acc[n0]);
    }

    // gate j = n0*16+m = 64q + 16b + m  (q=n0>>2, b=n0&3) -> cell=16b+m
    unsigned short* Gp = A.G[seg];
    int localrow = rowbase0 - segbase + wv * 16 + kg * 4;
    #pragma unroll
    for (int b = 0; b < 4; b++) {
        int cell = 16*b + m;
        float bj0 = bias[      16*b + m];
        float bj1 = bias[ 64 + 16*b + m];
        float bj2 = bias[128 + 16*b + m];
        float bj3 = bias[192 + 16*b + m];
        #pragma unroll
        for (int r = 0; r < 4; r++) {
            ushort4 o;
            o.x = f2bf(acc[b   ][r] + bj0);
            o.y = f2bf(acc[4+b ][r] + bj1);
            o.z = f2bf(acc[8+b ][r] + bj2);
            o.w = f2bf(acc[12+b][r] + bj3);
            *(ushort4*)(Gp + (size_t)(localrow + r)*NG + cell*4) = o;
        }
    }
}

// ---------------- MFMA-based recurrence: 16 chunks per block -----------------
// Per step: D[16 rows=chunks][256 cols] = A[16][64]·Wseq^T + Gx (2-plane bf16 h).
// r16: depth-6 register ring for the Gx/Ks stream — r15 showed the kernel is
// MLP-bound (dur invariant under 2x blocks / -21% steps; FETCH & BW scaled
// proportionally at constant dur). Depth 1 meant each step's 16x2B loads had
// ~1 step (~500cy) to cover ~900cy HBM latency. Slots are constant-indexed
// through a 6-phase unrolled macro (rule #20).
struct SeqArgs {
    const unsigned short* gx[5];    // G3 [row][cell*4+q]
    const unsigned*       wseq[5];  // Wseq [256][32] uints (bf16 pairs)
    float*                hout[5];
    const int*            offs[5];
    const int*            ks[5];
};

__global__ __launch_bounds__(256,1) void seq_kernel(SeqArgs A)
{
    int bid = blockIdx.x;
    int chain, blk;
    if (bid < 3*BLK_VAD) { chain = bid / BLK_VAD; blk = bid % BLK_VAD; }
    else { int b2 = bid - 3*BLK_VAD; chain = 3 + b2 / BLK_LNG; blk = b2 % BLK_LNG; }

    const unsigned short* __restrict__ G3 = A.gx[chain];
    const unsigned* __restrict__ Wq = A.wseq[chain];
    float* __restrict__ hout = A.hout[chain];
    const int* __restrict__ offs = A.offs[chain];
    const int* __restrict__ Ks = A.ks[chain];
    const bool isLang = (offs != nullptr);

    const int R = isLang ? offs[T_STEPS] : T_STEPS;
    const int CH = isLang ? (BLK_LNG*16) : (BLK_VAD*16);
    const int len = (R + CH - 1) / CH;
    const int nsteps = len + WARM;

    int tid = threadIdx.x, wv = tid >> 6, l = tid & 63;
    int cl = l & 15, kg = l >> 4;            // A/B-frag roles
    int rg = l >> 4, a = (l >> 2) & 3, rr = l & 3;  // D roles

    // B-frags (static): Bf[n0][kk] = Wseq[wv*64+n0*16+cl][k=32kk+8kg..+8]
    uint4 Bf[4][2];
    #pragma unroll
    for (int n0 = 0; n0 < 4; n0++)
        #pragma unroll
        for (int kk = 0; kk < 2; kk++)
            Bf[n0][kk] = *(const uint4*)(Wq + (size_t)(wv*64 + n0*16 + cl)*32 + kk*16 + kg*4);

    // Gx row pointers for chunk slots m = 4*rg + r  (D rows)
    const unsigned short* gptr0; const unsigned short* gptr1;
    const unsigned short* gptr2; const unsigned short* gptr3;
    {
        auto mk = [&](int r)->const unsigned short* {
            int gc = blk*16 + 4*rg + r;
            int S = gc * len;
            int st = (S < R) ? max(0, S - WARM) : 0;
            return G3 + (size_t)st * NG + wv*64 + cl;
        };
        gptr0 = mk(0); gptr1 = mk(1); gptr2 = mk(2); gptr3 = mk(3);
    }

    // emission chunk m_e = 4*rg + rr  (post-transpose row)
    int gcE = blk*16 + 4*rg + rr;
    int S_e = gcE * len;
    bool aliveE = S_e < R;
    int E_e = min(S_e + len, R);
    int start_e = aliveE ? max(0, S_e - WARM) : 0;
    int rix = start_e;

    int tptr = 0;
    if (isLang && aliveE) {
        int lo = 1, hi = T_STEPS + 1;
        while (lo < hi) { int mid=(lo+hi)>>1; if (offs[mid] <= S_e) lo = mid+1; else hi = mid; }
        tptr = lo - 1;
    }
    // leading empty timesteps -> zero hp rows (chunk 0 only)
    if (isLang && blk == 0 && rg == 0 && rr == 0) {
        for (int i = 0; i < tptr; i++)
            #pragma unroll
            for (int n0 = 0; n0 < 4; n0++)
                hout[(size_t)i*HH + wv*16 + n0*4 + a] = 0.f;
    }

    // LDS: h planes [buf][plane][row 16][cell 64] bf16, XOR-swizzled bytes
    __shared__ unsigned short hb[2][2][16][64];
    {
        uint4* p = (uint4*)hb;   // 512 x uint4 = 8KB
        p[tid] = make_uint4(0,0,0,0);
        p[tid+256] = make_uint4(0,0,0,0);
    }
    __syncthreads();

    float c0=0.f, c1=0.f, c2=0.f, c3=0.f;   // c per n0 for (cell(n0), row_e)

    // depth-6 ring: gbuf[slot][r*4+n0], kbuf[slot]; constant-indexed only
    unsigned short gbuf[6][16];
    int kbuf[6];
    #pragma unroll
    for (int j = 0; j < 6; j++) {
        #pragma unroll
        for (int n0 = 0; n0 < 4; n0++) {
            gbuf[j][0*4+n0] = gptr0[j*NG + n0*16];
            gbuf[j][1*4+n0] = gptr1[j*NG + n0*16];
            gbuf[j][2*4+n0] = gptr2[j*NG + n0*16];
            gbuf[j][3*4+n0] = gptr3[j*NG + n0*16];
        }
        kbuf[j] = isLang ? Ks[rix + j] : 0;
    }

    const float kSig  = -1.44269504088896340736f;
    const float kTan2 =  2.88539008177792681472f;

    bool q0 = (rr & 1) != 0, q1 = (rr & 2) != 0;
    int buf = 0;
    int rowe = 4*rg + rr;
    int swe = (rowe & 7) << 4;
    int cbw = wv*32 + a*2;              // + n0*8, XOR swe
    int swr = (cl & 7) << 4;            // A-frag read swizzle (row = cl)

#define SEQ_STEP(PH) do { \
    unsigned short gxc00=gbuf[PH][0], gxc01=gbuf[PH][1], gxc02=gbuf[PH][2], gxc03=gbuf[PH][3]; \
    unsigned short gxc10=gbuf[PH][4], gxc11=gbuf[PH][5], gxc12=gbuf[PH][6], gxc13=gbuf[PH][7]; \
    unsigned short gxc20=gbuf[PH][8], gxc21=gbuf[PH][9], gxc22=gbuf[PH][10], gxc23=gbuf[PH][11]; \
    unsigned short gxc30=gbuf[PH][12], gxc31=gbuf[PH][13], gxc32=gbuf[PH][14], gxc33=gbuf[PH][15]; \
    int kcur = kbuf[PH]; \
    _Pragma("unroll") \
    for (int n0 = 0; n0 < 4; n0++) { \
        gbuf[PH][0*4+n0] = gptr0[6*NG + n0*16]; \
        gbuf[PH][1*4+n0] = gptr1[6*NG + n0*16]; \
        gbuf[PH][2*4+n0] = gptr2[6*NG + n0*16]; \
        gbuf[PH][3*4+n0] = gptr3[6*NG + n0*16]; \
    } \
    kbuf[PH] = isLang ? Ks[rix + 6] : 0; \
    uint4 A0k0, A0k1, A1k0, A1k1; \
    { \
        char* base = (char*)hb; \
        int b0 = ((buf*2+0)*16 + cl)*128; \
        int b1 = ((buf*2+1)*16 + cl)*128; \
        A0k0 = *(const uint4*)(base + b0 + ((kg*16)      ^ swr)); \
        A0k1 = *(const uint4*)(base + b0 + ((64 + kg*16) ^ swr)); \
        A1k0 = *(const uint4*)(base + b1 + ((kg*16)      ^ swr)); \
        A1k1 = *(const uint4*)(base + b1 + ((64 + kg*16) ^ swr)); \
    } \
    f32x4 d0v, d1v, d2v, d3v; \
    { f32x4 acc; acc[0]=bf2f(gxc00); acc[1]=bf2f(gxc10); acc[2]=bf2f(gxc20); acc[3]=bf2f(gxc30); \
      acc = MF(A0k0, Bf[0][0], acc); acc = MF(A0k1, Bf[0][1], acc); \
      acc = MF(A1k0, Bf[0][0], acc); acc = MF(A1k1, Bf[0][1], acc); d0v = acc; } \
    { f32x4 acc; acc[0]=bf2f(gxc01); acc[1]=bf2f(gxc11); acc[2]=bf2f(gxc21); acc[3]=bf2f(gxc31); \
      acc = MF(A0k0, Bf[1][0], acc); acc = MF(A0k1, Bf[1][1], acc); \
      acc = MF(A1k0, Bf[1][0], acc); acc = MF(A1k1, Bf[1][1], acc); d1v = acc; } \
    { f32x4 acc; acc[0]=bf2f(gxc02); acc[1]=bf2f(gxc12); acc[2]=bf2f(gxc22); acc[3]=bf2f(gxc32); \
      acc = MF(A0k0, Bf[2][0], acc); acc = MF(A0k1, Bf[2][1], acc); \
      acc = MF(A1k0, Bf[2][0], acc); acc = MF(A1k1, Bf[2][1], acc); d2v = acc; } \
    { f32x4 acc; acc[0]=bf2f(gxc03); acc[1]=bf2f(gxc13); acc[2]=bf2f(gxc23); acc[3]=bf2f(gxc33); \
      acc = MF(A0k0, Bf[3][0], acc); acc = MF(A0k1, Bf[3][1], acc); \
      acc = MF(A1k0, Bf[3][0], acc); acc = MF(A1k1, Bf[3][1], acc); d3v = acc; } \
    float h0, h1, h2, h3; \
    PROC(d0v, c0, h0) PROC(d1v, c1, h1) PROC(d2v, c2, h2) PROC(d3v, c3, h3) \
    { \
        char* wb0 = (char*)hb + (((buf^1)*2+0)*16 + rowe)*128; \
        char* wb1 = (char*)hb + (((buf^1)*2+1)*16 + rowe)*128; \
        WRH(0, h0) WRH(1, h1) WRH(2, h2) WRH(3, h3) \
    } \
    bool em = aliveE & (rix >= S_e) & (rix < E_e); \
    if (!isLang) { \
        if (em) { \
            hout[(size_t)rix*HH + wv*16 + 0*4 + a] = h0; \
            hout[(size_t)rix*HH + wv*16 + 1*4 + a] = h1; \
            hout[(size_t)rix*HH + wv*16 + 2*4 + a] = h2; \
            hout[(size_t)rix*HH + wv*16 + 3*4 + a] = h3; \
        } \
    } else if (em) { \
        for (int i = 0; i < kcur; i++) { \
            float* hp = hout + (size_t)(tptr+i)*HH + wv*16 + a; \
            hp[0] = h0; hp[4] = h1; hp[8] = h2; hp[12] = h3; \
        } \
        tptr += kcur; \
    } \
    rix++; \
    gptr0 += NG; gptr1 += NG; gptr2 += NG; gptr3 += NG; \
    BAR(); \
    buf ^= 1; \
} while(0)

#define PROC(dd, cc, hh) { \
    float v0 = dd[0], v1 = dd[1], v2 = dd[2], v3 = dd[3]; \
    float s0 = q0 ? v0 : v1;  float s1 = q0 ? v2 : v3; \
    float x0 = dpp_xor1(s0), x1 = dpp_xor1(s1); \
    v0 = q0 ? x0 : v0;  v1 = q0 ? v1 : x0; \
    v2 = q0 ? x1 : v2;  v3 = q0 ? v3 : x1; \
    s0 = q1 ? v0 : v2;  s1 = q1 ? v1 : v3; \
    x0 = dpp_xor2(s0);  x1 = dpp_xor2(s1); \
    v0 = q1 ? x0 : v0;  v2 = q1 ? v2 : x0; \
    v1 = q1 ? x1 : v1;  v3 = q1 ? v3 : x1; \
    float i_ = fast_rcp(1.f + fast_exp2(v0 * kSig)); \
    float f_ = fast_rcp(1.f + fast_exp2(v1 * kSig)); \
    float g_ = fmaf(-2.f, fast_rcp(1.f + fast_exp2(v2 * kTan2)), 1.f); \
    float o_ = fast_rcp(1.f + fast_exp2(v3 * kSig)); \
    cc = fmaf(f_, cc, i_ * g_); \
    float tc = fmaf(-2.f, fast_rcp(1.f + fast_exp2(cc * kTan2)), 1.f); \
    hh = o_ * tc; }

#define WRH(n0, hh) { \
    unsigned hu = __float_as_uint(hh); \
    unsigned bu = hu & 0xffff0000u; \
    float dd2 = hh - __uint_as_float(bu); \
    *(unsigned short*)(wb0 + ((cbw + n0*8) ^ swe)) = (unsigned short)(bu >> 16); \
    *(unsigned short*)(wb1 + ((cbw + n0*8) ^ swe)) = f2bf(dd2); }

    int niter = (nsteps + 5) / 6;
    for (int it6 = 0; it6 < niter; ++it6) {
        SEQ_STEP(0);
        SEQ_STEP(1);
        SEQ_STEP(2);
        SEQ_STEP(3);
        SEQ_STEP(4);
        SEQ_STEP(5);
    }
#undef SEQ_STEP
#undef PROC
#undef WRH
}

// ---------------- final: alpha[t] = sigmoid(fc_w . concat + fc_b) ------------
__global__ __launch_bounds__(256) void final_fc(const float* __restrict__ hA,
    const float* __restrict__ hB, const float* __restrict__ hI,
    const float* __restrict__ hpa, const float* __restrict__ hpb,
    const float* __restrict__ fcw, const float* __restrict__ fcb,
    float* __restrict__ out)
{
    int t = blockIdx.x * blockDim.x + threadIdx.x;
    if (t >= T_STEPS) return;
    float acc = fcb[0];
    const float* hs0 = hA  + (size_t)t*HH;
    const float* hs1 = hB  + (size_t)t*HH;
    const float* hs2 = hI  + (size_t)t*HH;
    const float* hs3 = hpa + (size_t)t*HH;
    const float* hs4 = hpb + (size_t)t*HH;
    #pragma unroll
    for (int k = 0; k < HH; k++) acc = fmaf(hs0[k], fcw[0*HH+k], acc);
    #pragma unroll
    for (int k = 0; k < HH; k++) acc = fmaf(hs1[k], fcw[1*HH+k], acc);
    #pragma unroll
    for (int k = 0; k < HH; k++) acc = fmaf(hs2[k], fcw[2*HH+k], acc);
    #pragma unroll
    for (int k = 0; k < HH; k++) acc = fmaf(hs3[k], fcw[3*HH+k], acc);
    #pragma unroll
    for (int k = 0; k < HH; k++) acc = fmaf(hs4[k], fcw[4*HH+k], acc);
    out[t] = fast_rcp(1.f + fast_exp2(acc * -1.44269504088896340736f));
}

// ---------------- launch -----------------------------------------------------
extern "C" void kernel_launch(void* const* d_in, const int* in_sizes, int n_in,
                              void* d_out, int out_size, void* d_ws, size_t ws_size,
                              hipStream_t stream)
{
    const float* xA      = (const float*)d_in[0];
    const float* xB      = (const float*)d_in[1];
    const float* img     = (const float*)d_in[2];
    const float* PA      = (const float*)d_in[3];
    const float* PB      = (const float*)d_in[4];
    const int*   lenA    = (const int*)d_in[5];
    const int*   lenB    = (const int*)d_in[6];
    const float* Wih_vad = (const float*)d_in[7];
    const float* Whh_vad = (const float*)d_in[8];
    const float* b_vad   = (const float*)d_in[9];
    const float* Wih_img = (const float*)d_in[10];
    const float* Whh_img = (const float*)d_in[11];
    const float* b_img   = (const float*)d_in[12];
    const float* Wih_lng = (const float*)d_in[13];
    const float* Whh_lng = (const float*)d_in[14];
    const float* b_lng   = (const float*)d_in[15];
    const float* fc_w    = (const float*)d_in[16];
    const float* fc_b    = (const float*)d_in[17];
    float* out = (float*)d_out;

    char* ws = (char*)d_ws;
    size_t off = 0;
    auto alloc = [&](size_t bytes) -> void* {
        void* p = ws + off;
        off += (bytes + 255) & ~(size_t)255;
        return p;
    };
    int* offsA = (int*)alloc((T_STEPS+1)*sizeof(int));
    int* offsB = (int*)alloc((T_STEPS+1)*sizeof(int));
    int* idxA  = (int*)alloc((size_t)SMAX*sizeof(int));
    int* idxB  = (int*)alloc((size_t)SMAX*sizeof(int));
    int* KsA   = (int*)alloc((size_t)KS_WORDS*sizeof(int));   // contiguous with KsB
    int* KsB   = (int*)alloc((size_t)KS_WORDS*sizeof(int));
    unsigned short* GvA = (unsigned short*)alloc((size_t)GD_ROWS*NG*2);
    unsigned short* GvB = (unsigned short*)alloc((size_t)GD_ROWS*NG*2);
    unsigned short* Gim = (unsigned short*)alloc((size_t)GD_ROWS*NG*2);
    unsigned short* GlA = (unsigned short*)alloc((size_t)GL_ROWS*NG*2);
    unsigned short* GlB = (unsigned short*)alloc((size_t)GL_ROWS*NG*2);
    float* hA  = (float*)alloc((size_t)T_STEPS*HH*sizeof(float));
    float* hB  = (float*)alloc((size_t)T_STEPS*HH*sizeof(float));
    float* hI  = (float*)alloc((size_t)T_STEPS*HH*sizeof(float));
    float* hpa = (float*)alloc((size_t)T_STEPS*HH*sizeof(float));
    float* hpb = (float*)alloc((size_t)T_STEPS*HH*sizeof(float));
    unsigned* Wbf0 = (unsigned*)alloc((size_t)NG*64*sizeof(unsigned));
    unsigned* Wbf1 = (unsigned*)alloc((size_t)NG*64*sizeof(unsigned));
    unsigned* Wbf2 = (unsigned*)alloc((size_t)NG*64*sizeof(unsigned));
    unsigned* Wsq0 = (unsigned*)alloc((size_t)NG*32*sizeof(unsigned));
    unsigned* Wsq1 = (unsigned*)alloc((size_t)NG*32*sizeof(unsigned));
    unsigned* Wsq2 = (unsigned*)alloc((size_t)NG*32*sizeof(unsigned));
    (void)ws_size; (void)in_sizes; (void)n_in; (void)out_size;

    scan_kernel<<<2, 64, 0, stream>>>(lenA, lenB, offsA, offsB);
    hipMemsetAsync(KsA, 0, 2*(size_t)KS_WORDS*sizeof(int), stream);
    build_meta<<<(T_STEPS+255)/256, 256, 0, stream>>>(lenA, offsA, idxA, KsA);
    build_meta<<<(T_STEPS+255)/256, 256, 0, stream>>>(lenB, offsB, idxB, KsB);
    conv_w<<<dim3(64,3), 256, 0, stream>>>(Wih_vad, Wih_img, Wih_lng, Wbf0, Wbf1, Wbf2);
    conv_wseq<<<3, 256, 0, stream>>>(Whh_vad, Whh_img, Whh_lng, Wsq0, Wsq1, Wsq2);

    GemmArgs GA;
    GA.xsrc[0]=xA; GA.xsrc[1]=xB; GA.xsrc[2]=img;
    GA.psrc[0]=PA; GA.psrc[1]=PB;
    GA.idx[0]=idxA; GA.idx[1]=idxB;
    GA.Wb[0]=Wbf0; GA.Wb[1]=Wbf1; GA.Wb[2]=Wbf2;
    GA.bias[0]=b_vad; GA.bias[1]=b_img; GA.bias[2]=b_lng;
    GA.G[0]=GvA; GA.G[1]=GvB; GA.G[2]=Gim; GA.G[3]=GlA; GA.G[4]=GlB;
    GA.offs[0]=offsA; GA.offs[1]=offsB;
    gates_mfma<<<TOTROWS/64, 256, 0, stream>>>(GA);

    SeqArgs A;
    A.gx[0]=GvA;  A.gx[1]=GvB;  A.gx[2]=Gim;  A.gx[3]=GlA;  A.gx[4]=GlB;
    A.wseq[0]=Wsq0; A.wseq[1]=Wsq0; A.wseq[2]=Wsq1; A.wseq[3]=Wsq2; A.wseq[4]=Wsq2;
    A.hout[0]=hA; A.hout[1]=hB; A.hout[2]=hI; A.hout[3]=hpa; A.hout[4]=hpb;
    A.offs[0]=nullptr; A.offs[1]=nullptr; A.offs[2]=nullptr; A.offs[3]=offsA; A.offs[4]=offsB;
    A.ks[0]=nullptr; A.ks[1]=nullptr; A.ks[2]=nullptr; A.ks[3]=KsA; A.ks[4]=KsB;
    seq_kernel<<<NBLK_SEQ, 256, 0, stream>>>(A);

    final_fc<<<(T_STEPS+255)/256, 256, 0, stream>>>(hA, hB, hI, hpa, hpb, fc_w, fc_b, out);
}